// Round 18
// baseline (1068.956 us; speedup 1.0000x reference)
//
#include <hip/hip_runtime.h>
#include <hip/hip_bf16.h>
#include <math.h>

#define B 32
#define T 50
#define H 1024
#define E 128
#define V 32000
#define G4 4096   // 4*H
#define HE 1152   // H+E
#define MROWS 1664 // 13*128 padded M for GEMM
#define NB 256    // coop grid blocks

typedef __fp16 half2v __attribute__((ext_vector_type(2)));
typedef __fp16 half8 __attribute__((ext_vector_type(8)));
typedef unsigned long long ull;
union U32H2 { unsigned u; half2v h; };
union U4H8 { uint4 u4; half8 h8; };
typedef short short8 __attribute__((ext_vector_type(8)));
typedef float floatx4 __attribute__((ext_vector_type(4)));
union U16S8 { uint4 u4; short8 s8; };

// 16B LLC-coherent load (bypass L1+L2), issue-only; pair with one vmcnt wait.
#define LLC_LOAD(dst, ptr) \
  asm volatile("global_load_dwordx4 %0, %1, off sc0 sc1" : "=v"((dst).u4) : "v"(ptr))

__device__ __forceinline__ float sigm(float x){ return 1.0f/(1.0f+expf(-x)); }

__device__ __forceinline__ half2v pk2(float a, float b){
#if __has_builtin(__builtin_amdgcn_cvt_pkrtz)
  return __builtin_amdgcn_cvt_pkrtz(a, b);
#else
  half2v r; r.x = (__fp16)a; r.y = (__fp16)b; return r;
#endif
}

// pack two f32 -> one u32 of two bf16 (RNE)
__device__ __forceinline__ unsigned pkbf(float a, float b){
  unsigned ua = __float_as_uint(a), ub = __float_as_uint(b);
  unsigned ra = (ua + 0x7FFFu + ((ua>>16)&1u)) >> 16;
  unsigned rb = (ub + 0x7FFFu + ((ub>>16)&1u)) >> 16;
  return ra | (rb << 16);
}

// agent-scope store, 8B (bypasses caches, lands at LLC)
__device__ __forceinline__ void stA8(void* p, uint2 v){
  ull q = ((ull)v.y << 32) | (ull)v.x;
  __hip_atomic_store((ull*)p, q, __ATOMIC_RELAXED, __HIP_MEMORY_SCOPE_AGENT);
}

// ---- fence-free slot-write + scanner grid barrier ----
// bar[0]=root; bar[8+g*4]=leaf flag g (g=0..7); bar[64+bid*16]=per-block slot
// (cache-line spread). Arrival = ONE independent store per block; blocks 0..7
// scan their 32 slots in parallel (32 lanes, __all); block 0 publishes root.
// Ordering: s_waitcnt vmcnt(0) drains wave-0's agent state stores pre-arrival.
__device__ __forceinline__ void gbar(unsigned* bar, unsigned ep){
  __syncthreads();
  const int bid = blockIdx.x;
  const int t = threadIdx.x;
  if (t < 64){
    if (t == 0){
      asm volatile("s_waitcnt vmcnt(0)" ::: "memory");
      __hip_atomic_store(&bar[64 + bid*16], ep, __ATOMIC_RELAXED, __HIP_MEMORY_SCOPE_AGENT);
    }
    if (bid < 8){
      bool ok;
      do {
        unsigned v = (t < 32)
          ? __hip_atomic_load(&bar[64 + (bid*32 + t)*16], __ATOMIC_RELAXED, __HIP_MEMORY_SCOPE_AGENT)
          : ep;
        ok = __all(v >= ep);
        if (!ok) __builtin_amdgcn_s_sleep(1);
      } while (!ok);
      if (t == 0)
        __hip_atomic_store(&bar[8 + bid*4], ep, __ATOMIC_RELAXED, __HIP_MEMORY_SCOPE_AGENT);
      if (bid == 0){
        do {
          unsigned v = (t < 8)
            ? __hip_atomic_load(&bar[8 + t*4], __ATOMIC_RELAXED, __HIP_MEMORY_SCOPE_AGENT)
            : ep;
          ok = __all(v >= ep);
          if (!ok) __builtin_amdgcn_s_sleep(1);
        } while (!ok);
        if (t == 0)
          __hip_atomic_store(&bar[0], ep, __ATOMIC_RELAXED, __HIP_MEMORY_SCOPE_AGENT);
      } else if (t == 0){
        while (__hip_atomic_load(&bar[0], __ATOMIC_RELAXED, __HIP_MEMORY_SCOPE_AGENT) < ep)
          __builtin_amdgcn_s_sleep(1);
      }
    } else if (t == 0){
      while (__hip_atomic_load(&bar[0], __ATOMIC_RELAXED, __HIP_MEMORY_SCOPE_AGENT) < ep)
        __builtin_amdgcn_s_sleep(1);
    }
  }
  __syncthreads();
}

// encp[b][e] = proj_b[e] + sum_j enc[b][j] * proj_w[e][E+j]
__global__ void k_encp(const float* __restrict__ enc, const float* __restrict__ pw,
                       const float* __restrict__ pb, float* __restrict__ encp){
  int b = blockIdx.x, e = threadIdx.x;
  const float* er = enc + b*H;
  const float* wr = pw + e*HE + E;
  float acc = pb[e];
  for (int j=0;j<H;j+=4){
    float4 w4 = *(const float4*)(wr+j);
    float4 e4 = *(const float4*)(er+j);
    acc += w4.x*e4.x + w4.y*e4.y + w4.z*e4.z + w4.w*e4.w;
  }
  encp[b*E+e] = acc;
}

// P[t][e][b] = encp[b][e] + sum_j target[b][t][j] * proj_w[e][j]
__global__ void k_proj(const float* __restrict__ target, const float* __restrict__ pw,
                       const float* __restrict__ encp, float* __restrict__ P){
  int t = blockIdx.x / B, b = blockIdx.x % B, e = threadIdx.x;
  const float* xr = target + (b*T + t)*E;
  const float* wr = pw + e*HE;
  float acc = encp[b*E+e];
  for (int j=0;j<E;j+=4){
    float4 w4 = *(const float4*)(wr+j);
    float4 x4 = *(const float4*)(xr+j);
    acc += w4.x*x4.x + w4.y*x4.y + w4.z*x4.z + w4.w*x4.w;
  }
  P[(t*E + e)*B + b] = acc;
}

// xg0[t][r][b] = b_ih0[r]+b_hh0[r] + sum_e w_ih0[r][e] * P[t][e][b]
__global__ void k_xg0(const float* __restrict__ wih0, const float* __restrict__ bih0,
                      const float* __restrict__ bhh0, const float* __restrict__ P,
                      float* __restrict__ xg){
  int idx = blockIdx.x*256 + threadIdx.x;
  int b = idx & 31; int r = (idx >> 5) & 4095; int t = idx >> 17;
  const float* wr = wih0 + r*E;
  const float* pr = P + t*E*B + b;
  float acc = bih0[r] + bhh0[r];
  #pragma unroll 8
  for (int e=0;e<E;e++) acc += wr[e] * pr[e*B];
  xg[idx] = acc;
}

__global__ void k_zero32(unsigned* __restrict__ p){
  p[blockIdx.x*256 + threadIdx.x] = 0u;
}

// convert lw f32 -> bf16 in the GEMM's swizzled tile layout
__global__ void k_cvtw(const float* __restrict__ lw, uint4* __restrict__ wsw){
  int gid = blockIdx.x*256 + threadIdx.x;   // 4,096,000
  int n = gid >> 7, rem = gid & 127;
  int k0c = rem >> 3, seg = rem & 7;
  const float4* src = (const float4*)(lw + (long)n*H + k0c*64 + seg*8);
  float4 v0 = src[0], v1 = src[1];
  uint4 pk;
  pk.x = pkbf(v0.x, v0.y); pk.y = pkbf(v0.z, v0.w);
  pk.z = pkbf(v1.x, v1.y); pk.w = pkbf(v1.z, v1.w);
  int bn = n >> 7, row = n & 127;
  wsw[((long)(bn*16 + k0c)*128 + row)*8 + (seg ^ (row & 7))] = pk;
}

// pack H1Tmk f32 [m][k] -> Abf swizzled bf16 tiles (fallback path only)
__global__ void k_pack(const float* __restrict__ H1Tmk, uint4* __restrict__ Abf){
  int gid = blockIdx.x*256 + threadIdx.x;   // 204,800
  int m = gid >> 7, rem = gid & 127;
  int k0c = rem >> 3, seg = rem & 7;
  const float4* src = (const float4*)(H1Tmk + (long)m*1024 + k0c*64 + seg*8);
  float4 v0 = src[0], v1 = src[1];
  uint4 pk;
  pk.x = pkbf(v0.x, v0.y); pk.y = pkbf(v0.z, v0.w);
  pk.z = pkbf(v1.x, v1.y); pk.w = pkbf(v1.z, v1.w);
  int bm = m >> 7, row = m & 127;
  Abf[((long)(bm*16 + k0c)*128 + row)*8 + (seg ^ (row & 7))] = pk;
}

// ---------------- cooperative persistent cells (v11: scanner barrier) ----------------
__global__ __launch_bounds__(1024, 4) void k_cells(
    const float* __restrict__ whh0, const float* __restrict__ wih1, const float* __restrict__ whh1,
    const float* __restrict__ bih1, const float* __restrict__ bhh1,
    const float* __restrict__ enc, const float* __restrict__ xg0,
    unsigned* __restrict__ h0A2, unsigned* __restrict__ h0B2,
    unsigned* __restrict__ h1A2, unsigned* __restrict__ h1B2,
    unsigned* __restrict__ Abf, unsigned* __restrict__ bar){
  const int gB = blockIdx.x;
  const int tid = threadIdx.x;
  const int w = tid >> 6;       // wave 0..15 = k-chunk owner
  const int l = tid & 63;
  const int lrow = l & 15;      // fragment row/col
  const int lk = l >> 4;        // k-segment 0..3

  __shared__ uint4 w0s4[16*128];        // layer0 whh0 rows, f16 swizzled (32 KB)
  __shared__ uint4 w1s4[32*128];        // wih1(0-15)+whh1(16-31) (64 KB)
  __shared__ float partial[16][16][34]; // [wave][row][b-col] pad 34
  __shared__ float gates[16][32];
  __shared__ float cst[2][4][32];
  __shared__ float bs1v[16];
  __shared__ __fp16 h1loc[4][1600];     // [hl][b*T+t] (12.8 KB)

  // ---- stage weights f32 -> f16, XOR-swizzled segments ----
  for (int i = tid; i < 2048; i += 1024){
    int row = i >> 7, seg = i & 127;
    int q = row >> 2, hl = row & 3;
    const float* src = whh0 + ((long)q*H + 4*gB + hl)*H + seg*8;
    float4 v0 = *(const float4*)src, v1 = *(const float4*)(src+4);
    U32H2 z0,z1,z2,z3;
    z0.h = pk2(v0.x,v0.y); z1.h = pk2(v0.z,v0.w);
    z2.h = pk2(v1.x,v1.y); z3.h = pk2(v1.z,v1.w);
    uint4 pk; pk.x=z0.u; pk.y=z1.u; pk.z=z2.u; pk.w=z3.u;
    int phys = (seg & ~7) | ((seg & 7) ^ (row & 7));
    w0s4[row*128 + phys] = pk;
  }
  for (int i = tid; i < 4096; i += 1024){
    int row = i >> 7, seg = i & 127;
    int rr = row & 15;
    int q = rr >> 2, hl = rr & 3;
    const float* srcm = (row < 16) ? wih1 : whh1;
    const float* src = srcm + ((long)q*H + 4*gB + hl)*H + seg*8;
    float4 v0 = *(const float4*)src, v1 = *(const float4*)(src+4);
    U32H2 z0,z1,z2,z3;
    z0.h = pk2(v0.x,v0.y); z1.h = pk2(v0.z,v0.w);
    z2.h = pk2(v1.x,v1.y); z3.h = pk2(v1.z,v1.w);
    uint4 pk; pk.x=z0.u; pk.y=z1.u; pk.z=z2.u; pk.w=z3.u;
    int phys = (seg & ~7) | ((seg & 7) ^ (rr & 7));
    w1s4[row*128 + phys] = pk;
  }
  if (tid < 16){
    int q = tid >> 2, hl = tid & 3;
    bs1v[tid] = bih1[q*H + 4*gB + hl] + bhh1[q*H + 4*gB + hl];
  }
  if (tid < 128){
    int hl = tid >> 5, bb = tid & 31;
    float v = enc[bb*H + 4*gB + hl];
    cst[0][hl][bb] = v; cst[1][hl][bb] = v;
  }
  if (tid < 32){
    int bb = tid;
    U32H2 z0, z1;
    z0.h = pk2(enc[bb*H + 4*gB + 0], enc[bb*H + 4*gB + 1]);
    z1.h = pk2(enc[bb*H + 4*gB + 2], enc[bb*H + 4*gB + 3]);
    uint2 val; val.x = z0.u; val.y = z1.u;
    stA8((char*)h0A2 + (long)(bb*1024 + 4*gB)*2, val);
    stA8((char*)h1A2 + (long)(bb*1024 + 4*gB)*2, val);
  }
  unsigned ep = 1;
  gbar(bar, ep); ep++;

  for (int p = 0; p <= T; p++){
    const unsigned* h0r = (p & 1) ? h0B2 : h0A2;
    unsigned*       h0w = (p & 1) ? h0A2 : h0B2;
    const unsigned* h1r = (p & 1) ? h1A2 : h1B2;
    unsigned*       h1w = (p & 1) ? h1B2 : h1A2;

    // ---- batched LLC state loads (issue all, wait once) ----
    int c = (w + gB + p) & 15;
    U4H8 b0a0, b0a1, b0b0, b0b1, b1a0, b1a1, b1b0, b1b1;
    {
      int kb = c*64;
      const __fp16* h0f = (const __fp16*)h0r;
      const __fp16* h1f = (const __fp16*)h1r;
      const __fp16* s0a = h0f + lrow*1024 + kb + lk*8;
      const __fp16* s0b = h0f + (16+lrow)*1024 + kb + lk*8;
      LLC_LOAD(b0a0, s0a);      LLC_LOAD(b0a1, s0a + 32);
      LLC_LOAD(b0b0, s0b);      LLC_LOAD(b0b1, s0b + 32);
      if (p >= 1){
        const __fp16* s1a = h1f + lrow*1024 + kb + lk*8;
        const __fp16* s1b = h1f + (16+lrow)*1024 + kb + lk*8;
        LLC_LOAD(b1a0, s1a);    LLC_LOAD(b1a1, s1a + 32);
        LLC_LOAD(b1b0, s1b);    LLC_LOAD(b1b1, s1b + 32);
      }
      asm volatile("s_waitcnt vmcnt(0)" ::: "memory");
      __builtin_amdgcn_sched_barrier(0);
    }

    // xg prefetch for layer0(p) — issued after the state-wait, overlaps MFMAs
    float xgv = 0.f;
    if (p < T && tid < 512){
      int r = tid >> 5, bb = tid & 31;
      int q = r >> 2, hl = r & 3;
      xgv = xg0[((long)p*G4 + (long)q*H + 4*gB + hl)*32 + bb];
    }

    // ---- MFMA matvec ----
    floatx4 acc10 = {0,0,0,0}, acc11 = {0,0,0,0};
    floatx4 acc00 = {0,0,0,0}, acc01 = {0,0,0,0};
    #pragma unroll
    for (int ks = 0; ks < 2; ks++){
      int phys = c*8 + (((ks<<2) + lk) ^ (lrow & 7));
      half8 B0a = ks ? b0a1.h8 : b0a0.h8;
      half8 B0b = ks ? b0b1.h8 : b0b0.h8;
      if (p < T){
        U4H8 a0v; a0v.u4 = w0s4[lrow*128 + phys];
        acc00 = __builtin_amdgcn_mfma_f32_16x16x32_f16(a0v.h8, B0a, acc00, 0, 0, 0);
        acc01 = __builtin_amdgcn_mfma_f32_16x16x32_f16(a0v.h8, B0b, acc01, 0, 0, 0);
      }
      if (p >= 1){
        U4H8 a1i; a1i.u4 = w1s4[lrow*128 + phys];
        U4H8 a1h; a1h.u4 = w1s4[(16+lrow)*128 + phys];
        half8 B1a = ks ? b1a1.h8 : b1a0.h8;
        half8 B1b = ks ? b1b1.h8 : b1b0.h8;
        acc10 = __builtin_amdgcn_mfma_f32_16x16x32_f16(a1i.h8, B0a, acc10, 0, 0, 0);
        acc10 = __builtin_amdgcn_mfma_f32_16x16x32_f16(a1h.h8, B1a, acc10, 0, 0, 0);
        acc11 = __builtin_amdgcn_mfma_f32_16x16x32_f16(a1i.h8, B0b, acc11, 0, 0, 0);
        acc11 = __builtin_amdgcn_mfma_f32_16x16x32_f16(a1h.h8, B1b, acc11, 0, 0, 0);
      }
    }
    if (p >= 1){
      #pragma unroll
      for (int r = 0; r < 4; r++){
        partial[w][lk*4 + r][lrow]      = acc10[r];
        partial[w][lk*4 + r][16 + lrow] = acc11[r];
      }
    }
    __syncthreads();
    // ---- layer1(p-1) reduce + cell ----
    if (p >= 1 && tid < 512){
      int r = tid >> 5, bb = tid & 31;
      float s = 0.f;
      #pragma unroll
      for (int w2 = 0; w2 < 16; w2++) s += partial[w2][r][bb];
      float v = s + bs1v[r];
      gates[r][bb] = ((r >> 2) == 2) ? tanhf(v) : sigm(v);
    }
    __syncthreads();
    if (p >= 1 && tid < 32){
      int bb = tid, t1 = p - 1;
      float hn[4];
      #pragma unroll
      for (int hl = 0; hl < 4; hl++){
        float cn = gates[4+hl][bb]*cst[1][hl][bb] + gates[0+hl][bb]*gates[8+hl][bb];
        cst[1][hl][bb] = cn;
        hn[hl] = gates[12+hl][bb]*tanhf(cn);
        h1loc[hl][bb*T + t1] = (__fp16)hn[hl];
      }
      U32H2 z0, z1; z0.h = pk2(hn[0], hn[1]); z1.h = pk2(hn[2], hn[3]);
      uint2 val; val.x = z0.u; val.y = z1.u;
      stA8((char*)h1w + (long)(bb*1024 + 4*gB)*2, val);
    }
    // ---- layer0(p) partial stash ----
    if (p < T){
      #pragma unroll
      for (int r = 0; r < 4; r++){
        partial[w][lk*4 + r][lrow]      = acc00[r];
        partial[w][lk*4 + r][16 + lrow] = acc01[r];
      }
    }
    __syncthreads();
    if (p < T && tid < 512){
      int r = tid >> 5, bb = tid & 31;
      float s = 0.f;
      #pragma unroll
      for (int w2 = 0; w2 < 16; w2++) s += partial[w2][r][bb];
      float v = s + xgv;
      gates[r][bb] = ((r >> 2) == 2) ? tanhf(v) : sigm(v);
    }
    __syncthreads();
    if (p < T && tid < 32){
      int bb = tid;
      float hn[4];
      #pragma unroll
      for (int hl = 0; hl < 4; hl++){
        float cn = gates[4+hl][bb]*cst[0][hl][bb] + gates[0+hl][bb]*gates[8+hl][bb];
        cst[0][hl][bb] = cn;
        hn[hl] = gates[12+hl][bb]*tanhf(cn);
      }
      U32H2 z0, z1; z0.h = pk2(hn[0], hn[1]); z1.h = pk2(hn[2], hn[3]);
      uint2 val; val.x = z0.u; val.y = z1.u;
      stA8((char*)h0w + (long)(bb*1024 + 4*gB)*2, val);
    }
    gbar(bar, ep); ep++;
  }

  // direct swizzled-Abf flush: block gB owns k = 4gB..4gB+3 (8B half-slot)
  {
    int k0c = gB >> 4;
    int seg = (gB & 15) >> 1;
    int posb = (gB & 1) * 8;
    for (int m = tid; m < B*T; m += 1024){
      float v0 = (float)h1loc[0][m], v1 = (float)h1loc[1][m];
      float v2 = (float)h1loc[2][m], v3 = (float)h1loc[3][m];
      int bm = m >> 7, row = m & 127;
      long slot = ((long)(bm*16 + k0c)*128 + row)*8 + (seg ^ (row & 7));
      uint2 val; val.x = pkbf(v0, v1); val.y = pkbf(v2, v3);
      *(uint2*)((char*)Abf + slot*16 + posb) = val;
    }
  }
}

// ---------------- fallback per-step cells ----------------
__global__ void k_init(const float* __restrict__ enc, float* __restrict__ h0, float* __restrict__ c0,
                       float* __restrict__ h1, float* __restrict__ c1){
  int idx = blockIdx.x*256 + threadIdx.x;
  int b = idx & 31, h = idx >> 5;
  float v = enc[b*H + h];
  h0[idx]=v; c0[idx]=v; h1[idx]=v; c1[idx]=v;
}

__global__ __launch_bounds__(256) void k_cell0(const float* __restrict__ whh, const float* __restrict__ xg_t,
                       const float* __restrict__ h_in, float* __restrict__ h_out,
                       float* __restrict__ c){
  int h = (blockIdx.x*256 + threadIdx.x) >> 6;
  int lane = threadIdx.x & 63;
  int b = lane & 31, kh = lane >> 5;
  const float* w0 = whh + (0*H + h)*H + kh*512;
  const float* w1 = whh + (1*H + h)*H + kh*512;
  const float* w2 = whh + (2*H + h)*H + kh*512;
  const float* w3 = whh + (3*H + h)*H + kh*512;
  const float* hk = h_in + (kh*512)*B + b;
  float a0=0,a1=0,a2=0,a3=0, p0=0,p1=0,p2=0,p3=0;
  #pragma unroll 4
  for (int k=0;k<512;k+=4){
    float4 w40 = *(const float4*)(w0+k);
    float4 w41 = *(const float4*)(w1+k);
    float4 w42 = *(const float4*)(w2+k);
    float4 w43 = *(const float4*)(w3+k);
    float hv0 = hk[(k+0)*B], hv1 = hk[(k+1)*B], hv2 = hk[(k+2)*B], hv3 = hk[(k+3)*B];
    a0 += w40.x*hv0 + w40.y*hv1;  p0 += w40.z*hv2 + w40.w*hv3;
    a1 += w41.x*hv0 + w41.y*hv1;  p1 += w41.z*hv2 + w41.w*hv3;
    a2 += w42.x*hv0 + w42.y*hv1;  p2 += w42.z*hv2 + w42.w*hv3;
    a3 += w43.x*hv0 + w43.y*hv1;  p3 += w43.z*hv2 + w43.w*hv3;
  }
  float g0=a0+p0, g1=a1+p1, g2=a2+p2, g3=a3+p3;
  g0 += __shfl_xor(g0, 32);
  g1 += __shfl_xor(g1, 32);
  g2 += __shfl_xor(g2, 32);
  g3 += __shfl_xor(g3, 32);
  g0 += xg_t[(0*H+h)*B + b];
  g1 += xg_t[(1*H+h)*B + b];
  g2 += xg_t[(2*H+h)*B + b];
  g3 += xg_t[(3*H+h)*B + b];
  float ig = sigm(g0), fg = sigm(g1), gg = tanhf(g2), og = sigm(g3);
  int sidx = h*B + b;
  float cn = fg*c[sidx] + ig*gg;
  float hn = og*tanhf(cn);
  if (kh==0){ c[sidx]=cn; h_out[sidx]=hn; }
}

__global__ __launch_bounds__(256) void k_cell1(const float* __restrict__ wih, const float* __restrict__ whh,
                       const float* __restrict__ bih, const float* __restrict__ bhh,
                       const float* __restrict__ h0n, const float* __restrict__ h_in,
                       float* __restrict__ h_out, float* __restrict__ c,
                       float* __restrict__ H1Tmk, int t){
  int h = (blockIdx.x*256 + threadIdx.x) >> 6;
  int lane = threadIdx.x & 63;
  int b = lane & 31, kh = lane >> 5;
  float a0=0,a1=0,a2=0,a3=0, p0=0,p1=0,p2=0,p3=0;
  {
    const float* w0 = wih + (0*H + h)*H + kh*512;
    const float* w1 = wih + (1*H + h)*H + kh*512;
    const float* w2 = wih + (2*H + h)*H + kh*512;
    const float* w3 = wih + (3*H + h)*H + kh*512;
    const float* hk = h0n + (kh*512)*B + b;
    #pragma unroll 4
    for (int k=0;k<512;k+=4){
      float4 w40 = *(const float4*)(w0+k);
      float4 w41 = *(const float4*)(w1+k);
      float4 w42 = *(const float4*)(w2+k);
      float4 w43 = *(const float4*)(w3+k);
      float hv0 = hk[(k+0)*B], hv1 = hk[(k+1)*B], hv2 = hk[(k+2)*B], hv3 = hk[(k+3)*B];
      a0 += w40.x*hv0 + w40.y*hv1;  p0 += w40.z*hv2 + w40.w*hv3;
      a1 += w41.x*hv0 + w41.y*hv1;  p1 += w41.z*hv2 + w41.w*hv3;
      a2 += w42.x*hv0 + w42.y*hv1;  p2 += w42.z*hv2 + w42.w*hv3;
      a3 += w43.x*hv0 + w43.y*hv1;  p3 += w43.z*hv2 + w43.w*hv3;
    }
  }
  {
    const float* w0 = whh + (0*H + h)*H + kh*512;
    const float* w1 = whh + (1*H + h)*H + kh*512;
    const float* w2 = whh + (2*H + h)*H + kh*512;
    const float* w3 = whh + (3*H + h)*H + kh*512;
    const float* hk = h_in + (kh*512)*B + b;
    #pragma unroll 4
    for (int k=0;k<512;k+=4){
      float4 w40 = *(const float4*)(w0+k);
      float4 w41 = *(const float4*)(w1+k);
      float4 w42 = *(const float4*)(w2+k);
      float4 w43 = *(const float4*)(w3+k);
      float hv0 = hk[(k+0)*B], hv1 = hk[(k+1)*B], hv2 = hk[(k+2)*B], hv3 = hk[(k+3)*B];
      a0 += w40.x*hv0 + w40.y*hv1;  p0 += w40.z*hv2 + w40.w*hv3;
      a1 += w41.x*hv0 + w41.y*hv1;  p1 += w41.z*hv2 + w41.w*hv3;
      a2 += w42.x*hv0 + w42.y*hv1;  p2 += w42.z*hv2 + w42.w*hv3;
      a3 += w43.x*hv0 + w43.y*hv1;  p3 += w43.z*hv2 + w43.w*hv3;
    }
  }
  float g0=a0+p0, g1=a1+p1, g2=a2+p2, g3=a3+p3;
  g0 += __shfl_xor(g0, 32);
  g1 += __shfl_xor(g1, 32);
  g2 += __shfl_xor(g2, 32);
  g3 += __shfl_xor(g3, 32);
  g0 += bih[0*H+h] + bhh[0*H+h];
  g1 += bih[1*H+h] + bhh[1*H+h];
  g2 += bih[2*H+h] + bhh[2*H+h];
  g3 += bih[3*H+h] + bhh[3*H+h];
  float ig = sigm(g0), fg = sigm(g1), gg = tanhf(g2), og = sigm(g3);
  int sidx = h*B + b;
  float cn = fg*c[sidx] + ig*gg;
  float hn = og*tanhf(cn);
  if (kh==0){ c[sidx]=cn; h_out[sidx]=hn; H1Tmk[((long)(b*T + t))*1024 + h] = hn; }
}

// ---------------- MFMA bf16 output GEMM (pre-swizzled operands) ----------------
__global__ __launch_bounds__(256, 2) void k_gemm_pre(const uint4* __restrict__ Abf4,
                      const uint4* __restrict__ Wsw4, const float* __restrict__ lb,
                      float* __restrict__ out){
  __shared__ uint4 As4[1024];
  __shared__ uint4 Ws4[1024];
  const int tid = threadIdx.x;
  int orig = blockIdx.x;
  int xcd = orig & 7, ii = orig >> 3;
  int wgid = (xcd < 2 ? xcd*407 : 814 + (xcd-2)*406) + ii;
  int bm = wgid % 13, bn = wgid / 13;
  int m0 = bm*128, n0 = bn*128;
  const int wv = tid >> 6, l = tid & 63;
  const int wm = (wv >> 1)*64, wn = (wv & 1)*64;
  const int lrow = l & 15, lk = l >> 4;

  floatx4 acc[4][4] = {};
  for (int k0c = 0; k0c < 16; k0c++){
    const uint4* sA = Abf4 + (long)(bm*16 + k0c)*1024;
    const uint4* sW = Wsw4 + (long)(bn*16 + k0c)*1024;
    #pragma unroll
    for (int it = 0; it < 4; it++){
      int slot = tid + it*256;
      As4[slot] = sA[slot];
      Ws4[slot] = sW[slot];
    }
    __syncthreads();
    #pragma unroll
    for (int ks = 0; ks < 2; ks++){
      short8 af[4], bf_[4];
      #pragma unroll
      for (int fi = 0; fi < 4; fi++){
        int row = wm + fi*16 + lrow;
        U16S8 u; u.u4 = As4[row*8 + ((ks*4 + lk) ^ (lrow & 7))];
        af[fi] = u.s8;
      }
      #pragma unroll
      for (int fj = 0; fj < 4; fj++){
        int row = wn + fj*16 + lrow;
        U16S8 u; u.u4 = Ws4[row*8 + ((ks*4 + lk) ^ (lrow & 7))];
        bf_[fj] = u.s8;
      }
      #pragma unroll
      for (int fi = 0; fi < 4; fi++)
        #pragma unroll
        for (int fj = 0; fj < 4; fj++)
          acc[fi][fj] = __builtin_amdgcn_mfma_f32_16x16x32_bf16(af[fi], bf_[fj], acc[fi][fj], 0, 0, 0);
    }
    __syncthreads();
  }
  #pragma unroll
  for (int fj = 0; fj < 4; fj++){
    int n = n0 + wn + fj*16 + lrow;
    float bias = lb[n];
    #pragma unroll
    for (int fi = 0; fi < 4; fi++){
      floatx4 av = acc[fi][fj];
      int mb = m0 + wm + fi*16 + lk*4;
      #pragma unroll
      for (int r = 0; r < 4; r++){
        int m = mb + r;
        if (m < B*T) out[(long)m*V + n] = av[r] + bias;
      }
    }
  }
}

// fallback GEMM: A pre-swizzled, W converted inline from f32
__global__ __launch_bounds__(256, 2) void k_gemm_inl(const uint4* __restrict__ Abf4,
                      const float* __restrict__ lw, const float* __restrict__ lb,
                      float* __restrict__ out){
  __shared__ uint4 As4[1024];
  __shared__ uint4 Ws4[1024];
  const int tid = threadIdx.x;
  int orig = blockIdx.x;
  int xcd = orig & 7, ii = orig >> 3;
  int wgid = (xcd < 2 ? xcd*407 : 814 + (xcd-2)*406) + ii;
  int bm = wgid % 13, bn = wgid / 13;
  int m0 = bm*128, n0 = bn*128;
  const int wv = tid >> 6, l = tid & 63;
  const int wm = (wv >> 1)*64, wn = (wv & 1)*64;
  const int lrow = l & 15, lk = l >> 4;

  floatx4 acc[4][4] = {};
  for (int k0c = 0; k0c < 16; k0c++){
    const uint4* sA = Abf4 + (long)(bm*16 + k0c)*1024;
    #pragma unroll
    for (int it = 0; it < 4; it++){
      int slot = tid + it*256;
      As4[slot] = sA[slot];
      int row = slot >> 3, seg = slot & 7;
      const float4* src = (const float4*)(lw + (long)(n0+row)*H + k0c*64 + seg*8);
      float4 v0 = src[0], v1 = src[1];
      uint4 pk;
      pk.x = pkbf(v0.x, v0.y); pk.y = pkbf(v0.z, v0.w);
      pk.z = pkbf(v1.x, v1.y); pk.w = pkbf(v1.z, v1.w);
      Ws4[row*8 + (seg ^ (row & 7))] = pk;
    }
    __syncthreads();
    #pragma unroll
    for (int ks = 0; ks < 2; ks++){
      short8 af[4], bf_[4];
      #pragma unroll
      for (int fi = 0; fi < 4; fi++){
        int row = wm + fi*16 + lrow;
        U16S8 u; u.u4 = As4[row*8 + ((ks*4 + lk) ^ (lrow & 7))];
        af[fi] = u.s8;
      }
      #pragma unroll
      for (int fj = 0; fj < 4; fj++){
        int row = wn + fj*16 + lrow;
        U16S8 u; u.u4 = Ws4[row*8 + ((ks*4 + lk) ^ (lrow & 7))];
        bf_[fj] = u.s8;
      }
      #pragma unroll
      for (int fi = 0; fi < 4; fi++)
        #pragma unroll
        for (int fj = 0; fj < 4; fj++)
          acc[fi][fj] = __builtin_amdgcn_mfma_f32_16x16x32_bf16(af[fi], bf_[fj], acc[fi][fj], 0, 0, 0);
    }
    __syncthreads();
  }
  #pragma unroll
  for (int fj = 0; fj < 4; fj++){
    int n = n0 + wn + fj*16 + lrow;
    float bias = lb[n];
    #pragma unroll
    for (int fi = 0; fi < 4; fi++){
      floatx4 av = acc[fi][fj];
      int mb = m0 + wm + fi*16 + lk*4;
      #pragma unroll
      for (int r = 0; r < 4; r++){
        int m = mb + r;
        if (m < B*T) out[(long)m*V + n] = av[r] + bias;
      }
    }
  }
}

// online 2-pass log-softmax
__global__ __launch_bounds__(256) void k_lsm(float* __restrict__ out){
  __shared__ float redm[256], reds[256];
  float4* row = (float4*)(out + (long)blockIdx.x * V);
  const int tid = threadIdx.x;
  float m = -INFINITY, s = 0.f;
  for (int n=tid;n<V/4;n+=256){
    float4 v = row[n];
    float cm = fmaxf(fmaxf(v.x,v.y), fmaxf(v.z,v.w));
    if (cm > m){ s *= __expf(m - cm); m = cm; }
    s += __expf(v.x-m)+__expf(v.y-m)+__expf(v.z-m)+__expf(v.w-m);
  }
  redm[tid]=m; reds[tid]=s; __syncthreads();
  for (int st=128;st>0;st>>=1){
    if (tid<st){
      float m1=redm[tid], s1=reds[tid];
      float m2=redm[tid+st], s2=reds[tid+st];
      float M=fmaxf(m1,m2);
      reds[tid]=s1*__expf(m1-M)+s2*__expf(m2-M);
      redm[tid]=M;
    }
    __syncthreads();
  }
  float lse = redm[0] + __logf(reds[0]);
  for (int n=tid;n<V/4;n+=256){
    float4 v = row[n];
    v.x-=lse; v.y-=lse; v.z-=lse; v.w-=lse;
    row[n] = v;
  }
}

extern "C" void kernel_launch(void* const* d_in, const int* in_sizes, int n_in,
                              void* d_out, int out_size, void* d_ws, size_t ws_size,
                              hipStream_t stream){
  const float* enc    = (const float*)d_in[0];
  const float* target = (const float*)d_in[1];
  const float* pw     = (const float*)d_in[2];
  const float* pb     = (const float*)d_in[3];
  const float* wih0   = (const float*)d_in[4];
  const float* whh0   = (const float*)d_in[5];
  const float* bih0   = (const float*)d_in[6];
  const float* bhh0   = (const float*)d_in[7];
  const float* wih1   = (const float*)d_in[8];
  const float* whh1   = (const float*)d_in[9];
  const float* bih1   = (const float*)d_in[10];
  const float* bhh1   = (const float*)d_in[11];
  const float* lw     = (const float*)d_in[12];
  const float* lb     = (const float*)d_in[13];
  float* out = (float*)d_out;

  float* ws   = (float*)d_ws;
  float* xg0  = ws;                              // 6,553,600 f
  float* P    = xg0 + (long)T*G4*B;              // 204,800 f
  float* encp = P + T*E*B;                       // 4,096 f
  float* H1Tmk = encp + B*E;                     // MROWS*1024 = 1,703,936 f (fallback)
  unsigned* Abf = (unsigned*)(H1Tmk + (long)MROWS*1024);  // 851,968 u32
  unsigned* h0A2 = Abf + 851968;                 // 16,384 each (64KB f16 state)
  unsigned* h0B2 = h0A2 + 16384;
  unsigned* h1A2 = h0B2 + 16384;
  unsigned* h1B2 = h1A2 + 16384;
  float* fh0a = (float*)(h1B2 + 16384);          // fallback f32 state
  float* fh0b = fh0a + H*B;
  float* fh1a = fh0b + H*B;
  float* fh1b = fh1a + H*B;
  float* fc0  = fh1b + H*B;
  float* fc1  = fc0 + H*B;
  unsigned* bar = (unsigned*)(fc1 + H*B);        // 8,192 u32 (slots spread)
  unsigned* lwsw = bar + 8192;                   // 16,384,000 u32
  size_t need = (size_t)((char*)(lwsw + 16384000) - (char*)d_ws);
  bool pre = (ws_size >= need);

  k_encp<<<B, E, 0, stream>>>(enc, pw, pb, encp);
  k_proj<<<T*B, E, 0, stream>>>(target, pw, encp, P);
  k_xg0<<<(T*G4*B)/256, 256, 0, stream>>>(wih0, bih0, bhh0, P, xg0);
  k_zero32<<<32, 256, 0, stream>>>(bar);
  if (pre) k_cvtw<<<16000, 256, 0, stream>>>(lw, (uint4*)lwsw);

  void* cargs[] = {(void*)&whh0, (void*)&wih1, (void*)&whh1, (void*)&bih1, (void*)&bhh1,
                   (void*)&enc, (void*)&xg0,
                   (void*)&h0A2, (void*)&h0B2, (void*)&h1A2, (void*)&h1B2,
                   (void*)&Abf, (void*)&bar};
  hipError_t cerr = hipLaunchCooperativeKernel((void*)k_cells, dim3(NB), dim3(1024),
                                               cargs, 0, stream);
  if (cerr != hipSuccess){
    k_init<<<(H*B)/256, 256, 0, stream>>>(enc, fh0a, fc0, fh1a, fc1);
    float* h0in=fh0a; float* h0out=fh0b;
    float* h1in=fh1a; float* h1out=fh1b;
    for (int t=0;t<T;t++){
      k_cell0<<<256, 256, 0, stream>>>(whh0, xg0 + (long)t*G4*B, h0in, h0out, fc0);
      k_cell1<<<256, 256, 0, stream>>>(wih1, whh1, bih1, bhh1, h0out, h1in, h1out, fc1,
                                       H1Tmk, t);
      float* tmp;
      tmp=h0in; h0in=h0out; h0out=tmp;
      tmp=h1in; h1in=h1out; h1out=tmp;
    }
    k_pack<<<800, 256, 0, stream>>>(H1Tmk, (uint4*)Abf);
  }

  if (pre) k_gemm_pre<<<3250, 256, 0, stream>>>((const uint4*)Abf, (const uint4*)lwsw, lb, out);
  else     k_gemm_inl<<<3250, 256, 0, stream>>>((const uint4*)Abf, lw, lb, out);
  k_lsm<<<B*T, 256, 0, stream>>>(out);
}

// Round 19
// 1041.145 us; speedup vs baseline: 1.0267x; 1.0267x over previous
//
#include <hip/hip_runtime.h>
#include <hip/hip_bf16.h>
#include <math.h>

#define B 32
#define T 50
#define H 1024
#define E 128
#define V 32000
#define G4 4096   // 4*H
#define HE 1152   // H+E
#define MROWS 1664 // 13*128 padded M for GEMM
#define NB 256    // coop grid blocks

typedef __fp16 half2v __attribute__((ext_vector_type(2)));
typedef __fp16 half8 __attribute__((ext_vector_type(8)));
typedef unsigned long long ull;
union U32H2 { unsigned u; half2v h; };
union U4H8 { uint4 u4; half8 h8; };
typedef short short8 __attribute__((ext_vector_type(8)));
typedef float floatx4 __attribute__((ext_vector_type(4)));
union U16S8 { uint4 u4; short8 s8; };

// 16B LLC-coherent load (bypass L1+L2), issue-only; pair with one vmcnt wait.
#define LLC_LOAD(dst, ptr) \
  asm volatile("global_load_dwordx4 %0, %1, off sc0 sc1" : "=v"((dst).u4) : "v"(ptr))

__device__ __forceinline__ float sigm(float x){ return 1.0f/(1.0f+expf(-x)); }

__device__ __forceinline__ half2v pk2(float a, float b){
#if __has_builtin(__builtin_amdgcn_cvt_pkrtz)
  return __builtin_amdgcn_cvt_pkrtz(a, b);
#else
  half2v r; r.x = (__fp16)a; r.y = (__fp16)b; return r;
#endif
}

// pack two f32 -> one u32 of two bf16 (RNE)
__device__ __forceinline__ unsigned pkbf(float a, float b){
  unsigned ua = __float_as_uint(a), ub = __float_as_uint(b);
  unsigned ra = (ua + 0x7FFFu + ((ua>>16)&1u)) >> 16;
  unsigned rb = (ub + 0x7FFFu + ((ub>>16)&1u)) >> 16;
  return ra | (rb << 16);
}

// agent-scope store, 8B (bypasses caches, lands at LLC)
__device__ __forceinline__ void stA8(void* p, uint2 v){
  ull q = ((ull)v.y << 32) | (ull)v.x;
  __hip_atomic_store((ull*)p, q, __ATOMIC_RELAXED, __HIP_MEMORY_SCOPE_AGENT);
}

// ---- fence-free tree grid barrier (8 leaves x 32 + root) — round-17 verified ----
__device__ __forceinline__ void gbar(unsigned* bar, unsigned ep){
  __syncthreads();
  if (threadIdx.x == 0){
    asm volatile("s_waitcnt vmcnt(0)" ::: "memory");
    unsigned g = blockIdx.x & 7u;
    unsigned old = __hip_atomic_fetch_add(&bar[64 + g*64], 1u,
                     __ATOMIC_RELAXED, __HIP_MEMORY_SCOPE_AGENT);
    if (old == ep*32u - 1u)
      __hip_atomic_fetch_add(&bar[0], 1u, __ATOMIC_RELAXED, __HIP_MEMORY_SCOPE_AGENT);
    while (__hip_atomic_load(&bar[0], __ATOMIC_RELAXED, __HIP_MEMORY_SCOPE_AGENT) < ep*8u)
      __builtin_amdgcn_s_sleep(1);
  }
  __syncthreads();
}

// encp[b][e] = proj_b[e] + sum_j enc[b][j] * proj_w[e][E+j]
__global__ void k_encp(const float* __restrict__ enc, const float* __restrict__ pw,
                       const float* __restrict__ pb, float* __restrict__ encp){
  int b = blockIdx.x, e = threadIdx.x;
  const float* er = enc + b*H;
  const float* wr = pw + e*HE + E;
  float acc = pb[e];
  for (int j=0;j<H;j+=4){
    float4 w4 = *(const float4*)(wr+j);
    float4 e4 = *(const float4*)(er+j);
    acc += w4.x*e4.x + w4.y*e4.y + w4.z*e4.z + w4.w*e4.w;
  }
  encp[b*E+e] = acc;
}

// P[t][e][b] = encp[b][e] + sum_j target[b][t][j] * proj_w[e][j]
__global__ void k_proj(const float* __restrict__ target, const float* __restrict__ pw,
                       const float* __restrict__ encp, float* __restrict__ P){
  int t = blockIdx.x / B, b = blockIdx.x % B, e = threadIdx.x;
  const float* xr = target + (b*T + t)*E;
  const float* wr = pw + e*HE;
  float acc = encp[b*E+e];
  for (int j=0;j<E;j+=4){
    float4 w4 = *(const float4*)(wr+j);
    float4 x4 = *(const float4*)(xr+j);
    acc += w4.x*x4.x + w4.y*x4.y + w4.z*x4.z + w4.w*x4.w;
  }
  P[(t*E + e)*B + b] = acc;
}

// xg0[t][r][b] = b_ih0[r]+b_hh0[r] + sum_e w_ih0[r][e] * P[t][e][b]
// w loaded as float4 (4x fewer load instrs); P reads stay b-coalesced scalars.
__global__ void k_xg0(const float* __restrict__ wih0, const float* __restrict__ bih0,
                      const float* __restrict__ bhh0, const float* __restrict__ P,
                      float* __restrict__ xg){
  int idx = blockIdx.x*256 + threadIdx.x;
  int b = idx & 31; int r = (idx >> 5) & 4095; int t = idx >> 17;
  const float* wr = wih0 + r*E;
  const float* pr = P + t*E*B + b;
  float acc = bih0[r] + bhh0[r];
  #pragma unroll 8
  for (int e=0;e<E;e+=4){
    float4 w4 = *(const float4*)(wr+e);
    acc += w4.x*pr[(e+0)*B] + w4.y*pr[(e+1)*B]
         + w4.z*pr[(e+2)*B] + w4.w*pr[(e+3)*B];
  }
  xg[idx] = acc;
}

__global__ void k_zero32(unsigned* __restrict__ p){
  p[blockIdx.x*256 + threadIdx.x] = 0u;
}

// convert lw f32 -> bf16 in the GEMM's swizzled tile layout
__global__ void k_cvtw(const float* __restrict__ lw, uint4* __restrict__ wsw){
  int gid = blockIdx.x*256 + threadIdx.x;   // 4,096,000
  int n = gid >> 7, rem = gid & 127;
  int k0c = rem >> 3, seg = rem & 7;
  const float4* src = (const float4*)(lw + (long)n*H + k0c*64 + seg*8);
  float4 v0 = src[0], v1 = src[1];
  uint4 pk;
  pk.x = pkbf(v0.x, v0.y); pk.y = pkbf(v0.z, v0.w);
  pk.z = pkbf(v1.x, v1.y); pk.w = pkbf(v1.z, v1.w);
  int bn = n >> 7, row = n & 127;
  wsw[((long)(bn*16 + k0c)*128 + row)*8 + (seg ^ (row & 7))] = pk;
}

// pack H1Tmk f32 [m][k] -> Abf swizzled bf16 tiles (fallback path only)
__global__ void k_pack(const float* __restrict__ H1Tmk, uint4* __restrict__ Abf){
  int gid = blockIdx.x*256 + threadIdx.x;   // 204,800
  int m = gid >> 7, rem = gid & 127;
  int k0c = rem >> 3, seg = rem & 7;
  const float4* src = (const float4*)(H1Tmk + (long)m*1024 + k0c*64 + seg*8);
  float4 v0 = src[0], v1 = src[1];
  uint4 pk;
  pk.x = pkbf(v0.x, v0.y); pk.y = pkbf(v0.z, v0.w);
  pk.z = pkbf(v1.x, v1.y); pk.w = pkbf(v1.z, v1.w);
  int bm = m >> 7, row = m & 127;
  Abf[((long)(bm*16 + k0c)*128 + row)*8 + (seg ^ (row & 7))] = pk;
}

// ---------------- cooperative persistent cells (v12 = v10 + r17 barrier) ----------------
__global__ __launch_bounds__(1024, 4) void k_cells(
    const float* __restrict__ whh0, const float* __restrict__ wih1, const float* __restrict__ whh1,
    const float* __restrict__ bih1, const float* __restrict__ bhh1,
    const float* __restrict__ enc, const float* __restrict__ xg0,
    unsigned* __restrict__ h0A2, unsigned* __restrict__ h0B2,
    unsigned* __restrict__ h1A2, unsigned* __restrict__ h1B2,
    unsigned* __restrict__ Abf, unsigned* __restrict__ bar){
  const int gB = blockIdx.x;
  const int tid = threadIdx.x;
  const int w = tid >> 6;       // wave 0..15 = k-chunk owner
  const int l = tid & 63;
  const int lrow = l & 15;      // fragment row/col
  const int lk = l >> 4;        // k-segment 0..3

  __shared__ uint4 w0s4[16*128];        // layer0 whh0 rows, f16 swizzled (32 KB)
  __shared__ uint4 w1s4[32*128];        // wih1(0-15)+whh1(16-31) (64 KB)
  __shared__ float partial[16][16][34]; // [wave][row][b-col] pad 34
  __shared__ float gates[16][32];
  __shared__ float cst[2][4][32];
  __shared__ float bs1v[16];
  __shared__ __fp16 h1loc[4][1600];     // [hl][b*T+t] (12.8 KB)

  // ---- stage weights f32 -> f16, XOR-swizzled segments ----
  for (int i = tid; i < 2048; i += 1024){
    int row = i >> 7, seg = i & 127;
    int q = row >> 2, hl = row & 3;
    const float* src = whh0 + ((long)q*H + 4*gB + hl)*H + seg*8;
    float4 v0 = *(const float4*)src, v1 = *(const float4*)(src+4);
    U32H2 z0,z1,z2,z3;
    z0.h = pk2(v0.x,v0.y); z1.h = pk2(v0.z,v0.w);
    z2.h = pk2(v1.x,v1.y); z3.h = pk2(v1.z,v1.w);
    uint4 pk; pk.x=z0.u; pk.y=z1.u; pk.z=z2.u; pk.w=z3.u;
    int phys = (seg & ~7) | ((seg & 7) ^ (row & 7));
    w0s4[row*128 + phys] = pk;
  }
  for (int i = tid; i < 4096; i += 1024){
    int row = i >> 7, seg = i & 127;
    int rr = row & 15;
    int q = rr >> 2, hl = rr & 3;
    const float* srcm = (row < 16) ? wih1 : whh1;
    const float* src = srcm + ((long)q*H + 4*gB + hl)*H + seg*8;
    float4 v0 = *(const float4*)src, v1 = *(const float4*)(src+4);
    U32H2 z0,z1,z2,z3;
    z0.h = pk2(v0.x,v0.y); z1.h = pk2(v0.z,v0.w);
    z2.h = pk2(v1.x,v1.y); z3.h = pk2(v1.z,v1.w);
    uint4 pk; pk.x=z0.u; pk.y=z1.u; pk.z=z2.u; pk.w=z3.u;
    int phys = (seg & ~7) | ((seg & 7) ^ (rr & 7));
    w1s4[row*128 + phys] = pk;
  }
  if (tid < 16){
    int q = tid >> 2, hl = tid & 3;
    bs1v[tid] = bih1[q*H + 4*gB + hl] + bhh1[q*H + 4*gB + hl];
  }
  if (tid < 128){
    int hl = tid >> 5, bb = tid & 31;
    float v = enc[bb*H + 4*gB + hl];
    cst[0][hl][bb] = v; cst[1][hl][bb] = v;
  }
  if (tid < 32){
    int bb = tid;
    U32H2 z0, z1;
    z0.h = pk2(enc[bb*H + 4*gB + 0], enc[bb*H + 4*gB + 1]);
    z1.h = pk2(enc[bb*H + 4*gB + 2], enc[bb*H + 4*gB + 3]);
    uint2 val; val.x = z0.u; val.y = z1.u;
    stA8((char*)h0A2 + (long)(bb*1024 + 4*gB)*2, val);
    stA8((char*)h1A2 + (long)(bb*1024 + 4*gB)*2, val);
  }
  unsigned ep = 1;
  gbar(bar, ep); ep++;

  for (int p = 0; p <= T; p++){
    const unsigned* h0r = (p & 1) ? h0B2 : h0A2;
    unsigned*       h0w = (p & 1) ? h0A2 : h0B2;
    const unsigned* h1r = (p & 1) ? h1A2 : h1B2;
    unsigned*       h1w = (p & 1) ? h1B2 : h1A2;

    // ---- batched LLC state loads (issue all, wait once) ----
    int c = (w + gB + p) & 15;
    U4H8 b0a0, b0a1, b0b0, b0b1, b1a0, b1a1, b1b0, b1b1;
    {
      int kb = c*64;
      const __fp16* h0f = (const __fp16*)h0r;
      const __fp16* h1f = (const __fp16*)h1r;
      const __fp16* s0a = h0f + lrow*1024 + kb + lk*8;
      const __fp16* s0b = h0f + (16+lrow)*1024 + kb + lk*8;
      LLC_LOAD(b0a0, s0a);      LLC_LOAD(b0a1, s0a + 32);
      LLC_LOAD(b0b0, s0b);      LLC_LOAD(b0b1, s0b + 32);
      if (p >= 1){
        const __fp16* s1a = h1f + lrow*1024 + kb + lk*8;
        const __fp16* s1b = h1f + (16+lrow)*1024 + kb + lk*8;
        LLC_LOAD(b1a0, s1a);    LLC_LOAD(b1a1, s1a + 32);
        LLC_LOAD(b1b0, s1b);    LLC_LOAD(b1b1, s1b + 32);
      }
      asm volatile("s_waitcnt vmcnt(0)" ::: "memory");
      __builtin_amdgcn_sched_barrier(0);
    }

    // xg prefetch for layer0(p) — issued after the state-wait, overlaps MFMAs
    float xgv = 0.f;
    if (p < T && tid < 512){
      int r = tid >> 5, bb = tid & 31;
      int q = r >> 2, hl = r & 3;
      xgv = xg0[((long)p*G4 + (long)q*H + 4*gB + hl)*32 + bb];
    }

    // ---- MFMA matvec ----
    floatx4 acc10 = {0,0,0,0}, acc11 = {0,0,0,0};
    floatx4 acc00 = {0,0,0,0}, acc01 = {0,0,0,0};
    #pragma unroll
    for (int ks = 0; ks < 2; ks++){
      int phys = c*8 + (((ks<<2) + lk) ^ (lrow & 7));
      half8 B0a = ks ? b0a1.h8 : b0a0.h8;
      half8 B0b = ks ? b0b1.h8 : b0b0.h8;
      if (p < T){
        U4H8 a0v; a0v.u4 = w0s4[lrow*128 + phys];
        acc00 = __builtin_amdgcn_mfma_f32_16x16x32_f16(a0v.h8, B0a, acc00, 0, 0, 0);
        acc01 = __builtin_amdgcn_mfma_f32_16x16x32_f16(a0v.h8, B0b, acc01, 0, 0, 0);
      }
      if (p >= 1){
        U4H8 a1i; a1i.u4 = w1s4[lrow*128 + phys];
        U4H8 a1h; a1h.u4 = w1s4[(16+lrow)*128 + phys];
        half8 B1a = ks ? b1a1.h8 : b1a0.h8;
        half8 B1b = ks ? b1b1.h8 : b1b0.h8;
        acc10 = __builtin_amdgcn_mfma_f32_16x16x32_f16(a1i.h8, B0a, acc10, 0, 0, 0);
        acc10 = __builtin_amdgcn_mfma_f32_16x16x32_f16(a1h.h8, B1a, acc10, 0, 0, 0);
        acc11 = __builtin_amdgcn_mfma_f32_16x16x32_f16(a1i.h8, B0b, acc11, 0, 0, 0);
        acc11 = __builtin_amdgcn_mfma_f32_16x16x32_f16(a1h.h8, B1b, acc11, 0, 0, 0);
      }
    }
    if (p >= 1){
      #pragma unroll
      for (int r = 0; r < 4; r++){
        partial[w][lk*4 + r][lrow]      = acc10[r];
        partial[w][lk*4 + r][16 + lrow] = acc11[r];
      }
    }
    __syncthreads();
    // ---- layer1(p-1) reduce + cell ----
    if (p >= 1 && tid < 512){
      int r = tid >> 5, bb = tid & 31;
      float s = 0.f;
      #pragma unroll
      for (int w2 = 0; w2 < 16; w2++) s += partial[w2][r][bb];
      float v = s + bs1v[r];
      gates[r][bb] = ((r >> 2) == 2) ? tanhf(v) : sigm(v);
    }
    __syncthreads();
    if (p >= 1 && tid < 32){
      int bb = tid, t1 = p - 1;
      float hn[4];
      #pragma unroll
      for (int hl = 0; hl < 4; hl++){
        float cn = gates[4+hl][bb]*cst[1][hl][bb] + gates[0+hl][bb]*gates[8+hl][bb];
        cst[1][hl][bb] = cn;
        hn[hl] = gates[12+hl][bb]*tanhf(cn);
        h1loc[hl][bb*T + t1] = (__fp16)hn[hl];
      }
      U32H2 z0, z1; z0.h = pk2(hn[0], hn[1]); z1.h = pk2(hn[2], hn[3]);
      uint2 val; val.x = z0.u; val.y = z1.u;
      stA8((char*)h1w + (long)(bb*1024 + 4*gB)*2, val);
    }
    // ---- layer0(p) partial stash ----
    if (p < T){
      #pragma unroll
      for (int r = 0; r < 4; r++){
        partial[w][lk*4 + r][lrow]      = acc00[r];
        partial[w][lk*4 + r][16 + lrow] = acc01[r];
      }
    }
    __syncthreads();
    if (p < T && tid < 512){
      int r = tid >> 5, bb = tid & 31;
      float s = 0.f;
      #pragma unroll
      for (int w2 = 0; w2 < 16; w2++) s += partial[w2][r][bb];
      float v = s + xgv;
      gates[r][bb] = ((r >> 2) == 2) ? tanhf(v) : sigm(v);
    }
    __syncthreads();
    if (p < T && tid < 32){
      int bb = tid;
      float hn[4];
      #pragma unroll
      for (int hl = 0; hl < 4; hl++){
        float cn = gates[4+hl][bb]*cst[0][hl][bb] + gates[0+hl][bb]*gates[8+hl][bb];
        cst[0][hl][bb] = cn;
        hn[hl] = gates[12+hl][bb]*tanhf(cn);
      }
      U32H2 z0, z1; z0.h = pk2(hn[0], hn[1]); z1.h = pk2(hn[2], hn[3]);
      uint2 val; val.x = z0.u; val.y = z1.u;
      stA8((char*)h0w + (long)(bb*1024 + 4*gB)*2, val);
    }
    gbar(bar, ep); ep++;
  }

  // direct swizzled-Abf flush: block gB owns k = 4gB..4gB+3 (8B half-slot)
  {
    int k0c = gB >> 4;
    int seg = (gB & 15) >> 1;
    int posb = (gB & 1) * 8;
    for (int m = tid; m < B*T; m += 1024){
      float v0 = (float)h1loc[0][m], v1 = (float)h1loc[1][m];
      float v2 = (float)h1loc[2][m], v3 = (float)h1loc[3][m];
      int bm = m >> 7, row = m & 127;
      long slot = ((long)(bm*16 + k0c)*128 + row)*8 + (seg ^ (row & 7));
      uint2 val; val.x = pkbf(v0, v1); val.y = pkbf(v2, v3);
      *(uint2*)((char*)Abf + slot*16 + posb) = val;
    }
  }
}

// ---------------- fallback per-step cells ----------------
__global__ void k_init(const float* __restrict__ enc, float* __restrict__ h0, float* __restrict__ c0,
                       float* __restrict__ h1, float* __restrict__ c1){
  int idx = blockIdx.x*256 + threadIdx.x;
  int b = idx & 31, h = idx >> 5;
  float v = enc[b*H + h];
  h0[idx]=v; c0[idx]=v; h1[idx]=v; c1[idx]=v;
}

__global__ __launch_bounds__(256) void k_cell0(const float* __restrict__ whh, const float* __restrict__ xg_t,
                       const float* __restrict__ h_in, float* __restrict__ h_out,
                       float* __restrict__ c){
  int h = (blockIdx.x*256 + threadIdx.x) >> 6;
  int lane = threadIdx.x & 63;
  int b = lane & 31, kh = lane >> 5;
  const float* w0 = whh + (0*H + h)*H + kh*512;
  const float* w1 = whh + (1*H + h)*H + kh*512;
  const float* w2 = whh + (2*H + h)*H + kh*512;
  const float* w3 = whh + (3*H + h)*H + kh*512;
  const float* hk = h_in + (kh*512)*B + b;
  float a0=0,a1=0,a2=0,a3=0, p0=0,p1=0,p2=0,p3=0;
  #pragma unroll 4
  for (int k=0;k<512;k+=4){
    float4 w40 = *(const float4*)(w0+k);
    float4 w41 = *(const float4*)(w1+k);
    float4 w42 = *(const float4*)(w2+k);
    float4 w43 = *(const float4*)(w3+k);
    float hv0 = hk[(k+0)*B], hv1 = hk[(k+1)*B], hv2 = hk[(k+2)*B], hv3 = hk[(k+3)*B];
    a0 += w40.x*hv0 + w40.y*hv1;  p0 += w40.z*hv2 + w40.w*hv3;
    a1 += w41.x*hv0 + w41.y*hv1;  p1 += w41.z*hv2 + w41.w*hv3;
    a2 += w42.x*hv0 + w42.y*hv1;  p2 += w42.z*hv2 + w42.w*hv3;
    a3 += w43.x*hv0 + w43.y*hv1;  p3 += w43.z*hv2 + w43.w*hv3;
  }
  float g0=a0+p0, g1=a1+p1, g2=a2+p2, g3=a3+p3;
  g0 += __shfl_xor(g0, 32);
  g1 += __shfl_xor(g1, 32);
  g2 += __shfl_xor(g2, 32);
  g3 += __shfl_xor(g3, 32);
  g0 += xg_t[(0*H+h)*B + b];
  g1 += xg_t[(1*H+h)*B + b];
  g2 += xg_t[(2*H+h)*B + b];
  g3 += xg_t[(3*H+h)*B + b];
  float ig = sigm(g0), fg = sigm(g1), gg = tanhf(g2), og = sigm(g3);
  int sidx = h*B + b;
  float cn = fg*c[sidx] + ig*gg;
  float hn = og*tanhf(cn);
  if (kh==0){ c[sidx]=cn; h_out[sidx]=hn; }
}

__global__ __launch_bounds__(256) void k_cell1(const float* __restrict__ wih, const float* __restrict__ whh,
                       const float* __restrict__ bih, const float* __restrict__ bhh,
                       const float* __restrict__ h0n, const float* __restrict__ h_in,
                       float* __restrict__ h_out, float* __restrict__ c,
                       float* __restrict__ H1Tmk, int t){
  int h = (blockIdx.x*256 + threadIdx.x) >> 6;
  int lane = threadIdx.x & 63;
  int b = lane & 31, kh = lane >> 5;
  float a0=0,a1=0,a2=0,a3=0, p0=0,p1=0,p2=0,p3=0;
  {
    const float* w0 = wih + (0*H + h)*H + kh*512;
    const float* w1 = wih + (1*H + h)*H + kh*512;
    const float* w2 = wih + (2*H + h)*H + kh*512;
    const float* w3 = wih + (3*H + h)*H + kh*512;
    const float* hk = h0n + (kh*512)*B + b;
    #pragma unroll 4
    for (int k=0;k<512;k+=4){
      float4 w40 = *(const float4*)(w0+k);
      float4 w41 = *(const float4*)(w1+k);
      float4 w42 = *(const float4*)(w2+k);
      float4 w43 = *(const float4*)(w3+k);
      float hv0 = hk[(k+0)*B], hv1 = hk[(k+1)*B], hv2 = hk[(k+2)*B], hv3 = hk[(k+3)*B];
      a0 += w40.x*hv0 + w40.y*hv1;  p0 += w40.z*hv2 + w40.w*hv3;
      a1 += w41.x*hv0 + w41.y*hv1;  p1 += w41.z*hv2 + w41.w*hv3;
      a2 += w42.x*hv0 + w42.y*hv1;  p2 += w42.z*hv2 + w42.w*hv3;
      a3 += w43.x*hv0 + w43.y*hv1;  p3 += w43.z*hv2 + w43.w*hv3;
    }
  }
  {
    const float* w0 = whh + (0*H + h)*H + kh*512;
    const float* w1 = whh + (1*H + h)*H + kh*512;
    const float* w2 = whh + (2*H + h)*H + kh*512;
    const float* w3 = whh + (3*H + h)*H + kh*512;
    const float* hk = h_in + (kh*512)*B + b;
    #pragma unroll 4
    for (int k=0;k<512;k+=4){
      float4 w40 = *(const float4*)(w0+k);
      float4 w41 = *(const float4*)(w1+k);
      float4 w42 = *(const float4*)(w2+k);
      float4 w43 = *(const float4*)(w3+k);
      float hv0 = hk[(k+0)*B], hv1 = hk[(k+1)*B], hv2 = hk[(k+2)*B], hv3 = hk[(k+3)*B];
      a0 += w40.x*hv0 + w40.y*hv1;  p0 += w40.z*hv2 + w40.w*hv3;
      a1 += w41.x*hv0 + w41.y*hv1;  p1 += w41.z*hv2 + w41.w*hv3;
      a2 += w42.x*hv0 + w42.y*hv1;  p2 += w42.z*hv2 + w42.w*hv3;
      a3 += w43.x*hv0 + w43.y*hv1;  p3 += w43.z*hv2 + w43.w*hv3;
    }
  }
  float g0=a0+p0, g1=a1+p1, g2=a2+p2, g3=a3+p3;
  g0 += __shfl_xor(g0, 32);
  g1 += __shfl_xor(g1, 32);
  g2 += __shfl_xor(g2, 32);
  g3 += __shfl_xor(g3, 32);
  g0 += bih[0*H+h] + bhh[0*H+h];
  g1 += bih[1*H+h] + bhh[1*H+h];
  g2 += bih[2*H+h] + bhh[2*H+h];
  g3 += bih[3*H+h] + bhh[3*H+h];
  float ig = sigm(g0), fg = sigm(g1), gg = tanhf(g2), og = sigm(g3);
  int sidx = h*B + b;
  float cn = fg*c[sidx] + ig*gg;
  float hn = og*tanhf(cn);
  if (kh==0){ c[sidx]=cn; h_out[sidx]=hn; H1Tmk[((long)(b*T + t))*1024 + h] = hn; }
}

// ---------------- MFMA bf16 output GEMM (pre-swizzled operands) ----------------
__global__ __launch_bounds__(256, 2) void k_gemm_pre(const uint4* __restrict__ Abf4,
                      const uint4* __restrict__ Wsw4, const float* __restrict__ lb,
                      float* __restrict__ out){
  __shared__ uint4 As4[1024];
  __shared__ uint4 Ws4[1024];
  const int tid = threadIdx.x;
  int orig = blockIdx.x;
  int xcd = orig & 7, ii = orig >> 3;
  int wgid = (xcd < 2 ? xcd*407 : 814 + (xcd-2)*406) + ii;
  int bm = wgid % 13, bn = wgid / 13;
  int m0 = bm*128, n0 = bn*128;
  const int wv = tid >> 6, l = tid & 63;
  const int wm = (wv >> 1)*64, wn = (wv & 1)*64;
  const int lrow = l & 15, lk = l >> 4;

  floatx4 acc[4][4] = {};
  for (int k0c = 0; k0c < 16; k0c++){
    const uint4* sA = Abf4 + (long)(bm*16 + k0c)*1024;
    const uint4* sW = Wsw4 + (long)(bn*16 + k0c)*1024;
    #pragma unroll
    for (int it = 0; it < 4; it++){
      int slot = tid + it*256;
      As4[slot] = sA[slot];
      Ws4[slot] = sW[slot];
    }
    __syncthreads();
    #pragma unroll
    for (int ks = 0; ks < 2; ks++){
      short8 af[4], bf_[4];
      #pragma unroll
      for (int fi = 0; fi < 4; fi++){
        int row = wm + fi*16 + lrow;
        U16S8 u; u.u4 = As4[row*8 + ((ks*4 + lk) ^ (lrow & 7))];
        af[fi] = u.s8;
      }
      #pragma unroll
      for (int fj = 0; fj < 4; fj++){
        int row = wn + fj*16 + lrow;
        U16S8 u; u.u4 = Ws4[row*8 + ((ks*4 + lk) ^ (lrow & 7))];
        bf_[fj] = u.s8;
      }
      #pragma unroll
      for (int fi = 0; fi < 4; fi++)
        #pragma unroll
        for (int fj = 0; fj < 4; fj++)
          acc[fi][fj] = __builtin_amdgcn_mfma_f32_16x16x32_bf16(af[fi], bf_[fj], acc[fi][fj], 0, 0, 0);
    }
    __syncthreads();
  }
  #pragma unroll
  for (int fj = 0; fj < 4; fj++){
    int n = n0 + wn + fj*16 + lrow;
    float bias = lb[n];
    #pragma unroll
    for (int fi = 0; fi < 4; fi++){
      floatx4 av = acc[fi][fj];
      int mb = m0 + wm + fi*16 + lk*4;
      #pragma unroll
      for (int r = 0; r < 4; r++){
        int m = mb + r;
        if (m < B*T) out[(long)m*V + n] = av[r] + bias;
      }
    }
  }
}

// fallback GEMM: A pre-swizzled, W converted inline from f32
__global__ __launch_bounds__(256, 2) void k_gemm_inl(const uint4* __restrict__ Abf4,
                      const float* __restrict__ lw, const float* __restrict__ lb,
                      float* __restrict__ out){
  __shared__ uint4 As4[1024];
  __shared__ uint4 Ws4[1024];
  const int tid = threadIdx.x;
  int orig = blockIdx.x;
  int xcd = orig & 7, ii = orig >> 3;
  int wgid = (xcd < 2 ? xcd*407 : 814 + (xcd-2)*406) + ii;
  int bm = wgid % 13, bn = wgid / 13;
  int m0 = bm*128, n0 = bn*128;
  const int wv = tid >> 6, l = tid & 63;
  const int wm = (wv >> 1)*64, wn = (wv & 1)*64;
  const int lrow = l & 15, lk = l >> 4;

  floatx4 acc[4][4] = {};
  for (int k0c = 0; k0c < 16; k0c++){
    const uint4* sA = Abf4 + (long)(bm*16 + k0c)*1024;
    #pragma unroll
    for (int it = 0; it < 4; it++){
      int slot = tid + it*256;
      As4[slot] = sA[slot];
      int row = slot >> 3, seg = slot & 7;
      const float4* src = (const float4*)(lw + (long)(n0+row)*H + k0c*64 + seg*8);
      float4 v0 = src[0], v1 = src[1];
      uint4 pk;
      pk.x = pkbf(v0.x, v0.y); pk.y = pkbf(v0.z, v0.w);
      pk.z = pkbf(v1.x, v1.y); pk.w = pkbf(v1.z, v1.w);
      Ws4[row*8 + (seg ^ (row & 7))] = pk;
    }
    __syncthreads();
    #pragma unroll
    for (int ks = 0; ks < 2; ks++){
      short8 af[4], bf_[4];
      #pragma unroll
      for (int fi = 0; fi < 4; fi++){
        int row = wm + fi*16 + lrow;
        U16S8 u; u.u4 = As4[row*8 + ((ks*4 + lk) ^ (lrow & 7))];
        af[fi] = u.s8;
      }
      #pragma unroll
      for (int fj = 0; fj < 4; fj++){
        int row = wn + fj*16 + lrow;
        U16S8 u; u.u4 = Ws4[row*8 + ((ks*4 + lk) ^ (lrow & 7))];
        bf_[fj] = u.s8;
      }
      #pragma unroll
      for (int fi = 0; fi < 4; fi++)
        #pragma unroll
        for (int fj = 0; fj < 4; fj++)
          acc[fi][fj] = __builtin_amdgcn_mfma_f32_16x16x32_bf16(af[fi], bf_[fj], acc[fi][fj], 0, 0, 0);
    }
    __syncthreads();
  }
  #pragma unroll
  for (int fj = 0; fj < 4; fj++){
    int n = n0 + wn + fj*16 + lrow;
    float bias = lb[n];
    #pragma unroll
    for (int fi = 0; fi < 4; fi++){
      floatx4 av = acc[fi][fj];
      int mb = m0 + wm + fi*16 + lk*4;
      #pragma unroll
      for (int r = 0; r < 4; r++){
        int m = mb + r;
        if (m < B*T) out[(long)m*V + n] = av[r] + bias;
      }
    }
  }
}

// online 2-pass log-softmax
__global__ __launch_bounds__(256) void k_lsm(float* __restrict__ out){
  __shared__ float redm[256], reds[256];
  float4* row = (float4*)(out + (long)blockIdx.x * V);
  const int tid = threadIdx.x;
  float m = -INFINITY, s = 0.f;
  for (int n=tid;n<V/4;n+=256){
    float4 v = row[n];
    float cm = fmaxf(fmaxf(v.x,v.y), fmaxf(v.z,v.w));
    if (cm > m){ s *= __expf(m - cm); m = cm; }
    s += __expf(v.x-m)+__expf(v.y-m)+__expf(v.z-m)+__expf(v.w-m);
  }
  redm[tid]=m; reds[tid]=s; __syncthreads();
  for (int st=128;st>0;st>>=1){
    if (tid<st){
      float m1=redm[tid], s1=reds[tid];
      float m2=redm[tid+st], s2=reds[tid+st];
      float M=fmaxf(m1,m2);
      reds[tid]=s1*__expf(m1-M)+s2*__expf(m2-M);
      redm[tid]=M;
    }
    __syncthreads();
  }
  float lse = redm[0] + __logf(reds[0]);
  for (int n=tid;n<V/4;n+=256){
    float4 v = row[n];
    v.x-=lse; v.y-=lse; v.z-=lse; v.w-=lse;
    row[n] = v;
  }
}

extern "C" void kernel_launch(void* const* d_in, const int* in_sizes, int n_in,
                              void* d_out, int out_size, void* d_ws, size_t ws_size,
                              hipStream_t stream){
  const float* enc    = (const float*)d_in[0];
  const float* target = (const float*)d_in[1];
  const float* pw     = (const float*)d_in[2];
  const float* pb     = (const float*)d_in[3];
  const float* wih0   = (const float*)d_in[4];
  const float* whh0   = (const float*)d_in[5];
  const float* bih0   = (const float*)d_in[6];
  const float* bhh0   = (const float*)d_in[7];
  const float* wih1   = (const float*)d_in[8];
  const float* whh1   = (const float*)d_in[9];
  const float* bih1   = (const float*)d_in[10];
  const float* bhh1   = (const float*)d_in[11];
  const float* lw     = (const float*)d_in[12];
  const float* lb     = (const float*)d_in[13];
  float* out = (float*)d_out;

  float* ws   = (float*)d_ws;
  float* xg0  = ws;                              // 6,553,600 f
  float* P    = xg0 + (long)T*G4*B;              // 204,800 f
  float* encp = P + T*E*B;                       // 4,096 f
  float* H1Tmk = encp + B*E;                     // MROWS*1024 = 1,703,936 f (fallback)
  unsigned* Abf = (unsigned*)(H1Tmk + (long)MROWS*1024);  // 851,968 u32
  unsigned* h0A2 = Abf + 851968;                 // 16,384 each (64KB f16 state)
  unsigned* h0B2 = h0A2 + 16384;
  unsigned* h1A2 = h0B2 + 16384;
  unsigned* h1B2 = h1A2 + 16384;
  float* fh0a = (float*)(h1B2 + 16384);          // fallback f32 state
  float* fh0b = fh0a + H*B;
  float* fh1a = fh0b + H*B;
  float* fh1b = fh1a + H*B;
  float* fc0  = fh1b + H*B;
  float* fc1  = fc0 + H*B;
  unsigned* bar = (unsigned*)(fc1 + H*B);        // 1,024 u32
  unsigned* lwsw = bar + 1024;                   // 16,384,000 u32
  size_t need = (size_t)((char*)(lwsw + 16384000) - (char*)d_ws);
  bool pre = (ws_size >= need);

  k_encp<<<B, E, 0, stream>>>(enc, pw, pb, encp);
  k_proj<<<T*B, E, 0, stream>>>(target, pw, encp, P);
  k_xg0<<<(T*G4*B)/256, 256, 0, stream>>>(wih0, bih0, bhh0, P, xg0);
  k_zero32<<<4, 256, 0, stream>>>(bar);
  if (pre) k_cvtw<<<16000, 256, 0, stream>>>(lw, (uint4*)lwsw);

  void* cargs[] = {(void*)&whh0, (void*)&wih1, (void*)&whh1, (void*)&bih1, (void*)&bhh1,
                   (void*)&enc, (void*)&xg0,
                   (void*)&h0A2, (void*)&h0B2, (void*)&h1A2, (void*)&h1B2,
                   (void*)&Abf, (void*)&bar};
  hipError_t cerr = hipLaunchCooperativeKernel((void*)k_cells, dim3(NB), dim3(1024),
                                               cargs, 0, stream);
  if (cerr != hipSuccess){
    k_init<<<(H*B)/256, 256, 0, stream>>>(enc, fh0a, fc0, fh1a, fc1);
    float* h0in=fh0a; float* h0out=fh0b;
    float* h1in=fh1a; float* h1out=fh1b;
    for (int t=0;t<T;t++){
      k_cell0<<<256, 256, 0, stream>>>(whh0, xg0 + (long)t*G4*B, h0in, h0out, fc0);
      k_cell1<<<256, 256, 0, stream>>>(wih1, whh1, bih1, bhh1, h0out, h1in, h1out, fc1,
                                       H1Tmk, t);
      float* tmp;
      tmp=h0in; h0in=h0out; h0out=tmp;
      tmp=h1in; h1in=h1out; h1out=tmp;
    }
    k_pack<<<800, 256, 0, stream>>>(H1Tmk, (uint4*)Abf);
  }

  if (pre) k_gemm_pre<<<3250, 256, 0, stream>>>((const uint4*)Abf, (const uint4*)lwsw, lb, out);
  else     k_gemm_inl<<<3250, 256, 0, stream>>>((const uint4*)Abf, lw, lb, out);
  k_lsm<<<B*T, 256, 0, stream>>>(out);
}

// Round 20
// 842.852 us; speedup vs baseline: 1.2683x; 1.2353x over previous
//
#include <hip/hip_runtime.h>
#include <hip/hip_bf16.h>
#include <math.h>

#define B 32
#define T 50
#define H 1024
#define E 128
#define V 32000
#define G4 4096   // 4*H
#define HE 1152   // H+E
#define MROWS 1664 // 13*128 padded M for GEMM
#define NB 256    // coop grid blocks

typedef __fp16 half2v __attribute__((ext_vector_type(2)));
typedef __fp16 half8 __attribute__((ext_vector_type(8)));
typedef unsigned long long ull;
union U32H2 { unsigned u; half2v h; };
union U4H8 { uint4 u4; half8 h8; };
typedef short short8 __attribute__((ext_vector_type(8)));
typedef float floatx4 __attribute__((ext_vector_type(4)));
union U16S8 { uint4 u4; short8 s8; };

// 16B LLC-coherent load (bypass L1+L2), issue-only; pair with one vmcnt wait.
#define LLC_LOAD(dst, ptr) \
  asm volatile("global_load_dwordx4 %0, %1, off sc0 sc1" : "=v"((dst).u4) : "v"(ptr))

__device__ __forceinline__ float sigm(float x){ return 1.0f/(1.0f+expf(-x)); }

__device__ __forceinline__ half2v pk2(float a, float b){
#if __has_builtin(__builtin_amdgcn_cvt_pkrtz)
  return __builtin_amdgcn_cvt_pkrtz(a, b);
#else
  half2v r; r.x = (__fp16)a; r.y = (__fp16)b; return r;
#endif
}

// pack two f32 -> one u32 of two bf16 (RNE)
__device__ __forceinline__ unsigned pkbf(float a, float b){
  unsigned ua = __float_as_uint(a), ub = __float_as_uint(b);
  unsigned ra = (ua + 0x7FFFu + ((ua>>16)&1u)) >> 16;
  unsigned rb = (ub + 0x7FFFu + ((ub>>16)&1u)) >> 16;
  return ra | (rb << 16);
}

// agent-scope store, 8B (bypasses caches, lands at LLC)
__device__ __forceinline__ void stA8(void* p, uint2 v){
  ull q = ((ull)v.y << 32) | (ull)v.x;
  __hip_atomic_store((ull*)p, q, __ATOMIC_RELAXED, __HIP_MEMORY_SCOPE_AGENT);
}

// ---- fence-free tree grid barrier (8 leaves x 32 + root) — r17 verified ----
__device__ __forceinline__ void gbar(unsigned* bar, unsigned ep){
  __syncthreads();
  if (threadIdx.x == 0){
    asm volatile("s_waitcnt vmcnt(0)" ::: "memory");
    unsigned g = blockIdx.x & 7u;
    unsigned old = __hip_atomic_fetch_add(&bar[64 + g*64], 1u,
                     __ATOMIC_RELAXED, __HIP_MEMORY_SCOPE_AGENT);
    if (old == ep*32u - 1u)
      __hip_atomic_fetch_add(&bar[0], 1u, __ATOMIC_RELAXED, __HIP_MEMORY_SCOPE_AGENT);
    while (__hip_atomic_load(&bar[0], __ATOMIC_RELAXED, __HIP_MEMORY_SCOPE_AGENT) < ep*8u)
      __builtin_amdgcn_s_sleep(1);
  }
  __syncthreads();
}

// encp[b][e] = proj_b[e] + sum_j enc[b][j] * proj_w[e][E+j]
__global__ void k_encp(const float* __restrict__ enc, const float* __restrict__ pw,
                       const float* __restrict__ pb, float* __restrict__ encp){
  int b = blockIdx.x, e = threadIdx.x;
  const float* er = enc + b*H;
  const float* wr = pw + e*HE + E;
  float acc = pb[e];
  for (int j=0;j<H;j+=4){
    float4 w4 = *(const float4*)(wr+j);
    float4 e4 = *(const float4*)(er+j);
    acc += w4.x*e4.x + w4.y*e4.y + w4.z*e4.z + w4.w*e4.w;
  }
  encp[b*E+e] = acc;
}

// P[t][e][b] f32 (fallback) + Pf16[t][b][e] (coop MFMA B-operand)
__global__ void k_proj(const float* __restrict__ target, const float* __restrict__ pw,
                       const float* __restrict__ encp, float* __restrict__ P,
                       __fp16* __restrict__ Pf16){
  int t = blockIdx.x / B, b = blockIdx.x % B, e = threadIdx.x;
  const float* xr = target + (b*T + t)*E;
  const float* wr = pw + e*HE;
  float acc = encp[b*E+e];
  for (int j=0;j<E;j+=4){
    float4 w4 = *(const float4*)(wr+j);
    float4 x4 = *(const float4*)(xr+j);
    acc += w4.x*x4.x + w4.y*x4.y + w4.z*x4.z + w4.w*x4.w;
  }
  P[(t*E + e)*B + b] = acc;
  Pf16[((long)t*B + b)*E + e] = (__fp16)acc;
}

// xg0[t][r][b] (fallback path only)
__global__ void k_xg0(const float* __restrict__ wih0, const float* __restrict__ bih0,
                      const float* __restrict__ bhh0, const float* __restrict__ P,
                      float* __restrict__ xg){
  int idx = blockIdx.x*256 + threadIdx.x;
  int b = idx & 31; int r = (idx >> 5) & 4095; int t = idx >> 17;
  const float* wr = wih0 + r*E;
  const float* pr = P + t*E*B + b;
  float acc = bih0[r] + bhh0[r];
  #pragma unroll 8
  for (int e=0;e<E;e+=4){
    float4 w4 = *(const float4*)(wr+e);
    acc += w4.x*pr[(e+0)*B] + w4.y*pr[(e+1)*B]
         + w4.z*pr[(e+2)*B] + w4.w*pr[(e+3)*B];
  }
  xg[idx] = acc;
}

__global__ void k_zero32(unsigned* __restrict__ p){
  p[blockIdx.x*256 + threadIdx.x] = 0u;
}

// convert lw f32 -> bf16 in the GEMM's swizzled tile layout
__global__ void k_cvtw(const float* __restrict__ lw, uint4* __restrict__ wsw){
  int gid = blockIdx.x*256 + threadIdx.x;   // 4,096,000
  int n = gid >> 7, rem = gid & 127;
  int k0c = rem >> 3, seg = rem & 7;
  const float4* src = (const float4*)(lw + (long)n*H + k0c*64 + seg*8);
  float4 v0 = src[0], v1 = src[1];
  uint4 pk;
  pk.x = pkbf(v0.x, v0.y); pk.y = pkbf(v0.z, v0.w);
  pk.z = pkbf(v1.x, v1.y); pk.w = pkbf(v1.z, v1.w);
  int bn = n >> 7, row = n & 127;
  wsw[((long)(bn*16 + k0c)*128 + row)*8 + (seg ^ (row & 7))] = pk;
}

// pack H1Tmk f32 [m][k] -> Abf swizzled bf16 tiles (fallback path only)
__global__ void k_pack(const float* __restrict__ H1Tmk, uint4* __restrict__ Abf){
  int gid = blockIdx.x*256 + threadIdx.x;   // 204,800
  int m = gid >> 7, rem = gid & 127;
  int k0c = rem >> 3, seg = rem & 7;
  const float4* src = (const float4*)(H1Tmk + (long)m*1024 + k0c*64 + seg*8);
  float4 v0 = src[0], v1 = src[1];
  uint4 pk;
  pk.x = pkbf(v0.x, v0.y); pk.y = pkbf(v0.z, v0.w);
  pk.z = pkbf(v1.x, v1.y); pk.w = pkbf(v1.z, v1.w);
  int bm = m >> 7, row = m & 127;
  Abf[((long)(bm*16 + k0c)*128 + row)*8 + (seg ^ (row & 7))] = pk;
}

// ---------------- cooperative persistent cells (v13: fused xg MFMA) ----------------
__global__ __launch_bounds__(1024, 4) void k_cells(
    const float* __restrict__ whh0, const float* __restrict__ wih1, const float* __restrict__ whh1,
    const float* __restrict__ wih0, const float* __restrict__ bih0, const float* __restrict__ bhh0,
    const float* __restrict__ bih1, const float* __restrict__ bhh1,
    const float* __restrict__ enc, const __fp16* __restrict__ Pf16,
    unsigned* __restrict__ h0A2, unsigned* __restrict__ h0B2,
    unsigned* __restrict__ h1A2, unsigned* __restrict__ h1B2,
    unsigned* __restrict__ Abf, unsigned* __restrict__ bar){
  const int gB = blockIdx.x;
  const int tid = threadIdx.x;
  const int w = tid >> 6;       // wave 0..15 = k-chunk owner
  const int l = tid & 63;
  const int lrow = l & 15;      // fragment row/col
  const int lk = l >> 4;        // k-segment 0..3

  __shared__ uint4 w0s4[16*128];        // layer0 whh0 rows, f16 swizzled (32 KB)
  __shared__ uint4 w1s4[32*128];        // wih1(0-15)+whh1(16-31) (64 KB)
  __shared__ uint4 w0x4[16*16];         // layer0 wih0 rows, f16 swizzled (4 KB)
  __shared__ float partial[16][16][34]; // [wave][row][b-col] pad 34
  __shared__ float gates[16][32];
  __shared__ float cst[2][4][32];
  __shared__ float bs1v[16];
  __shared__ float bs0v[16];
  __shared__ __fp16 h1loc[4][1600];     // [hl][b*T+t] (12.8 KB)

  // ---- stage weights f32 -> f16, XOR-swizzled segments ----
  for (int i = tid; i < 2048; i += 1024){
    int row = i >> 7, seg = i & 127;
    int q = row >> 2, hl = row & 3;
    const float* src = whh0 + ((long)q*H + 4*gB + hl)*H + seg*8;
    float4 v0 = *(const float4*)src, v1 = *(const float4*)(src+4);
    U32H2 z0,z1,z2,z3;
    z0.h = pk2(v0.x,v0.y); z1.h = pk2(v0.z,v0.w);
    z2.h = pk2(v1.x,v1.y); z3.h = pk2(v1.z,v1.w);
    uint4 pk; pk.x=z0.u; pk.y=z1.u; pk.z=z2.u; pk.w=z3.u;
    int phys = (seg & ~7) | ((seg & 7) ^ (row & 7));
    w0s4[row*128 + phys] = pk;
  }
  for (int i = tid; i < 4096; i += 1024){
    int row = i >> 7, seg = i & 127;
    int rr = row & 15;
    int q = rr >> 2, hl = rr & 3;
    const float* srcm = (row < 16) ? wih1 : whh1;
    const float* src = srcm + ((long)q*H + 4*gB + hl)*H + seg*8;
    float4 v0 = *(const float4*)src, v1 = *(const float4*)(src+4);
    U32H2 z0,z1,z2,z3;
    z0.h = pk2(v0.x,v0.y); z1.h = pk2(v0.z,v0.w);
    z2.h = pk2(v1.x,v1.y); z3.h = pk2(v1.z,v1.w);
    uint4 pk; pk.x=z0.u; pk.y=z1.u; pk.z=z2.u; pk.w=z3.u;
    int phys = (seg & ~7) | ((seg & 7) ^ (rr & 7));
    w1s4[row*128 + phys] = pk;
  }
  if (tid < 256){
    int row = tid >> 4, seg = tid & 15;
    int q = row >> 2, hl = row & 3;
    const float* src = wih0 + ((long)q*H + 4*gB + hl)*E + seg*8;
    float4 v0 = *(const float4*)src, v1 = *(const float4*)(src+4);
    U32H2 z0,z1,z2,z3;
    z0.h = pk2(v0.x,v0.y); z1.h = pk2(v0.z,v0.w);
    z2.h = pk2(v1.x,v1.y); z3.h = pk2(v1.z,v1.w);
    uint4 pk; pk.x=z0.u; pk.y=z1.u; pk.z=z2.u; pk.w=z3.u;
    int phys = (seg & ~7) | ((seg & 7) ^ (row & 7));
    w0x4[row*16 + phys] = pk;
  }
  if (tid < 16){
    int q = tid >> 2, hl = tid & 3;
    bs1v[tid] = bih1[q*H + 4*gB + hl] + bhh1[q*H + 4*gB + hl];
    bs0v[tid] = bih0[q*H + 4*gB + hl] + bhh0[q*H + 4*gB + hl];
  }
  if (tid < 128){
    int hl = tid >> 5, bb = tid & 31;
    float v = enc[bb*H + 4*gB + hl];
    cst[0][hl][bb] = v; cst[1][hl][bb] = v;
  }
  if (tid < 32){
    int bb = tid;
    U32H2 z0, z1;
    z0.h = pk2(enc[bb*H + 4*gB + 0], enc[bb*H + 4*gB + 1]);
    z1.h = pk2(enc[bb*H + 4*gB + 2], enc[bb*H + 4*gB + 3]);
    uint2 val; val.x = z0.u; val.y = z1.u;
    stA8((char*)h0A2 + (long)(bb*1024 + 4*gB)*2, val);
    stA8((char*)h1A2 + (long)(bb*1024 + 4*gB)*2, val);
  }
  unsigned ep = 1;
  gbar(bar, ep); ep++;

  for (int p = 0; p <= T; p++){
    const unsigned* h0r = (p & 1) ? h0B2 : h0A2;
    unsigned*       h0w = (p & 1) ? h0A2 : h0B2;
    const unsigned* h1r = (p & 1) ? h1A2 : h1B2;
    unsigned*       h1w = (p & 1) ? h1B2 : h1A2;

    // ---- batched LLC state loads (issue all, wait once) ----
    int c = (w + gB + p) & 15;
    U4H8 b0a0, b0a1, b0b0, b0b1, b1a0, b1a1, b1b0, b1b1;
    {
      int kb = c*64;
      const __fp16* h0f = (const __fp16*)h0r;
      const __fp16* h1f = (const __fp16*)h1r;
      const __fp16* s0a = h0f + lrow*1024 + kb + lk*8;
      const __fp16* s0b = h0f + (16+lrow)*1024 + kb + lk*8;
      LLC_LOAD(b0a0, s0a);      LLC_LOAD(b0a1, s0a + 32);
      LLC_LOAD(b0b0, s0b);      LLC_LOAD(b0b1, s0b + 32);
      if (p >= 1){
        const __fp16* s1a = h1f + lrow*1024 + kb + lk*8;
        const __fp16* s1b = h1f + (16+lrow)*1024 + kb + lk*8;
        LLC_LOAD(b1a0, s1a);    LLC_LOAD(b1a1, s1a + 32);
        LLC_LOAD(b1b0, s1b);    LLC_LOAD(b1b1, s1b + 32);
      }
      asm volatile("s_waitcnt vmcnt(0)" ::: "memory");
      __builtin_amdgcn_sched_barrier(0);
    }

    // ---- MFMA matvec ----
    floatx4 acc10 = {0,0,0,0}, acc11 = {0,0,0,0};
    floatx4 acc00 = {0,0,0,0}, acc01 = {0,0,0,0};
    #pragma unroll
    for (int ks = 0; ks < 2; ks++){
      int phys = c*8 + (((ks<<2) + lk) ^ (lrow & 7));
      half8 B0a = ks ? b0a1.h8 : b0a0.h8;
      half8 B0b = ks ? b0b1.h8 : b0b0.h8;
      if (p < T){
        U4H8 a0v; a0v.u4 = w0s4[lrow*128 + phys];
        acc00 = __builtin_amdgcn_mfma_f32_16x16x32_f16(a0v.h8, B0a, acc00, 0, 0, 0);
        acc01 = __builtin_amdgcn_mfma_f32_16x16x32_f16(a0v.h8, B0b, acc01, 0, 0, 0);
      }
      if (p >= 1){
        U4H8 a1i; a1i.u4 = w1s4[lrow*128 + phys];
        U4H8 a1h; a1h.u4 = w1s4[(16+lrow)*128 + phys];
        half8 B1a = ks ? b1a1.h8 : b1a0.h8;
        half8 B1b = ks ? b1b1.h8 : b1b0.h8;
        acc10 = __builtin_amdgcn_mfma_f32_16x16x32_f16(a1i.h8, B0a, acc10, 0, 0, 0);
        acc10 = __builtin_amdgcn_mfma_f32_16x16x32_f16(a1h.h8, B1a, acc10, 0, 0, 0);
        acc11 = __builtin_amdgcn_mfma_f32_16x16x32_f16(a1i.h8, B0b, acc11, 0, 0, 0);
        acc11 = __builtin_amdgcn_mfma_f32_16x16x32_f16(a1h.h8, B1b, acc11, 0, 0, 0);
      }
    }
    // ---- fused xg contribution: waves with c<2 add wih0 . P_t ----
    if (p < T && c < 2){
      const __fp16* pbase = Pf16 + (long)p*B*E + c*64 + lk*8;
      U4H8 q0a, q1a, q0b, q1b;
      q0a.u4 = *(const uint4*)(pbase + lrow*E);
      q1a.u4 = *(const uint4*)(pbase + lrow*E + 32);
      q0b.u4 = *(const uint4*)(pbase + (16+lrow)*E);
      q1b.u4 = *(const uint4*)(pbase + (16+lrow)*E + 32);
      #pragma unroll
      for (int ks = 0; ks < 2; ks++){
        int phys = c*8 + (((ks<<2) + lk) ^ (lrow & 7));
        U4H8 aw; aw.u4 = w0x4[lrow*16 + phys];
        acc00 = __builtin_amdgcn_mfma_f32_16x16x32_f16(aw.h8, ks ? q1a.h8 : q0a.h8, acc00, 0, 0, 0);
        acc01 = __builtin_amdgcn_mfma_f32_16x16x32_f16(aw.h8, ks ? q1b.h8 : q0b.h8, acc01, 0, 0, 0);
      }
    }
    if (p >= 1){
      #pragma unroll
      for (int r = 0; r < 4; r++){
        partial[w][lk*4 + r][lrow]      = acc10[r];
        partial[w][lk*4 + r][16 + lrow] = acc11[r];
      }
    }
    __syncthreads();
    // ---- layer1(p-1) reduce + cell ----
    if (p >= 1 && tid < 512){
      int r = tid >> 5, bb = tid & 31;
      float s = 0.f;
      #pragma unroll
      for (int w2 = 0; w2 < 16; w2++) s += partial[w2][r][bb];
      float v = s + bs1v[r];
      gates[r][bb] = ((r >> 2) == 2) ? tanhf(v) : sigm(v);
    }
    __syncthreads();
    if (p >= 1 && tid < 32){
      int bb = tid, t1 = p - 1;
      float hn[4];
      #pragma unroll
      for (int hl = 0; hl < 4; hl++){
        float cn = gates[4+hl][bb]*cst[1][hl][bb] + gates[0+hl][bb]*gates[8+hl][bb];
        cst[1][hl][bb] = cn;
        hn[hl] = gates[12+hl][bb]*tanhf(cn);
        h1loc[hl][bb*T + t1] = (__fp16)hn[hl];
      }
      U32H2 z0, z1; z0.h = pk2(hn[0], hn[1]); z1.h = pk2(hn[2], hn[3]);
      uint2 val; val.x = z0.u; val.y = z1.u;
      stA8((char*)h1w + (long)(bb*1024 + 4*gB)*2, val);
    }
    // ---- layer0(p) partial stash ----
    if (p < T){
      #pragma unroll
      for (int r = 0; r < 4; r++){
        partial[w][lk*4 + r][lrow]      = acc00[r];
        partial[w][lk*4 + r][16 + lrow] = acc01[r];
      }
    }
    __syncthreads();
    if (p < T && tid < 512){
      int r = tid >> 5, bb = tid & 31;
      float s = 0.f;
      #pragma unroll
      for (int w2 = 0; w2 < 16; w2++) s += partial[w2][r][bb];
      float v = s + bs0v[r];
      gates[r][bb] = ((r >> 2) == 2) ? tanhf(v) : sigm(v);
    }
    __syncthreads();
    if (p < T && tid < 32){
      int bb = tid;
      float hn[4];
      #pragma unroll
      for (int hl = 0; hl < 4; hl++){
        float cn = gates[4+hl][bb]*cst[0][hl][bb] + gates[0+hl][bb]*gates[8+hl][bb];
        cst[0][hl][bb] = cn;
        hn[hl] = gates[12+hl][bb]*tanhf(cn);
      }
      U32H2 z0, z1; z0.h = pk2(hn[0], hn[1]); z1.h = pk2(hn[2], hn[3]);
      uint2 val; val.x = z0.u; val.y = z1.u;
      stA8((char*)h0w + (long)(bb*1024 + 4*gB)*2, val);
    }
    gbar(bar, ep); ep++;
  }

  // direct swizzled-Abf flush: block gB owns k = 4gB..4gB+3 (8B half-slot)
  {
    int k0c = gB >> 4;
    int seg = (gB & 15) >> 1;
    int posb = (gB & 1) * 8;
    for (int m = tid; m < B*T; m += 1024){
      float v0 = (float)h1loc[0][m], v1 = (float)h1loc[1][m];
      float v2 = (float)h1loc[2][m], v3 = (float)h1loc[3][m];
      int bm = m >> 7, row = m & 127;
      long slot = ((long)(bm*16 + k0c)*128 + row)*8 + (seg ^ (row & 7));
      uint2 val; val.x = pkbf(v0, v1); val.y = pkbf(v2, v3);
      *(uint2*)((char*)Abf + slot*16 + posb) = val;
    }
  }
}

// ---------------- fallback per-step cells ----------------
__global__ void k_init(const float* __restrict__ enc, float* __restrict__ h0, float* __restrict__ c0,
                       float* __restrict__ h1, float* __restrict__ c1){
  int idx = blockIdx.x*256 + threadIdx.x;
  int b = idx & 31, h = idx >> 5;
  float v = enc[b*H + h];
  h0[idx]=v; c0[idx]=v; h1[idx]=v; c1[idx]=v;
}

__global__ __launch_bounds__(256) void k_cell0(const float* __restrict__ whh, const float* __restrict__ xg_t,
                       const float* __restrict__ h_in, float* __restrict__ h_out,
                       float* __restrict__ c){
  int h = (blockIdx.x*256 + threadIdx.x) >> 6;
  int lane = threadIdx.x & 63;
  int b = lane & 31, kh = lane >> 5;
  const float* w0 = whh + (0*H + h)*H + kh*512;
  const float* w1 = whh + (1*H + h)*H + kh*512;
  const float* w2 = whh + (2*H + h)*H + kh*512;
  const float* w3 = whh + (3*H + h)*H + kh*512;
  const float* hk = h_in + (kh*512)*B + b;
  float a0=0,a1=0,a2=0,a3=0, p0=0,p1=0,p2=0,p3=0;
  #pragma unroll 4
  for (int k=0;k<512;k+=4){
    float4 w40 = *(const float4*)(w0+k);
    float4 w41 = *(const float4*)(w1+k);
    float4 w42 = *(const float4*)(w2+k);
    float4 w43 = *(const float4*)(w3+k);
    float hv0 = hk[(k+0)*B], hv1 = hk[(k+1)*B], hv2 = hk[(k+2)*B], hv3 = hk[(k+3)*B];
    a0 += w40.x*hv0 + w40.y*hv1;  p0 += w40.z*hv2 + w40.w*hv3;
    a1 += w41.x*hv0 + w41.y*hv1;  p1 += w41.z*hv2 + w41.w*hv3;
    a2 += w42.x*hv0 + w42.y*hv1;  p2 += w42.z*hv2 + w42.w*hv3;
    a3 += w43.x*hv0 + w43.y*hv1;  p3 += w43.z*hv2 + w43.w*hv3;
  }
  float g0=a0+p0, g1=a1+p1, g2=a2+p2, g3=a3+p3;
  g0 += __shfl_xor(g0, 32);
  g1 += __shfl_xor(g1, 32);
  g2 += __shfl_xor(g2, 32);
  g3 += __shfl_xor(g3, 32);
  g0 += xg_t[(0*H+h)*B + b];
  g1 += xg_t[(1*H+h)*B + b];
  g2 += xg_t[(2*H+h)*B + b];
  g3 += xg_t[(3*H+h)*B + b];
  float ig = sigm(g0), fg = sigm(g1), gg = tanhf(g2), og = sigm(g3);
  int sidx = h*B + b;
  float cn = fg*c[sidx] + ig*gg;
  float hn = og*tanhf(cn);
  if (kh==0){ c[sidx]=cn; h_out[sidx]=hn; }
}

__global__ __launch_bounds__(256) void k_cell1(const float* __restrict__ wih, const float* __restrict__ whh,
                       const float* __restrict__ bih, const float* __restrict__ bhh,
                       const float* __restrict__ h0n, const float* __restrict__ h_in,
                       float* __restrict__ h_out, float* __restrict__ c,
                       float* __restrict__ H1Tmk, int t){
  int h = (blockIdx.x*256 + threadIdx.x) >> 6;
  int lane = threadIdx.x & 63;
  int b = lane & 31, kh = lane >> 5;
  float a0=0,a1=0,a2=0,a3=0, p0=0,p1=0,p2=0,p3=0;
  {
    const float* w0 = wih + (0*H + h)*H + kh*512;
    const float* w1 = wih + (1*H + h)*H + kh*512;
    const float* w2 = wih + (2*H + h)*H + kh*512;
    const float* w3 = wih + (3*H + h)*H + kh*512;
    const float* hk = h0n + (kh*512)*B + b;
    #pragma unroll 4
    for (int k=0;k<512;k+=4){
      float4 w40 = *(const float4*)(w0+k);
      float4 w41 = *(const float4*)(w1+k);
      float4 w42 = *(const float4*)(w2+k);
      float4 w43 = *(const float4*)(w3+k);
      float hv0 = hk[(k+0)*B], hv1 = hk[(k+1)*B], hv2 = hk[(k+2)*B], hv3 = hk[(k+3)*B];
      a0 += w40.x*hv0 + w40.y*hv1;  p0 += w40.z*hv2 + w40.w*hv3;
      a1 += w41.x*hv0 + w41.y*hv1;  p1 += w41.z*hv2 + w41.w*hv3;
      a2 += w42.x*hv0 + w42.y*hv1;  p2 += w42.z*hv2 + w42.w*hv3;
      a3 += w43.x*hv0 + w43.y*hv1;  p3 += w43.z*hv2 + w43.w*hv3;
    }
  }
  {
    const float* w0 = whh + (0*H + h)*H + kh*512;
    const float* w1 = whh + (1*H + h)*H + kh*512;
    const float* w2 = whh + (2*H + h)*H + kh*512;
    const float* w3 = whh + (3*H + h)*H + kh*512;
    const float* hk = h_in + (kh*512)*B + b;
    #pragma unroll 4
    for (int k=0;k<512;k+=4){
      float4 w40 = *(const float4*)(w0+k);
      float4 w41 = *(const float4*)(w1+k);
      float4 w42 = *(const float4*)(w2+k);
      float4 w43 = *(const float4*)(w3+k);
      float hv0 = hk[(k+0)*B], hv1 = hk[(k+1)*B], hv2 = hk[(k+2)*B], hv3 = hk[(k+3)*B];
      a0 += w40.x*hv0 + w40.y*hv1;  p0 += w40.z*hv2 + w40.w*hv3;
      a1 += w41.x*hv0 + w41.y*hv1;  p1 += w41.z*hv2 + w41.w*hv3;
      a2 += w42.x*hv0 + w42.y*hv1;  p2 += w42.z*hv2 + w42.w*hv3;
      a3 += w43.x*hv0 + w43.y*hv1;  p3 += w43.z*hv2 + w43.w*hv3;
    }
  }
  float g0=a0+p0, g1=a1+p1, g2=a2+p2, g3=a3+p3;
  g0 += __shfl_xor(g0, 32);
  g1 += __shfl_xor(g1, 32);
  g2 += __shfl_xor(g2, 32);
  g3 += __shfl_xor(g3, 32);
  g0 += bih[0*H+h] + bhh[0*H+h];
  g1 += bih[1*H+h] + bhh[1*H+h];
  g2 += bih[2*H+h] + bhh[2*H+h];
  g3 += bih[3*H+h] + bhh[3*H+h];
  float ig = sigm(g0), fg = sigm(g1), gg = tanhf(g2), og = sigm(g3);
  int sidx = h*B + b;
  float cn = fg*c[sidx] + ig*gg;
  float hn = og*tanhf(cn);
  if (kh==0){ c[sidx]=cn; h_out[sidx]=hn; H1Tmk[((long)(b*T + t))*1024 + h] = hn; }
}

// ---------------- MFMA bf16 output GEMM (pre-swizzled operands) ----------------
__global__ __launch_bounds__(256, 2) void k_gemm_pre(const uint4* __restrict__ Abf4,
                      const uint4* __restrict__ Wsw4, const float* __restrict__ lb,
                      float* __restrict__ out){
  __shared__ uint4 As4[1024];
  __shared__ uint4 Ws4[1024];
  const int tid = threadIdx.x;
  int orig = blockIdx.x;
  int xcd = orig & 7, ii = orig >> 3;
  int wgid = (xcd < 2 ? xcd*407 : 814 + (xcd-2)*406) + ii;
  int bm = wgid % 13, bn = wgid / 13;
  int m0 = bm*128, n0 = bn*128;
  const int wv = tid >> 6, l = tid & 63;
  const int wm = (wv >> 1)*64, wn = (wv & 1)*64;
  const int lrow = l & 15, lk = l >> 4;

  floatx4 acc[4][4] = {};
  for (int k0c = 0; k0c < 16; k0c++){
    const uint4* sA = Abf4 + (long)(bm*16 + k0c)*1024;
    const uint4* sW = Wsw4 + (long)(bn*16 + k0c)*1024;
    #pragma unroll
    for (int it = 0; it < 4; it++){
      int slot = tid + it*256;
      As4[slot] = sA[slot];
      Ws4[slot] = sW[slot];
    }
    __syncthreads();
    #pragma unroll
    for (int ks = 0; ks < 2; ks++){
      short8 af[4], bf_[4];
      #pragma unroll
      for (int fi = 0; fi < 4; fi++){
        int row = wm + fi*16 + lrow;
        U16S8 u; u.u4 = As4[row*8 + ((ks*4 + lk) ^ (lrow & 7))];
        af[fi] = u.s8;
      }
      #pragma unroll
      for (int fj = 0; fj < 4; fj++){
        int row = wn + fj*16 + lrow;
        U16S8 u; u.u4 = Ws4[row*8 + ((ks*4 + lk) ^ (lrow & 7))];
        bf_[fj] = u.s8;
      }
      #pragma unroll
      for (int fi = 0; fi < 4; fi++)
        #pragma unroll
        for (int fj = 0; fj < 4; fj++)
          acc[fi][fj] = __builtin_amdgcn_mfma_f32_16x16x32_bf16(af[fi], bf_[fj], acc[fi][fj], 0, 0, 0);
    }
    __syncthreads();
  }
  #pragma unroll
  for (int fj = 0; fj < 4; fj++){
    int n = n0 + wn + fj*16 + lrow;
    float bias = lb[n];
    #pragma unroll
    for (int fi = 0; fi < 4; fi++){
      floatx4 av = acc[fi][fj];
      int mb = m0 + wm + fi*16 + lk*4;
      #pragma unroll
      for (int r = 0; r < 4; r++){
        int m = mb + r;
        if (m < B*T) out[(long)m*V + n] = av[r] + bias;
      }
    }
  }
}

// fallback GEMM: A pre-swizzled, W converted inline from f32
__global__ __launch_bounds__(256, 2) void k_gemm_inl(const uint4* __restrict__ Abf4,
                      const float* __restrict__ lw, const float* __restrict__ lb,
                      float* __restrict__ out){
  __shared__ uint4 As4[1024];
  __shared__ uint4 Ws4[1024];
  const int tid = threadIdx.x;
  int orig = blockIdx.x;
  int xcd = orig & 7, ii = orig >> 3;
  int wgid = (xcd < 2 ? xcd*407 : 814 + (xcd-2)*406) + ii;
  int bm = wgid % 13, bn = wgid / 13;
  int m0 = bm*128, n0 = bn*128;
  const int wv = tid >> 6, l = tid & 63;
  const int wm = (wv >> 1)*64, wn = (wv & 1)*64;
  const int lrow = l & 15, lk = l >> 4;

  floatx4 acc[4][4] = {};
  for (int k0c = 0; k0c < 16; k0c++){
    const uint4* sA = Abf4 + (long)(bm*16 + k0c)*1024;
    #pragma unroll
    for (int it = 0; it < 4; it++){
      int slot = tid + it*256;
      As4[slot] = sA[slot];
      int row = slot >> 3, seg = slot & 7;
      const float4* src = (const float4*)(lw + (long)(n0+row)*H + k0c*64 + seg*8);
      float4 v0 = src[0], v1 = src[1];
      uint4 pk;
      pk.x = pkbf(v0.x, v0.y); pk.y = pkbf(v0.z, v0.w);
      pk.z = pkbf(v1.x, v1.y); pk.w = pkbf(v1.z, v1.w);
      Ws4[row*8 + (seg ^ (row & 7))] = pk;
    }
    __syncthreads();
    #pragma unroll
    for (int ks = 0; ks < 2; ks++){
      short8 af[4], bf_[4];
      #pragma unroll
      for (int fi = 0; fi < 4; fi++){
        int row = wm + fi*16 + lrow;
        U16S8 u; u.u4 = As4[row*8 + ((ks*4 + lk) ^ (lrow & 7))];
        af[fi] = u.s8;
      }
      #pragma unroll
      for (int fj = 0; fj < 4; fj++){
        int row = wn + fj*16 + lrow;
        U16S8 u; u.u4 = Ws4[row*8 + ((ks*4 + lk) ^ (lrow & 7))];
        bf_[fj] = u.s8;
      }
      #pragma unroll
      for (int fi = 0; fi < 4; fi++)
        #pragma unroll
        for (int fj = 0; fj < 4; fj++)
          acc[fi][fj] = __builtin_amdgcn_mfma_f32_16x16x32_bf16(af[fi], bf_[fj], acc[fi][fj], 0, 0, 0);
    }
    __syncthreads();
  }
  #pragma unroll
  for (int fj = 0; fj < 4; fj++){
    int n = n0 + wn + fj*16 + lrow;
    float bias = lb[n];
    #pragma unroll
    for (int fi = 0; fi < 4; fi++){
      floatx4 av = acc[fi][fj];
      int mb = m0 + wm + fi*16 + lk*4;
      #pragma unroll
      for (int r = 0; r < 4; r++){
        int m = mb + r;
        if (m < B*T) out[(long)m*V + n] = av[r] + bias;
      }
    }
  }
}

// online 2-pass log-softmax
__global__ __launch_bounds__(256) void k_lsm(float* __restrict__ out){
  __shared__ float redm[256], reds[256];
  float4* row = (float4*)(out + (long)blockIdx.x * V);
  const int tid = threadIdx.x;
  float m = -INFINITY, s = 0.f;
  for (int n=tid;n<V/4;n+=256){
    float4 v = row[n];
    float cm = fmaxf(fmaxf(v.x,v.y), fmaxf(v.z,v.w));
    if (cm > m){ s *= __expf(m - cm); m = cm; }
    s += __expf(v.x-m)+__expf(v.y-m)+__expf(v.z-m)+__expf(v.w-m);
  }
  redm[tid]=m; reds[tid]=s; __syncthreads();
  for (int st=128;st>0;st>>=1){
    if (tid<st){
      float m1=redm[tid], s1=reds[tid];
      float m2=redm[tid+st], s2=reds[tid+st];
      float M=fmaxf(m1,m2);
      reds[tid]=s1*__expf(m1-M)+s2*__expf(m2-M);
      redm[tid]=M;
    }
    __syncthreads();
  }
  float lse = redm[0] + __logf(reds[0]);
  for (int n=tid;n<V/4;n+=256){
    float4 v = row[n];
    v.x-=lse; v.y-=lse; v.z-=lse; v.w-=lse;
    row[n] = v;
  }
}

extern "C" void kernel_launch(void* const* d_in, const int* in_sizes, int n_in,
                              void* d_out, int out_size, void* d_ws, size_t ws_size,
                              hipStream_t stream){
  const float* enc    = (const float*)d_in[0];
  const float* target = (const float*)d_in[1];
  const float* pw     = (const float*)d_in[2];
  const float* pb     = (const float*)d_in[3];
  const float* wih0   = (const float*)d_in[4];
  const float* whh0   = (const float*)d_in[5];
  const float* bih0   = (const float*)d_in[6];
  const float* bhh0   = (const float*)d_in[7];
  const float* wih1   = (const float*)d_in[8];
  const float* whh1   = (const float*)d_in[9];
  const float* bih1   = (const float*)d_in[10];
  const float* bhh1   = (const float*)d_in[11];
  const float* lw     = (const float*)d_in[12];
  const float* lb     = (const float*)d_in[13];
  float* out = (float*)d_out;

  float* ws   = (float*)d_ws;
  float* xg0  = ws;                              // 6,553,600 f (fallback)
  float* P    = xg0 + (long)T*G4*B;              // 204,800 f (fallback)
  float* encp = P + T*E*B;                       // 4,096 f
  float* H1Tmk = encp + B*E;                     // 1,703,936 f (fallback)
  unsigned* Abf = (unsigned*)(H1Tmk + (long)MROWS*1024);  // 851,968 u32
  unsigned* h0A2 = Abf + 851968;                 // 16,384 each (64KB f16 state)
  unsigned* h0B2 = h0A2 + 16384;
  unsigned* h1A2 = h0B2 + 16384;
  unsigned* h1B2 = h1A2 + 16384;
  float* fh0a = (float*)(h1B2 + 16384);          // fallback f32 state
  float* fh0b = fh0a + H*B;
  float* fh1a = fh0b + H*B;
  float* fh1b = fh1a + H*B;
  float* fc0  = fh1b + H*B;
  float* fc1  = fc0 + H*B;
  unsigned* bar = (unsigned*)(fc1 + H*B);        // 1,024 u32
  __fp16* Pf16 = (__fp16*)(bar + 1024);          // 204,800 f16
  unsigned* lwsw = (unsigned*)(Pf16 + (long)T*B*E);  // 16,384,000 u32
  size_t need = (size_t)((char*)(lwsw + 16384000) - (char*)d_ws);
  bool pre = (ws_size >= need);

  k_encp<<<B, E, 0, stream>>>(enc, pw, pb, encp);
  k_proj<<<T*B, E, 0, stream>>>(target, pw, encp, P, Pf16);
  k_zero32<<<4, 256, 0, stream>>>(bar);
  if (pre) k_cvtw<<<16000, 256, 0, stream>>>(lw, (uint4*)lwsw);

  void* cargs[] = {(void*)&whh0, (void*)&wih1, (void*)&whh1,
                   (void*)&wih0, (void*)&bih0, (void*)&bhh0,
                   (void*)&bih1, (void*)&bhh1,
                   (void*)&enc, (void*)&Pf16,
                   (void*)&h0A2, (void*)&h0B2, (void*)&h1A2, (void*)&h1B2,
                   (void*)&Abf, (void*)&bar};
  hipError_t cerr = hipLaunchCooperativeKernel((void*)k_cells, dim3(NB), dim3(1024),
                                               cargs, 0, stream);
  if (cerr != hipSuccess){
    k_xg0<<<(T*G4*B)/256, 256, 0, stream>>>(wih0, bih0, bhh0, P, xg0);
    k_init<<<(H*B)/256, 256, 0, stream>>>(enc, fh0a, fc0, fh1a, fc1);
    float* h0in=fh0a; float* h0out=fh0b;
    float* h1in=fh1a; float* h1out=fh1b;
    for (int t=0;t<T;t++){
      k_cell0<<<256, 256, 0, stream>>>(whh0, xg0 + (long)t*G4*B, h0in, h0out, fc0);
      k_cell1<<<256, 256, 0, stream>>>(wih1, whh1, bih1, bhh1, h0out, h1in, h1out, fc1,
                                       H1Tmk, t);
      float* tmp;
      tmp=h0in; h0in=h0out; h0out=tmp;
      tmp=h1in; h1in=h1out; h1out=tmp;
    }
    k_pack<<<800, 256, 0, stream>>>(H1Tmk, (uint4*)Abf);
  }

  if (pre) k_gemm_pre<<<3250, 256, 0, stream>>>((const uint4*)Abf, (const uint4*)lwsw, lb, out);
  else     k_gemm_inl<<<3250, 256, 0, stream>>>((const uint4*)Abf, lw, lb, out);
  k_lsm<<<B*T, 256, 0, stream>>>(out);
}

// Round 21
// 796.718 us; speedup vs baseline: 1.3417x; 1.0579x over previous
//
#include <hip/hip_runtime.h>
#include <hip/hip_bf16.h>
#include <math.h>

#define B 32
#define T 50
#define H 1024
#define E 128
#define V 32000
#define G4 4096   // 4*H
#define HE 1152   // H+E
#define MROWS 1664 // 13*128 padded M for GEMM
#define NB 256    // coop grid blocks

typedef __fp16 half2v __attribute__((ext_vector_type(2)));
typedef __fp16 half8 __attribute__((ext_vector_type(8)));
typedef unsigned long long ull;
union U32H2 { unsigned u; half2v h; };
union U4H8 { uint4 u4; half8 h8; };
typedef short short8 __attribute__((ext_vector_type(8)));
typedef float floatx4 __attribute__((ext_vector_type(4)));
union U16S8 { uint4 u4; short8 s8; };

// 16B LLC-coherent load (bypass L1+L2), issue-only; pair with one vmcnt wait.
#define LLC_LOAD(dst, ptr) \
  asm volatile("global_load_dwordx4 %0, %1, off sc0 sc1" : "=v"((dst).u4) : "v"(ptr))

__device__ __forceinline__ float sigm(float x){ return 1.0f/(1.0f+expf(-x)); }

__device__ __forceinline__ half2v pk2(float a, float b){
#if __has_builtin(__builtin_amdgcn_cvt_pkrtz)
  return __builtin_amdgcn_cvt_pkrtz(a, b);
#else
  half2v r; r.x = (__fp16)a; r.y = (__fp16)b; return r;
#endif
}

// pack two f32 -> one u32 of two bf16 (RNE)
__device__ __forceinline__ unsigned pkbf(float a, float b){
  unsigned ua = __float_as_uint(a), ub = __float_as_uint(b);
  unsigned ra = (ua + 0x7FFFu + ((ua>>16)&1u)) >> 16;
  unsigned rb = (ub + 0x7FFFu + ((ub>>16)&1u)) >> 16;
  return ra | (rb << 16);
}

// agent-scope store, 8B (bypasses caches, lands at LLC)
__device__ __forceinline__ void stA8(void* p, uint2 v){
  ull q = ((ull)v.y << 32) | (ull)v.x;
  __hip_atomic_store((ull*)p, q, __ATOMIC_RELAXED, __HIP_MEMORY_SCOPE_AGENT);
}

// ---- fence-free tree grid barrier (8 leaves x 32 + root) — r17 verified ----
__device__ __forceinline__ void gbar(unsigned* bar, unsigned ep){
  __syncthreads();
  if (threadIdx.x == 0){
    asm volatile("s_waitcnt vmcnt(0)" ::: "memory");
    unsigned g = blockIdx.x & 7u;
    unsigned old = __hip_atomic_fetch_add(&bar[64 + g*64], 1u,
                     __ATOMIC_RELAXED, __HIP_MEMORY_SCOPE_AGENT);
    if (old == ep*32u - 1u)
      __hip_atomic_fetch_add(&bar[0], 1u, __ATOMIC_RELAXED, __HIP_MEMORY_SCOPE_AGENT);
    while (__hip_atomic_load(&bar[0], __ATOMIC_RELAXED, __HIP_MEMORY_SCOPE_AGENT) < ep*8u)
      __builtin_amdgcn_s_sleep(1);
  }
  __syncthreads();
}

// encp[b][e] = proj_b[e] + sum_j enc[b][j] * proj_w[e][E+j]
__global__ void k_encp(const float* __restrict__ enc, const float* __restrict__ pw,
                       const float* __restrict__ pb, float* __restrict__ encp){
  int b = blockIdx.x, e = threadIdx.x;
  const float* er = enc + b*H;
  const float* wr = pw + e*HE + E;
  float acc = pb[e];
  for (int j=0;j<H;j+=4){
    float4 w4 = *(const float4*)(wr+j);
    float4 e4 = *(const float4*)(er+j);
    acc += w4.x*e4.x + w4.y*e4.y + w4.z*e4.z + w4.w*e4.w;
  }
  encp[b*E+e] = acc;
}

// P[t][e][b] f32 (fallback) + Pf16[t][b][e] (coop MFMA B-operand)
__global__ void k_proj(const float* __restrict__ target, const float* __restrict__ pw,
                       const float* __restrict__ encp, float* __restrict__ P,
                       __fp16* __restrict__ Pf16){
  int t = blockIdx.x / B, b = blockIdx.x % B, e = threadIdx.x;
  const float* xr = target + (b*T + t)*E;
  const float* wr = pw + e*HE;
  float acc = encp[b*E+e];
  for (int j=0;j<E;j+=4){
    float4 w4 = *(const float4*)(wr+j);
    float4 x4 = *(const float4*)(xr+j);
    acc += w4.x*x4.x + w4.y*x4.y + w4.z*x4.z + w4.w*x4.w;
  }
  P[(t*E + e)*B + b] = acc;
  Pf16[((long)t*B + b)*E + e] = (__fp16)acc;
}

// xg0[t][r][b] (fallback path only)
__global__ void k_xg0(const float* __restrict__ wih0, const float* __restrict__ bih0,
                      const float* __restrict__ bhh0, const float* __restrict__ P,
                      float* __restrict__ xg){
  int idx = blockIdx.x*256 + threadIdx.x;
  int b = idx & 31; int r = (idx >> 5) & 4095; int t = idx >> 17;
  const float* wr = wih0 + r*E;
  const float* pr = P + t*E*B + b;
  float acc = bih0[r] + bhh0[r];
  #pragma unroll 8
  for (int e=0;e<E;e+=4){
    float4 w4 = *(const float4*)(wr+e);
    acc += w4.x*pr[(e+0)*B] + w4.y*pr[(e+1)*B]
         + w4.z*pr[(e+2)*B] + w4.w*pr[(e+3)*B];
  }
  xg[idx] = acc;
}

__global__ void k_zero32(unsigned* __restrict__ p){
  p[blockIdx.x*256 + threadIdx.x] = 0u;
}

// convert lw f32 -> bf16 in the GEMM's swizzled tile layout (fallback path only)
__global__ void k_cvtw(const float* __restrict__ lw, uint4* __restrict__ wsw){
  int gid = blockIdx.x*256 + threadIdx.x;   // 4,096,000
  int n = gid >> 7, rem = gid & 127;
  int k0c = rem >> 3, seg = rem & 7;
  const float4* src = (const float4*)(lw + (long)n*H + k0c*64 + seg*8);
  float4 v0 = src[0], v1 = src[1];
  uint4 pk;
  pk.x = pkbf(v0.x, v0.y); pk.y = pkbf(v0.z, v0.w);
  pk.z = pkbf(v1.x, v1.y); pk.w = pkbf(v1.z, v1.w);
  int bn = n >> 7, row = n & 127;
  wsw[((long)(bn*16 + k0c)*128 + row)*8 + (seg ^ (row & 7))] = pk;
}

// pack H1Tmk f32 [m][k] -> Abf swizzled bf16 tiles (fallback path only)
__global__ void k_pack(const float* __restrict__ H1Tmk, uint4* __restrict__ Abf){
  int gid = blockIdx.x*256 + threadIdx.x;   // 204,800
  int m = gid >> 7, rem = gid & 127;
  int k0c = rem >> 3, seg = rem & 7;
  const float4* src = (const float4*)(H1Tmk + (long)m*1024 + k0c*64 + seg*8);
  float4 v0 = src[0], v1 = src[1];
  uint4 pk;
  pk.x = pkbf(v0.x, v0.y); pk.y = pkbf(v0.z, v0.w);
  pk.z = pkbf(v1.x, v1.y); pk.w = pkbf(v1.z, v1.w);
  int bm = m >> 7, row = m & 127;
  Abf[((long)(bm*16 + k0c)*128 + row)*8 + (seg ^ (row & 7))] = pk;
}

// ---------------- cooperative persistent cells (v14: fused xg + distributed cvtw) ----------------
__global__ __launch_bounds__(1024, 4) void k_cells(
    const float* __restrict__ whh0, const float* __restrict__ wih1, const float* __restrict__ whh1,
    const float* __restrict__ wih0, const float* __restrict__ bih0, const float* __restrict__ bhh0,
    const float* __restrict__ bih1, const float* __restrict__ bhh1,
    const float* __restrict__ enc, const __fp16* __restrict__ Pf16,
    const float* __restrict__ lw, uint4* __restrict__ lwsw,
    unsigned* __restrict__ h0A2, unsigned* __restrict__ h0B2,
    unsigned* __restrict__ h1A2, unsigned* __restrict__ h1B2,
    unsigned* __restrict__ Abf, unsigned* __restrict__ bar){
  const int gB = blockIdx.x;
  const int tid = threadIdx.x;
  const int w = tid >> 6;       // wave 0..15 = k-chunk owner
  const int l = tid & 63;
  const int lrow = l & 15;      // fragment row/col
  const int lk = l >> 4;        // k-segment 0..3

  __shared__ uint4 w0s4[16*128];        // layer0 whh0 rows, f16 swizzled (32 KB)
  __shared__ uint4 w1s4[32*128];        // wih1(0-15)+whh1(16-31) (64 KB)
  __shared__ uint4 w0x4[16*16];         // layer0 wih0 rows, f16 swizzled (4 KB)
  __shared__ float partial[16][16][34]; // [wave][row][b-col] pad 34
  __shared__ float gates[16][32];
  __shared__ float cst[2][4][32];
  __shared__ float bs1v[16];
  __shared__ float bs0v[16];
  __shared__ __fp16 h1loc[4][1600];     // [hl][b*T+t] (12.8 KB)

  // ---- stage weights f32 -> f16, XOR-swizzled segments ----
  for (int i = tid; i < 2048; i += 1024){
    int row = i >> 7, seg = i & 127;
    int q = row >> 2, hl = row & 3;
    const float* src = whh0 + ((long)q*H + 4*gB + hl)*H + seg*8;
    float4 v0 = *(const float4*)src, v1 = *(const float4*)(src+4);
    U32H2 z0,z1,z2,z3;
    z0.h = pk2(v0.x,v0.y); z1.h = pk2(v0.z,v0.w);
    z2.h = pk2(v1.x,v1.y); z3.h = pk2(v1.z,v1.w);
    uint4 pk; pk.x=z0.u; pk.y=z1.u; pk.z=z2.u; pk.w=z3.u;
    int phys = (seg & ~7) | ((seg & 7) ^ (row & 7));
    w0s4[row*128 + phys] = pk;
  }
  for (int i = tid; i < 4096; i += 1024){
    int row = i >> 7, seg = i & 127;
    int rr = row & 15;
    int q = rr >> 2, hl = rr & 3;
    const float* srcm = (row < 16) ? wih1 : whh1;
    const float* src = srcm + ((long)q*H + 4*gB + hl)*H + seg*8;
    float4 v0 = *(const float4*)src, v1 = *(const float4*)(src+4);
    U32H2 z0,z1,z2,z3;
    z0.h = pk2(v0.x,v0.y); z1.h = pk2(v0.z,v0.w);
    z2.h = pk2(v1.x,v1.y); z3.h = pk2(v1.z,v1.w);
    uint4 pk; pk.x=z0.u; pk.y=z1.u; pk.z=z2.u; pk.w=z3.u;
    int phys = (seg & ~7) | ((seg & 7) ^ (rr & 7));
    w1s4[row*128 + phys] = pk;
  }
  if (tid < 256){
    int row = tid >> 4, seg = tid & 15;
    int q = row >> 2, hl = row & 3;
    const float* src = wih0 + ((long)q*H + 4*gB + hl)*E + seg*8;
    float4 v0 = *(const float4*)src, v1 = *(const float4*)(src+4);
    U32H2 z0,z1,z2,z3;
    z0.h = pk2(v0.x,v0.y); z1.h = pk2(v0.z,v0.w);
    z2.h = pk2(v1.x,v1.y); z3.h = pk2(v1.z,v1.w);
    uint4 pk; pk.x=z0.u; pk.y=z1.u; pk.z=z2.u; pk.w=z3.u;
    int phys = (seg & ~7) | ((seg & 7) ^ (row & 7));
    w0x4[row*16 + phys] = pk;
  }
  if (tid < 16){
    int q = tid >> 2, hl = tid & 3;
    bs1v[tid] = bih1[q*H + 4*gB + hl] + bhh1[q*H + 4*gB + hl];
    bs0v[tid] = bih0[q*H + 4*gB + hl] + bhh0[q*H + 4*gB + hl];
  }
  if (tid < 128){
    int hl = tid >> 5, bb = tid & 31;
    float v = enc[bb*H + 4*gB + hl];
    cst[0][hl][bb] = v; cst[1][hl][bb] = v;
  }
  if (tid < 32){
    int bb = tid;
    U32H2 z0, z1;
    z0.h = pk2(enc[bb*H + 4*gB + 0], enc[bb*H + 4*gB + 1]);
    z1.h = pk2(enc[bb*H + 4*gB + 2], enc[bb*H + 4*gB + 3]);
    uint2 val; val.x = z0.u; val.y = z1.u;
    stA8((char*)h0A2 + (long)(bb*1024 + 4*gB)*2, val);
    stA8((char*)h1A2 + (long)(bb*1024 + 4*gB)*2, val);
  }
  unsigned ep = 1;
  gbar(bar, ep); ep++;

  for (int p = 0; p <= T; p++){
    const unsigned* h0r = (p & 1) ? h0B2 : h0A2;
    unsigned*       h0w = (p & 1) ? h0A2 : h0B2;
    const unsigned* h1r = (p & 1) ? h1A2 : h1B2;
    unsigned*       h1w = (p & 1) ? h1B2 : h1A2;

    // ---- batched LLC state loads (issue all, wait once) ----
    int c = (w + gB + p) & 15;
    U4H8 b0a0, b0a1, b0b0, b0b1, b1a0, b1a1, b1b0, b1b1;
    {
      int kb = c*64;
      const __fp16* h0f = (const __fp16*)h0r;
      const __fp16* h1f = (const __fp16*)h1r;
      const __fp16* s0a = h0f + lrow*1024 + kb + lk*8;
      const __fp16* s0b = h0f + (16+lrow)*1024 + kb + lk*8;
      LLC_LOAD(b0a0, s0a);      LLC_LOAD(b0a1, s0a + 32);
      LLC_LOAD(b0b0, s0b);      LLC_LOAD(b0b1, s0b + 32);
      if (p >= 1){
        const __fp16* s1a = h1f + lrow*1024 + kb + lk*8;
        const __fp16* s1b = h1f + (16+lrow)*1024 + kb + lk*8;
        LLC_LOAD(b1a0, s1a);    LLC_LOAD(b1a1, s1a + 32);
        LLC_LOAD(b1b0, s1b);    LLC_LOAD(b1b1, s1b + 32);
      }
      asm volatile("s_waitcnt vmcnt(0)" ::: "memory");
      __builtin_amdgcn_sched_barrier(0);
    }

    // ---- MFMA matvec ----
    floatx4 acc10 = {0,0,0,0}, acc11 = {0,0,0,0};
    floatx4 acc00 = {0,0,0,0}, acc01 = {0,0,0,0};
    #pragma unroll
    for (int ks = 0; ks < 2; ks++){
      int phys = c*8 + (((ks<<2) + lk) ^ (lrow & 7));
      half8 B0a = ks ? b0a1.h8 : b0a0.h8;
      half8 B0b = ks ? b0b1.h8 : b0b0.h8;
      if (p < T){
        U4H8 a0v; a0v.u4 = w0s4[lrow*128 + phys];
        acc00 = __builtin_amdgcn_mfma_f32_16x16x32_f16(a0v.h8, B0a, acc00, 0, 0, 0);
        acc01 = __builtin_amdgcn_mfma_f32_16x16x32_f16(a0v.h8, B0b, acc01, 0, 0, 0);
      }
      if (p >= 1){
        U4H8 a1i; a1i.u4 = w1s4[lrow*128 + phys];
        U4H8 a1h; a1h.u4 = w1s4[(16+lrow)*128 + phys];
        half8 B1a = ks ? b1a1.h8 : b1a0.h8;
        half8 B1b = ks ? b1b1.h8 : b1b0.h8;
        acc10 = __builtin_amdgcn_mfma_f32_16x16x32_f16(a1i.h8, B0a, acc10, 0, 0, 0);
        acc10 = __builtin_amdgcn_mfma_f32_16x16x32_f16(a1h.h8, B1a, acc10, 0, 0, 0);
        acc11 = __builtin_amdgcn_mfma_f32_16x16x32_f16(a1i.h8, B0b, acc11, 0, 0, 0);
        acc11 = __builtin_amdgcn_mfma_f32_16x16x32_f16(a1h.h8, B1b, acc11, 0, 0, 0);
      }
    }
    // ---- fused xg contribution: waves with c<2 add wih0 . P_t ----
    if (p < T && c < 2){
      const __fp16* pbase = Pf16 + (long)p*B*E + c*64 + lk*8;
      U4H8 q0a, q1a, q0b, q1b;
      q0a.u4 = *(const uint4*)(pbase + lrow*E);
      q1a.u4 = *(const uint4*)(pbase + lrow*E + 32);
      q0b.u4 = *(const uint4*)(pbase + (16+lrow)*E);
      q1b.u4 = *(const uint4*)(pbase + (16+lrow)*E + 32);
      #pragma unroll
      for (int ks = 0; ks < 2; ks++){
        int phys = c*8 + (((ks<<2) + lk) ^ (lrow & 7));
        U4H8 aw; aw.u4 = w0x4[lrow*16 + phys];
        acc00 = __builtin_amdgcn_mfma_f32_16x16x32_f16(aw.h8, ks ? q1a.h8 : q0a.h8, acc00, 0, 0, 0);
        acc01 = __builtin_amdgcn_mfma_f32_16x16x32_f16(aw.h8, ks ? q1b.h8 : q0b.h8, acc01, 0, 0, 0);
      }
    }
    // ---- distributed lw f32->bf16 swizzled conversion (rides latency shadows) ----
    if (lwsw && p < T && tid < 320){
      int slot = (gB*T + p)*320 + tid;   // 256*50*320 = 4,096,000 exactly
      int n = slot >> 7, rem = slot & 127;
      int k0c = rem >> 3, seg = rem & 7;
      const float4* src = (const float4*)(lw + (long)n*H + k0c*64 + seg*8);
      float4 v0 = src[0], v1 = src[1];
      uint4 pk;
      pk.x = pkbf(v0.x, v0.y); pk.y = pkbf(v0.z, v0.w);
      pk.z = pkbf(v1.x, v1.y); pk.w = pkbf(v1.z, v1.w);
      int bn = n >> 7, row = n & 127;
      lwsw[((long)(bn*16 + k0c)*128 + row)*8 + (seg ^ (row & 7))] = pk;
    }
    if (p >= 1){
      #pragma unroll
      for (int r = 0; r < 4; r++){
        partial[w][lk*4 + r][lrow]      = acc10[r];
        partial[w][lk*4 + r][16 + lrow] = acc11[r];
      }
    }
    __syncthreads();
    // ---- layer1(p-1) reduce + cell ----
    if (p >= 1 && tid < 512){
      int r = tid >> 5, bb = tid & 31;
      float s = 0.f;
      #pragma unroll
      for (int w2 = 0; w2 < 16; w2++) s += partial[w2][r][bb];
      float v = s + bs1v[r];
      gates[r][bb] = ((r >> 2) == 2) ? tanhf(v) : sigm(v);
    }
    __syncthreads();
    if (p >= 1 && tid < 32){
      int bb = tid, t1 = p - 1;
      float hn[4];
      #pragma unroll
      for (int hl = 0; hl < 4; hl++){
        float cn = gates[4+hl][bb]*cst[1][hl][bb] + gates[0+hl][bb]*gates[8+hl][bb];
        cst[1][hl][bb] = cn;
        hn[hl] = gates[12+hl][bb]*tanhf(cn);
        h1loc[hl][bb*T + t1] = (__fp16)hn[hl];
      }
      U32H2 z0, z1; z0.h = pk2(hn[0], hn[1]); z1.h = pk2(hn[2], hn[3]);
      uint2 val; val.x = z0.u; val.y = z1.u;
      stA8((char*)h1w + (long)(bb*1024 + 4*gB)*2, val);
    }
    // ---- layer0(p) partial stash ----
    if (p < T){
      #pragma unroll
      for (int r = 0; r < 4; r++){
        partial[w][lk*4 + r][lrow]      = acc00[r];
        partial[w][lk*4 + r][16 + lrow] = acc01[r];
      }
    }
    __syncthreads();
    if (p < T && tid < 512){
      int r = tid >> 5, bb = tid & 31;
      float s = 0.f;
      #pragma unroll
      for (int w2 = 0; w2 < 16; w2++) s += partial[w2][r][bb];
      float v = s + bs0v[r];
      gates[r][bb] = ((r >> 2) == 2) ? tanhf(v) : sigm(v);
    }
    __syncthreads();
    if (p < T && tid < 32){
      int bb = tid;
      float hn[4];
      #pragma unroll
      for (int hl = 0; hl < 4; hl++){
        float cn = gates[4+hl][bb]*cst[0][hl][bb] + gates[0+hl][bb]*gates[8+hl][bb];
        cst[0][hl][bb] = cn;
        hn[hl] = gates[12+hl][bb]*tanhf(cn);
      }
      U32H2 z0, z1; z0.h = pk2(hn[0], hn[1]); z1.h = pk2(hn[2], hn[3]);
      uint2 val; val.x = z0.u; val.y = z1.u;
      stA8((char*)h0w + (long)(bb*1024 + 4*gB)*2, val);
    }
    gbar(bar, ep); ep++;
  }

  // direct swizzled-Abf flush: block gB owns k = 4gB..4gB+3 (8B half-slot)
  {
    int k0c = gB >> 4;
    int seg = (gB & 15) >> 1;
    int posb = (gB & 1) * 8;
    for (int m = tid; m < B*T; m += 1024){
      float v0 = (float)h1loc[0][m], v1 = (float)h1loc[1][m];
      float v2 = (float)h1loc[2][m], v3 = (float)h1loc[3][m];
      int bm = m >> 7, row = m & 127;
      long slot = ((long)(bm*16 + k0c)*128 + row)*8 + (seg ^ (row & 7));
      uint2 val; val.x = pkbf(v0, v1); val.y = pkbf(v2, v3);
      *(uint2*)((char*)Abf + slot*16 + posb) = val;
    }
  }
}

// ---------------- fallback per-step cells ----------------
__global__ void k_init(const float* __restrict__ enc, float* __restrict__ h0, float* __restrict__ c0,
                       float* __restrict__ h1, float* __restrict__ c1){
  int idx = blockIdx.x*256 + threadIdx.x;
  int b = idx & 31, h = idx >> 5;
  float v = enc[b*H + h];
  h0[idx]=v; c0[idx]=v; h1[idx]=v; c1[idx]=v;
}

__global__ __launch_bounds__(256) void k_cell0(const float* __restrict__ whh, const float* __restrict__ xg_t,
                       const float* __restrict__ h_in, float* __restrict__ h_out,
                       float* __restrict__ c){
  int h = (blockIdx.x*256 + threadIdx.x) >> 6;
  int lane = threadIdx.x & 63;
  int b = lane & 31, kh = lane >> 5;
  const float* w0 = whh + (0*H + h)*H + kh*512;
  const float* w1 = whh + (1*H + h)*H + kh*512;
  const float* w2 = whh + (2*H + h)*H + kh*512;
  const float* w3 = whh + (3*H + h)*H + kh*512;
  const float* hk = h_in + (kh*512)*B + b;
  float a0=0,a1=0,a2=0,a3=0, p0=0,p1=0,p2=0,p3=0;
  #pragma unroll 4
  for (int k=0;k<512;k+=4){
    float4 w40 = *(const float4*)(w0+k);
    float4 w41 = *(const float4*)(w1+k);
    float4 w42 = *(const float4*)(w2+k);
    float4 w43 = *(const float4*)(w3+k);
    float hv0 = hk[(k+0)*B], hv1 = hk[(k+1)*B], hv2 = hk[(k+2)*B], hv3 = hk[(k+3)*B];
    a0 += w40.x*hv0 + w40.y*hv1;  p0 += w40.z*hv2 + w40.w*hv3;
    a1 += w41.x*hv0 + w41.y*hv1;  p1 += w41.z*hv2 + w41.w*hv3;
    a2 += w42.x*hv0 + w42.y*hv1;  p2 += w42.z*hv2 + w42.w*hv3;
    a3 += w43.x*hv0 + w43.y*hv1;  p3 += w43.z*hv2 + w43.w*hv3;
  }
  float g0=a0+p0, g1=a1+p1, g2=a2+p2, g3=a3+p3;
  g0 += __shfl_xor(g0, 32);
  g1 += __shfl_xor(g1, 32);
  g2 += __shfl_xor(g2, 32);
  g3 += __shfl_xor(g3, 32);
  g0 += xg_t[(0*H+h)*B + b];
  g1 += xg_t[(1*H+h)*B + b];
  g2 += xg_t[(2*H+h)*B + b];
  g3 += xg_t[(3*H+h)*B + b];
  float ig = sigm(g0), fg = sigm(g1), gg = tanhf(g2), og = sigm(g3);
  int sidx = h*B + b;
  float cn = fg*c[sidx] + ig*gg;
  float hn = og*tanhf(cn);
  if (kh==0){ c[sidx]=cn; h_out[sidx]=hn; }
}

__global__ __launch_bounds__(256) void k_cell1(const float* __restrict__ wih, const float* __restrict__ whh,
                       const float* __restrict__ bih, const float* __restrict__ bhh,
                       const float* __restrict__ h0n, const float* __restrict__ h_in,
                       float* __restrict__ h_out, float* __restrict__ c,
                       float* __restrict__ H1Tmk, int t){
  int h = (blockIdx.x*256 + threadIdx.x) >> 6;
  int lane = threadIdx.x & 63;
  int b = lane & 31, kh = lane >> 5;
  float a0=0,a1=0,a2=0,a3=0, p0=0,p1=0,p2=0,p3=0;
  {
    const float* w0 = wih + (0*H + h)*H + kh*512;
    const float* w1 = wih + (1*H + h)*H + kh*512;
    const float* w2 = wih + (2*H + h)*H + kh*512;
    const float* w3 = wih + (3*H + h)*H + kh*512;
    const float* hk = h0n + (kh*512)*B + b;
    #pragma unroll 4
    for (int k=0;k<512;k+=4){
      float4 w40 = *(const float4*)(w0+k);
      float4 w41 = *(const float4*)(w1+k);
      float4 w42 = *(const float4*)(w2+k);
      float4 w43 = *(const float4*)(w3+k);
      float hv0 = hk[(k+0)*B], hv1 = hk[(k+1)*B], hv2 = hk[(k+2)*B], hv3 = hk[(k+3)*B];
      a0 += w40.x*hv0 + w40.y*hv1;  p0 += w40.z*hv2 + w40.w*hv3;
      a1 += w41.x*hv0 + w41.y*hv1;  p1 += w41.z*hv2 + w41.w*hv3;
      a2 += w42.x*hv0 + w42.y*hv1;  p2 += w42.z*hv2 + w42.w*hv3;
      a3 += w43.x*hv0 + w43.y*hv1;  p3 += w43.z*hv2 + w43.w*hv3;
    }
  }
  {
    const float* w0 = whh + (0*H + h)*H + kh*512;
    const float* w1 = whh + (1*H + h)*H + kh*512;
    const float* w2 = whh + (2*H + h)*H + kh*512;
    const float* w3 = whh + (3*H + h)*H + kh*512;
    const float* hk = h_in + (kh*512)*B + b;
    #pragma unroll 4
    for (int k=0;k<512;k+=4){
      float4 w40 = *(const float4*)(w0+k);
      float4 w41 = *(const float4*)(w1+k);
      float4 w42 = *(const float4*)(w2+k);
      float4 w43 = *(const float4*)(w3+k);
      float hv0 = hk[(k+0)*B], hv1 = hk[(k+1)*B], hv2 = hk[(k+2)*B], hv3 = hk[(k+3)*B];
      a0 += w40.x*hv0 + w40.y*hv1;  p0 += w40.z*hv2 + w40.w*hv3;
      a1 += w41.x*hv0 + w41.y*hv1;  p1 += w41.z*hv2 + w41.w*hv3;
      a2 += w42.x*hv0 + w42.y*hv1;  p2 += w42.z*hv2 + w42.w*hv3;
      a3 += w43.x*hv0 + w43.y*hv1;  p3 += w43.z*hv2 + w43.w*hv3;
    }
  }
  float g0=a0+p0, g1=a1+p1, g2=a2+p2, g3=a3+p3;
  g0 += __shfl_xor(g0, 32);
  g1 += __shfl_xor(g1, 32);
  g2 += __shfl_xor(g2, 32);
  g3 += __shfl_xor(g3, 32);
  g0 += bih[0*H+h] + bhh[0*H+h];
  g1 += bih[1*H+h] + bhh[1*H+h];
  g2 += bih[2*H+h] + bhh[2*H+h];
  g3 += bih[3*H+h] + bhh[3*H+h];
  float ig = sigm(g0), fg = sigm(g1), gg = tanhf(g2), og = sigm(g3);
  int sidx = h*B + b;
  float cn = fg*c[sidx] + ig*gg;
  float hn = og*tanhf(cn);
  if (kh==0){ c[sidx]=cn; h_out[sidx]=hn; H1Tmk[((long)(b*T + t))*1024 + h] = hn; }
}

// ---------------- MFMA bf16 output GEMM (pre-swizzled operands) ----------------
__global__ __launch_bounds__(256, 2) void k_gemm_pre(const uint4* __restrict__ Abf4,
                      const uint4* __restrict__ Wsw4, const float* __restrict__ lb,
                      float* __restrict__ out){
  __shared__ uint4 As4[1024];
  __shared__ uint4 Ws4[1024];
  const int tid = threadIdx.x;
  int orig = blockIdx.x;
  int xcd = orig & 7, ii = orig >> 3;
  int wgid = (xcd < 2 ? xcd*407 : 814 + (xcd-2)*406) + ii;
  int bm = wgid % 13, bn = wgid / 13;
  int m0 = bm*128, n0 = bn*128;
  const int wv = tid >> 6, l = tid & 63;
  const int wm = (wv >> 1)*64, wn = (wv & 1)*64;
  const int lrow = l & 15, lk = l >> 4;

  floatx4 acc[4][4] = {};
  for (int k0c = 0; k0c < 16; k0c++){
    const uint4* sA = Abf4 + (long)(bm*16 + k0c)*1024;
    const uint4* sW = Wsw4 + (long)(bn*16 + k0c)*1024;
    #pragma unroll
    for (int it = 0; it < 4; it++){
      int slot = tid + it*256;
      As4[slot] = sA[slot];
      Ws4[slot] = sW[slot];
    }
    __syncthreads();
    #pragma unroll
    for (int ks = 0; ks < 2; ks++){
      short8 af[4], bf_[4];
      #pragma unroll
      for (int fi = 0; fi < 4; fi++){
        int row = wm + fi*16 + lrow;
        U16S8 u; u.u4 = As4[row*8 + ((ks*4 + lk) ^ (lrow & 7))];
        af[fi] = u.s8;
      }
      #pragma unroll
      for (int fj = 0; fj < 4; fj++){
        int row = wn + fj*16 + lrow;
        U16S8 u; u.u4 = Ws4[row*8 + ((ks*4 + lk) ^ (lrow & 7))];
        bf_[fj] = u.s8;
      }
      #pragma unroll
      for (int fi = 0; fi < 4; fi++)
        #pragma unroll
        for (int fj = 0; fj < 4; fj++)
          acc[fi][fj] = __builtin_amdgcn_mfma_f32_16x16x32_bf16(af[fi], bf_[fj], acc[fi][fj], 0, 0, 0);
    }
    __syncthreads();
  }
  #pragma unroll
  for (int fj = 0; fj < 4; fj++){
    int n = n0 + wn + fj*16 + lrow;
    float bias = lb[n];
    #pragma unroll
    for (int fi = 0; fi < 4; fi++){
      floatx4 av = acc[fi][fj];
      int mb = m0 + wm + fi*16 + lk*4;
      #pragma unroll
      for (int r = 0; r < 4; r++){
        int m = mb + r;
        if (m < B*T) out[(long)m*V + n] = av[r] + bias;
      }
    }
  }
}

// fallback GEMM: A pre-swizzled, W converted inline from f32
__global__ __launch_bounds__(256, 2) void k_gemm_inl(const uint4* __restrict__ Abf4,
                      const float* __restrict__ lw, const float* __restrict__ lb,
                      float* __restrict__ out){
  __shared__ uint4 As4[1024];
  __shared__ uint4 Ws4[1024];
  const int tid = threadIdx.x;
  int orig = blockIdx.x;
  int xcd = orig & 7, ii = orig >> 3;
  int wgid = (xcd < 2 ? xcd*407 : 814 + (xcd-2)*406) + ii;
  int bm = wgid % 13, bn = wgid / 13;
  int m0 = bm*128, n0 = bn*128;
  const int wv = tid >> 6, l = tid & 63;
  const int wm = (wv >> 1)*64, wn = (wv & 1)*64;
  const int lrow = l & 15, lk = l >> 4;

  floatx4 acc[4][4] = {};
  for (int k0c = 0; k0c < 16; k0c++){
    const uint4* sA = Abf4 + (long)(bm*16 + k0c)*1024;
    #pragma unroll
    for (int it = 0; it < 4; it++){
      int slot = tid + it*256;
      As4[slot] = sA[slot];
      int row = slot >> 3, seg = slot & 7;
      const float4* src = (const float4*)(lw + (long)(n0+row)*H + k0c*64 + seg*8);
      float4 v0 = src[0], v1 = src[1];
      uint4 pk;
      pk.x = pkbf(v0.x, v0.y); pk.y = pkbf(v0.z, v0.w);
      pk.z = pkbf(v1.x, v1.y); pk.w = pkbf(v1.z, v1.w);
      Ws4[row*8 + (seg ^ (row & 7))] = pk;
    }
    __syncthreads();
    #pragma unroll
    for (int ks = 0; ks < 2; ks++){
      short8 af[4], bf_[4];
      #pragma unroll
      for (int fi = 0; fi < 4; fi++){
        int row = wm + fi*16 + lrow;
        U16S8 u; u.u4 = As4[row*8 + ((ks*4 + lk) ^ (lrow & 7))];
        af[fi] = u.s8;
      }
      #pragma unroll
      for (int fj = 0; fj < 4; fj++){
        int row = wn + fj*16 + lrow;
        U16S8 u; u.u4 = Ws4[row*8 + ((ks*4 + lk) ^ (lrow & 7))];
        bf_[fj] = u.s8;
      }
      #pragma unroll
      for (int fi = 0; fi < 4; fi++)
        #pragma unroll
        for (int fj = 0; fj < 4; fj++)
          acc[fi][fj] = __builtin_amdgcn_mfma_f32_16x16x32_bf16(af[fi], bf_[fj], acc[fi][fj], 0, 0, 0);
    }
    __syncthreads();
  }
  #pragma unroll
  for (int fj = 0; fj < 4; fj++){
    int n = n0 + wn + fj*16 + lrow;
    float bias = lb[n];
    #pragma unroll
    for (int fi = 0; fi < 4; fi++){
      floatx4 av = acc[fi][fj];
      int mb = m0 + wm + fi*16 + lk*4;
      #pragma unroll
      for (int r = 0; r < 4; r++){
        int m = mb + r;
        if (m < B*T) out[(long)m*V + n] = av[r] + bias;
      }
    }
  }
}

// log-softmax with row cached in LDS (read out once, write once)
__global__ __launch_bounds__(1024) void k_lsm(float* __restrict__ out){
  __shared__ float4 rowbuf[V/4];          // 128 KB
  __shared__ float redm[1024], reds[1024];
  float4* row = (float4*)(out + (long)blockIdx.x * V);
  const int tid = threadIdx.x;
  float m = -INFINITY, s = 0.f;
  for (int n=tid;n<V/4;n+=1024){
    float4 v = row[n];
    rowbuf[n] = v;
    float cm = fmaxf(fmaxf(v.x,v.y), fmaxf(v.z,v.w));
    if (cm > m){ s *= __expf(m - cm); m = cm; }
    s += __expf(v.x-m)+__expf(v.y-m)+__expf(v.z-m)+__expf(v.w-m);
  }
  redm[tid]=m; reds[tid]=s; __syncthreads();
  for (int st=512;st>0;st>>=1){
    if (tid<st){
      float m1=redm[tid], s1=reds[tid];
      float m2=redm[tid+st], s2=reds[tid+st];
      float M=fmaxf(m1,m2);
      reds[tid]=s1*__expf(m1-M)+s2*__expf(m2-M);
      redm[tid]=M;
    }
    __syncthreads();
  }
  float lse = redm[0] + __logf(reds[0]);
  for (int n=tid;n<V/4;n+=1024){
    float4 v = rowbuf[n];
    v.x-=lse; v.y-=lse; v.z-=lse; v.w-=lse;
    row[n] = v;
  }
}

extern "C" void kernel_launch(void* const* d_in, const int* in_sizes, int n_in,
                              void* d_out, int out_size, void* d_ws, size_t ws_size,
                              hipStream_t stream){
  const float* enc    = (const float*)d_in[0];
  const float* target = (const float*)d_in[1];
  const float* pw     = (const float*)d_in[2];
  const float* pb     = (const float*)d_in[3];
  const float* wih0   = (const float*)d_in[4];
  const float* whh0   = (const float*)d_in[5];
  const float* bih0   = (const float*)d_in[6];
  const float* bhh0   = (const float*)d_in[7];
  const float* wih1   = (const float*)d_in[8];
  const float* whh1   = (const float*)d_in[9];
  const float* bih1   = (const float*)d_in[10];
  const float* bhh1   = (const float*)d_in[11];
  const float* lw     = (const float*)d_in[12];
  const float* lb     = (const float*)d_in[13];
  float* out = (float*)d_out;

  float* ws   = (float*)d_ws;
  float* xg0  = ws;                              // 6,553,600 f (fallback)
  float* P    = xg0 + (long)T*G4*B;              // 204,800 f (fallback)
  float* encp = P + T*E*B;                       // 4,096 f
  float* H1Tmk = encp + B*E;                     // 1,703,936 f (fallback)
  unsigned* Abf = (unsigned*)(H1Tmk + (long)MROWS*1024);  // 851,968 u32
  unsigned* h0A2 = Abf + 851968;                 // 16,384 each (64KB f16 state)
  unsigned* h0B2 = h0A2 + 16384;
  unsigned* h1A2 = h0B2 + 16384;
  unsigned* h1B2 = h1A2 + 16384;
  float* fh0a = (float*)(h1B2 + 16384);          // fallback f32 state
  float* fh0b = fh0a + H*B;
  float* fh1a = fh0b + H*B;
  float* fh1b = fh1a + H*B;
  float* fc0  = fh1b + H*B;
  float* fc1  = fc0 + H*B;
  unsigned* bar = (unsigned*)(fc1 + H*B);        // 1,024 u32
  __fp16* Pf16 = (__fp16*)(bar + 1024);          // 204,800 f16
  unsigned* lwsw = (unsigned*)(Pf16 + (long)T*B*E);  // 16,384,000 u32
  size_t need = (size_t)((char*)(lwsw + 16384000) - (char*)d_ws);
  bool pre = (ws_size >= need);

  k_encp<<<B, E, 0, stream>>>(enc, pw, pb, encp);
  k_proj<<<T*B, E, 0, stream>>>(target, pw, encp, P, Pf16);
  k_zero32<<<4, 256, 0, stream>>>(bar);

  uint4* lwsw4 = pre ? (uint4*)lwsw : (uint4*)0;
  void* cargs[] = {(void*)&whh0, (void*)&wih1, (void*)&whh1,
                   (void*)&wih0, (void*)&bih0, (void*)&bhh0,
                   (void*)&bih1, (void*)&bhh1,
                   (void*)&enc, (void*)&Pf16,
                   (void*)&lw, (void*)&lwsw4,
                   (void*)&h0A2, (void*)&h0B2, (void*)&h1A2, (void*)&h1B2,
                   (void*)&Abf, (void*)&bar};
  hipError_t cerr = hipLaunchCooperativeKernel((void*)k_cells, dim3(NB), dim3(1024),
                                               cargs, 0, stream);
  if (cerr != hipSuccess){
    if (pre) k_cvtw<<<16000, 256, 0, stream>>>(lw, (uint4*)lwsw);
    k_xg0<<<(T*G4*B)/256, 256, 0, stream>>>(wih0, bih0, bhh0, P, xg0);
    k_init<<<(H*B)/256, 256, 0, stream>>>(enc, fh0a, fc0, fh1a, fc1);
    float* h0in=fh0a; float* h0out=fh0b;
    float* h1in=fh1a; float* h1out=fh1b;
    for (int t=0;t<T;t++){
      k_cell0<<<256, 256, 0, stream>>>(whh0, xg0 + (long)t*G4*B, h0in, h0out, fc0);
      k_cell1<<<256, 256, 0, stream>>>(wih1, whh1, bih1, bhh1, h0out, h1in, h1out, fc1,
                                       H1Tmk, t);
      float* tmp;
      tmp=h0in; h0in=h0out; h0out=tmp;
      tmp=h1in; h1in=h1out; h1out=tmp;
    }
    k_pack<<<800, 256, 0, stream>>>(H1Tmk, (uint4*)Abf);
  }

  if (pre) k_gemm_pre<<<3250, 256, 0, stream>>>((const uint4*)Abf, (const uint4*)lwsw, lb, out);
  else     k_gemm_inl<<<3250, 256, 0, stream>>>((const uint4*)Abf, lw, lb, out);
  k_lsm<<<B*T, 1024, 0, stream>>>(out);
}

// Round 22
// 793.253 us; speedup vs baseline: 1.3476x; 1.0044x over previous
//
#include <hip/hip_runtime.h>
#include <hip/hip_bf16.h>
#include <math.h>

#define B 32
#define T 50
#define H 1024
#define E 128
#define V 32000
#define G4 4096   // 4*H
#define HE 1152   // H+E
#define MROWS 1664 // 13*128 padded M for GEMM
#define NB 256    // coop grid blocks

typedef __fp16 half2v __attribute__((ext_vector_type(2)));
typedef __fp16 half8 __attribute__((ext_vector_type(8)));
typedef unsigned long long ull;
union U32H2 { unsigned u; half2v h; };
union U4H8 { uint4 u4; half8 h8; };
typedef short short8 __attribute__((ext_vector_type(8)));
typedef float floatx4 __attribute__((ext_vector_type(4)));
union U16S8 { uint4 u4; short8 s8; };

// 16B LLC-coherent load (bypass L1+L2), issue-only; pair with one vmcnt wait.
#define LLC_LOAD(dst, ptr) \
  asm volatile("global_load_dwordx4 %0, %1, off sc0 sc1" : "=v"((dst).u4) : "v"(ptr))

__device__ __forceinline__ float sigm(float x){ return 1.0f/(1.0f+expf(-x)); }

__device__ __forceinline__ half2v pk2(float a, float b){
#if __has_builtin(__builtin_amdgcn_cvt_pkrtz)
  return __builtin_amdgcn_cvt_pkrtz(a, b);
#else
  half2v r; r.x = (__fp16)a; r.y = (__fp16)b; return r;
#endif
}

// pack two f32 -> one u32 of two bf16 (RNE)
__device__ __forceinline__ unsigned pkbf(float a, float b){
  unsigned ua = __float_as_uint(a), ub = __float_as_uint(b);
  unsigned ra = (ua + 0x7FFFu + ((ua>>16)&1u)) >> 16;
  unsigned rb = (ub + 0x7FFFu + ((ub>>16)&1u)) >> 16;
  return ra | (rb << 16);
}

// agent-scope store, 8B (bypasses caches, lands at LLC)
__device__ __forceinline__ void stA8(void* p, uint2 v){
  ull q = ((ull)v.y << 32) | (ull)v.x;
  __hip_atomic_store((ull*)p, q, __ATOMIC_RELAXED, __HIP_MEMORY_SCOPE_AGENT);
}

// ---- fence-free tree grid barrier (8 leaves x 32 + root) — r17 verified ----
__device__ __forceinline__ void gbar(unsigned* bar, unsigned ep){
  __syncthreads();
  if (threadIdx.x == 0){
    asm volatile("s_waitcnt vmcnt(0)" ::: "memory");
    unsigned g = blockIdx.x & 7u;
    unsigned old = __hip_atomic_fetch_add(&bar[64 + g*64], 1u,
                     __ATOMIC_RELAXED, __HIP_MEMORY_SCOPE_AGENT);
    if (old == ep*32u - 1u)
      __hip_atomic_fetch_add(&bar[0], 1u, __ATOMIC_RELAXED, __HIP_MEMORY_SCOPE_AGENT);
    while (__hip_atomic_load(&bar[0], __ATOMIC_RELAXED, __HIP_MEMORY_SCOPE_AGENT) < ep*8u)
      __builtin_amdgcn_s_sleep(1);
  }
  __syncthreads();
}

// encp[b][e] = proj_b[e] + sum_j enc[b][j] * proj_w[e][E+j]
__global__ void k_encp(const float* __restrict__ enc, const float* __restrict__ pw,
                       const float* __restrict__ pb, float* __restrict__ encp){
  int b = blockIdx.x, e = threadIdx.x;
  const float* er = enc + b*H;
  const float* wr = pw + e*HE + E;
  float acc = pb[e];
  for (int j=0;j<H;j+=4){
    float4 w4 = *(const float4*)(wr+j);
    float4 e4 = *(const float4*)(er+j);
    acc += w4.x*e4.x + w4.y*e4.y + w4.z*e4.z + w4.w*e4.w;
  }
  encp[b*E+e] = acc;
}

// P[t][e][b] f32 (fallback) + Pf16[t][b][e] (coop MFMA B-operand)
__global__ void k_proj(const float* __restrict__ target, const float* __restrict__ pw,
                       const float* __restrict__ encp, float* __restrict__ P,
                       __fp16* __restrict__ Pf16){
  int t = blockIdx.x / B, b = blockIdx.x % B, e = threadIdx.x;
  const float* xr = target + (b*T + t)*E;
  const float* wr = pw + e*HE;
  float acc = encp[b*E+e];
  for (int j=0;j<E;j+=4){
    float4 w4 = *(const float4*)(wr+j);
    float4 x4 = *(const float4*)(xr+j);
    acc += w4.x*x4.x + w4.y*x4.y + w4.z*x4.z + w4.w*x4.w;
  }
  P[(t*E + e)*B + b] = acc;
  Pf16[((long)t*B + b)*E + e] = (__fp16)acc;
}

// xg0[t][r][b] (fallback path only)
__global__ void k_xg0(const float* __restrict__ wih0, const float* __restrict__ bih0,
                      const float* __restrict__ bhh0, const float* __restrict__ P,
                      float* __restrict__ xg){
  int idx = blockIdx.x*256 + threadIdx.x;
  int b = idx & 31; int r = (idx >> 5) & 4095; int t = idx >> 17;
  const float* wr = wih0 + r*E;
  const float* pr = P + t*E*B + b;
  float acc = bih0[r] + bhh0[r];
  #pragma unroll 8
  for (int e=0;e<E;e+=4){
    float4 w4 = *(const float4*)(wr+e);
    acc += w4.x*pr[(e+0)*B] + w4.y*pr[(e+1)*B]
         + w4.z*pr[(e+2)*B] + w4.w*pr[(e+3)*B];
  }
  xg[idx] = acc;
}

__global__ void k_zero32(unsigned* __restrict__ p){
  p[blockIdx.x*256 + threadIdx.x] = 0u;
}

// convert lw f32 -> bf16 in the GEMM's swizzled tile layout (fallback path only)
__global__ void k_cvtw(const float* __restrict__ lw, uint4* __restrict__ wsw){
  int gid = blockIdx.x*256 + threadIdx.x;   // 4,096,000
  int n = gid >> 7, rem = gid & 127;
  int k0c = rem >> 3, seg = rem & 7;
  const float4* src = (const float4*)(lw + (long)n*H + k0c*64 + seg*8);
  float4 v0 = src[0], v1 = src[1];
  uint4 pk;
  pk.x = pkbf(v0.x, v0.y); pk.y = pkbf(v0.z, v0.w);
  pk.z = pkbf(v1.x, v1.y); pk.w = pkbf(v1.z, v1.w);
  int bn = n >> 7, row = n & 127;
  wsw[((long)(bn*16 + k0c)*128 + row)*8 + (seg ^ (row & 7))] = pk;
}

// pack H1Tmk f32 [m][k] -> Abf swizzled bf16 tiles (fallback path only)
__global__ void k_pack(const float* __restrict__ H1Tmk, uint4* __restrict__ Abf){
  int gid = blockIdx.x*256 + threadIdx.x;   // 204,800
  int m = gid >> 7, rem = gid & 127;
  int k0c = rem >> 3, seg = rem & 7;
  const float4* src = (const float4*)(H1Tmk + (long)m*1024 + k0c*64 + seg*8);
  float4 v0 = src[0], v1 = src[1];
  uint4 pk;
  pk.x = pkbf(v0.x, v0.y); pk.y = pkbf(v0.z, v0.w);
  pk.z = pkbf(v1.x, v1.y); pk.w = pkbf(v1.z, v1.w);
  int bm = m >> 7, row = m & 127;
  Abf[((long)(bm*16 + k0c)*128 + row)*8 + (seg ^ (row & 7))] = pk;
}

// ---------------- cooperative persistent cells (v15: cvtw off the barrier wave) ----------------
__global__ __launch_bounds__(1024, 4) void k_cells(
    const float* __restrict__ whh0, const float* __restrict__ wih1, const float* __restrict__ whh1,
    const float* __restrict__ wih0, const float* __restrict__ bih0, const float* __restrict__ bhh0,
    const float* __restrict__ bih1, const float* __restrict__ bhh1,
    const float* __restrict__ enc, const __fp16* __restrict__ Pf16,
    const float* __restrict__ lw, uint4* __restrict__ lwsw,
    unsigned* __restrict__ h0A2, unsigned* __restrict__ h0B2,
    unsigned* __restrict__ h1A2, unsigned* __restrict__ h1B2,
    unsigned* __restrict__ Abf, unsigned* __restrict__ bar){
  const int gB = blockIdx.x;
  const int tid = threadIdx.x;
  const int w = tid >> 6;       // wave 0..15 = k-chunk owner
  const int l = tid & 63;
  const int lrow = l & 15;      // fragment row/col
  const int lk = l >> 4;        // k-segment 0..3

  __shared__ uint4 w0s4[16*128];        // layer0 whh0 rows, f16 swizzled (32 KB)
  __shared__ uint4 w1s4[32*128];        // wih1(0-15)+whh1(16-31) (64 KB)
  __shared__ uint4 w0x4[16*16];         // layer0 wih0 rows, f16 swizzled (4 KB)
  __shared__ float partial[16][16][34]; // [wave][row][b-col] pad 34
  __shared__ float gates[16][32];
  __shared__ float cst[2][4][32];
  __shared__ float bs1v[16];
  __shared__ float bs0v[16];
  __shared__ __fp16 h1loc[4][1600];     // [hl][b*T+t] (12.8 KB)

  // ---- stage weights f32 -> f16, XOR-swizzled segments ----
  for (int i = tid; i < 2048; i += 1024){
    int row = i >> 7, seg = i & 127;
    int q = row >> 2, hl = row & 3;
    const float* src = whh0 + ((long)q*H + 4*gB + hl)*H + seg*8;
    float4 v0 = *(const float4*)src, v1 = *(const float4*)(src+4);
    U32H2 z0,z1,z2,z3;
    z0.h = pk2(v0.x,v0.y); z1.h = pk2(v0.z,v0.w);
    z2.h = pk2(v1.x,v1.y); z3.h = pk2(v1.z,v1.w);
    uint4 pk; pk.x=z0.u; pk.y=z1.u; pk.z=z2.u; pk.w=z3.u;
    int phys = (seg & ~7) | ((seg & 7) ^ (row & 7));
    w0s4[row*128 + phys] = pk;
  }
  for (int i = tid; i < 4096; i += 1024){
    int row = i >> 7, seg = i & 127;
    int rr = row & 15;
    int q = rr >> 2, hl = rr & 3;
    const float* srcm = (row < 16) ? wih1 : whh1;
    const float* src = srcm + ((long)q*H + 4*gB + hl)*H + seg*8;
    float4 v0 = *(const float4*)src, v1 = *(const float4*)(src+4);
    U32H2 z0,z1,z2,z3;
    z0.h = pk2(v0.x,v0.y); z1.h = pk2(v0.z,v0.w);
    z2.h = pk2(v1.x,v1.y); z3.h = pk2(v1.z,v1.w);
    uint4 pk; pk.x=z0.u; pk.y=z1.u; pk.z=z2.u; pk.w=z3.u;
    int phys = (seg & ~7) | ((seg & 7) ^ (rr & 7));
    w1s4[row*128 + phys] = pk;
  }
  if (tid < 256){
    int row = tid >> 4, seg = tid & 15;
    int q = row >> 2, hl = row & 3;
    const float* src = wih0 + ((long)q*H + 4*gB + hl)*E + seg*8;
    float4 v0 = *(const float4*)src, v1 = *(const float4*)(src+4);
    U32H2 z0,z1,z2,z3;
    z0.h = pk2(v0.x,v0.y); z1.h = pk2(v0.z,v0.w);
    z2.h = pk2(v1.x,v1.y); z3.h = pk2(v1.z,v1.w);
    uint4 pk; pk.x=z0.u; pk.y=z1.u; pk.z=z2.u; pk.w=z3.u;
    int phys = (seg & ~7) | ((seg & 7) ^ (row & 7));
    w0x4[row*16 + phys] = pk;
  }
  if (tid < 16){
    int q = tid >> 2, hl = tid & 3;
    bs1v[tid] = bih1[q*H + 4*gB + hl] + bhh1[q*H + 4*gB + hl];
    bs0v[tid] = bih0[q*H + 4*gB + hl] + bhh0[q*H + 4*gB + hl];
  }
  if (tid < 128){
    int hl = tid >> 5, bb = tid & 31;
    float v = enc[bb*H + 4*gB + hl];
    cst[0][hl][bb] = v; cst[1][hl][bb] = v;
  }
  if (tid < 32){
    int bb = tid;
    U32H2 z0, z1;
    z0.h = pk2(enc[bb*H + 4*gB + 0], enc[bb*H + 4*gB + 1]);
    z1.h = pk2(enc[bb*H + 4*gB + 2], enc[bb*H + 4*gB + 3]);
    uint2 val; val.x = z0.u; val.y = z1.u;
    stA8((char*)h0A2 + (long)(bb*1024 + 4*gB)*2, val);
    stA8((char*)h1A2 + (long)(bb*1024 + 4*gB)*2, val);
  }
  unsigned ep = 1;
  gbar(bar, ep); ep++;

  for (int p = 0; p <= T; p++){
    const unsigned* h0r = (p & 1) ? h0B2 : h0A2;
    unsigned*       h0w = (p & 1) ? h0A2 : h0B2;
    const unsigned* h1r = (p & 1) ? h1A2 : h1B2;
    unsigned*       h1w = (p & 1) ? h1B2 : h1A2;

    // ---- batched LLC state loads (issue all, wait once) ----
    int c = (w + gB + p) & 15;
    U4H8 b0a0, b0a1, b0b0, b0b1, b1a0, b1a1, b1b0, b1b1;
    {
      int kb = c*64;
      const __fp16* h0f = (const __fp16*)h0r;
      const __fp16* h1f = (const __fp16*)h1r;
      const __fp16* s0a = h0f + lrow*1024 + kb + lk*8;
      const __fp16* s0b = h0f + (16+lrow)*1024 + kb + lk*8;
      LLC_LOAD(b0a0, s0a);      LLC_LOAD(b0a1, s0a + 32);
      LLC_LOAD(b0b0, s0b);      LLC_LOAD(b0b1, s0b + 32);
      if (p >= 1){
        const __fp16* s1a = h1f + lrow*1024 + kb + lk*8;
        const __fp16* s1b = h1f + (16+lrow)*1024 + kb + lk*8;
        LLC_LOAD(b1a0, s1a);    LLC_LOAD(b1a1, s1a + 32);
        LLC_LOAD(b1b0, s1b);    LLC_LOAD(b1b1, s1b + 32);
      }
      asm volatile("s_waitcnt vmcnt(0)" ::: "memory");
      __builtin_amdgcn_sched_barrier(0);
    }

    // ---- MFMA matvec ----
    floatx4 acc10 = {0,0,0,0}, acc11 = {0,0,0,0};
    floatx4 acc00 = {0,0,0,0}, acc01 = {0,0,0,0};
    #pragma unroll
    for (int ks = 0; ks < 2; ks++){
      int phys = c*8 + (((ks<<2) + lk) ^ (lrow & 7));
      half8 B0a = ks ? b0a1.h8 : b0a0.h8;
      half8 B0b = ks ? b0b1.h8 : b0b0.h8;
      if (p < T){
        U4H8 a0v; a0v.u4 = w0s4[lrow*128 + phys];
        acc00 = __builtin_amdgcn_mfma_f32_16x16x32_f16(a0v.h8, B0a, acc00, 0, 0, 0);
        acc01 = __builtin_amdgcn_mfma_f32_16x16x32_f16(a0v.h8, B0b, acc01, 0, 0, 0);
      }
      if (p >= 1){
        U4H8 a1i; a1i.u4 = w1s4[lrow*128 + phys];
        U4H8 a1h; a1h.u4 = w1s4[(16+lrow)*128 + phys];
        half8 B1a = ks ? b1a1.h8 : b1a0.h8;
        half8 B1b = ks ? b1b1.h8 : b1b0.h8;
        acc10 = __builtin_amdgcn_mfma_f32_16x16x32_f16(a1i.h8, B0a, acc10, 0, 0, 0);
        acc10 = __builtin_amdgcn_mfma_f32_16x16x32_f16(a1h.h8, B1a, acc10, 0, 0, 0);
        acc11 = __builtin_amdgcn_mfma_f32_16x16x32_f16(a1i.h8, B0b, acc11, 0, 0, 0);
        acc11 = __builtin_amdgcn_mfma_f32_16x16x32_f16(a1h.h8, B1b, acc11, 0, 0, 0);
      }
    }
    // ---- fused xg contribution: waves with c<2 add wih0 . P_t ----
    if (p < T && c < 2){
      const __fp16* pbase = Pf16 + (long)p*B*E + c*64 + lk*8;
      U4H8 q0a, q1a, q0b, q1b;
      q0a.u4 = *(const uint4*)(pbase + lrow*E);
      q1a.u4 = *(const uint4*)(pbase + lrow*E + 32);
      q0b.u4 = *(const uint4*)(pbase + (16+lrow)*E);
      q1b.u4 = *(const uint4*)(pbase + (16+lrow)*E + 32);
      #pragma unroll
      for (int ks = 0; ks < 2; ks++){
        int phys = c*8 + (((ks<<2) + lk) ^ (lrow & 7));
        U4H8 aw; aw.u4 = w0x4[lrow*16 + phys];
        acc00 = __builtin_amdgcn_mfma_f32_16x16x32_f16(aw.h8, ks ? q1a.h8 : q0a.h8, acc00, 0, 0, 0);
        acc01 = __builtin_amdgcn_mfma_f32_16x16x32_f16(aw.h8, ks ? q1b.h8 : q0b.h8, acc01, 0, 0, 0);
      }
    }
    // ---- distributed lw f32->bf16 conversion on waves 2..6 (off barrier wave) ----
    if (lwsw && p < T && tid >= 128 && tid < 448){
      int slot = (gB*T + p)*320 + (tid - 128);   // 256*50*320 = 4,096,000 exactly
      int n = slot >> 7, rem = slot & 127;
      int k0c = rem >> 3, seg = rem & 7;
      const float4* src = (const float4*)(lw + (long)n*H + k0c*64 + seg*8);
      float4 v0 = src[0], v1 = src[1];
      uint4 pk;
      pk.x = pkbf(v0.x, v0.y); pk.y = pkbf(v0.z, v0.w);
      pk.z = pkbf(v1.x, v1.y); pk.w = pkbf(v1.z, v1.w);
      int bn = n >> 7, row = n & 127;
      lwsw[((long)(bn*16 + k0c)*128 + row)*8 + (seg ^ (row & 7))] = pk;
    }
    if (p >= 1){
      #pragma unroll
      for (int r = 0; r < 4; r++){
        partial[w][lk*4 + r][lrow]      = acc10[r];
        partial[w][lk*4 + r][16 + lrow] = acc11[r];
      }
    }
    __syncthreads();
    // ---- layer1(p-1) reduce + cell ----
    if (p >= 1 && tid < 512){
      int r = tid >> 5, bb = tid & 31;
      float s = 0.f;
      #pragma unroll
      for (int w2 = 0; w2 < 16; w2++) s += partial[w2][r][bb];
      float v = s + bs1v[r];
      gates[r][bb] = ((r >> 2) == 2) ? tanhf(v) : sigm(v);
    }
    __syncthreads();
    if (p >= 1 && tid < 32){
      int bb = tid, t1 = p - 1;
      float hn[4];
      #pragma unroll
      for (int hl = 0; hl < 4; hl++){
        float cn = gates[4+hl][bb]*cst[1][hl][bb] + gates[0+hl][bb]*gates[8+hl][bb];
        cst[1][hl][bb] = cn;
        hn[hl] = gates[12+hl][bb]*tanhf(cn);
        h1loc[hl][bb*T + t1] = (__fp16)hn[hl];
      }
      U32H2 z0, z1; z0.h = pk2(hn[0], hn[1]); z1.h = pk2(hn[2], hn[3]);
      uint2 val; val.x = z0.u; val.y = z1.u;
      stA8((char*)h1w + (long)(bb*1024 + 4*gB)*2, val);
    }
    // ---- layer0(p) partial stash ----
    if (p < T){
      #pragma unroll
      for (int r = 0; r < 4; r++){
        partial[w][lk*4 + r][lrow]      = acc00[r];
        partial[w][lk*4 + r][16 + lrow] = acc01[r];
      }
    }
    __syncthreads();
    if (p < T && tid < 512){
      int r = tid >> 5, bb = tid & 31;
      float s = 0.f;
      #pragma unroll
      for (int w2 = 0; w2 < 16; w2++) s += partial[w2][r][bb];
      float v = s + bs0v[r];
      gates[r][bb] = ((r >> 2) == 2) ? tanhf(v) : sigm(v);
    }
    __syncthreads();
    if (p < T && tid < 32){
      int bb = tid;
      float hn[4];
      #pragma unroll
      for (int hl = 0; hl < 4; hl++){
        float cn = gates[4+hl][bb]*cst[0][hl][bb] + gates[0+hl][bb]*gates[8+hl][bb];
        cst[0][hl][bb] = cn;
        hn[hl] = gates[12+hl][bb]*tanhf(cn);
      }
      U32H2 z0, z1; z0.h = pk2(hn[0], hn[1]); z1.h = pk2(hn[2], hn[3]);
      uint2 val; val.x = z0.u; val.y = z1.u;
      stA8((char*)h0w + (long)(bb*1024 + 4*gB)*2, val);
    }
    gbar(bar, ep); ep++;
  }

  // direct swizzled-Abf flush: block gB owns k = 4gB..4gB+3 (8B half-slot)
  {
    int k0c = gB >> 4;
    int seg = (gB & 15) >> 1;
    int posb = (gB & 1) * 8;
    for (int m = tid; m < B*T; m += 1024){
      float v0 = (float)h1loc[0][m], v1 = (float)h1loc[1][m];
      float v2 = (float)h1loc[2][m], v3 = (float)h1loc[3][m];
      int bm = m >> 7, row = m & 127;
      long slot = ((long)(bm*16 + k0c)*128 + row)*8 + (seg ^ (row & 7));
      uint2 val; val.x = pkbf(v0, v1); val.y = pkbf(v2, v3);
      *(uint2*)((char*)Abf + slot*16 + posb) = val;
    }
  }
}

// ---------------- fallback per-step cells ----------------
__global__ void k_init(const float* __restrict__ enc, float* __restrict__ h0, float* __restrict__ c0,
                       float* __restrict__ h1, float* __restrict__ c1){
  int idx = blockIdx.x*256 + threadIdx.x;
  int b = idx & 31, h = idx >> 5;
  float v = enc[b*H + h];
  h0[idx]=v; c0[idx]=v; h1[idx]=v; c1[idx]=v;
}

__global__ __launch_bounds__(256) void k_cell0(const float* __restrict__ whh, const float* __restrict__ xg_t,
                       const float* __restrict__ h_in, float* __restrict__ h_out,
                       float* __restrict__ c){
  int h = (blockIdx.x*256 + threadIdx.x) >> 6;
  int lane = threadIdx.x & 63;
  int b = lane & 31, kh = lane >> 5;
  const float* w0 = whh + (0*H + h)*H + kh*512;
  const float* w1 = whh + (1*H + h)*H + kh*512;
  const float* w2 = whh + (2*H + h)*H + kh*512;
  const float* w3 = whh + (3*H + h)*H + kh*512;
  const float* hk = h_in + (kh*512)*B + b;
  float a0=0,a1=0,a2=0,a3=0, p0=0,p1=0,p2=0,p3=0;
  #pragma unroll 4
  for (int k=0;k<512;k+=4){
    float4 w40 = *(const float4*)(w0+k);
    float4 w41 = *(const float4*)(w1+k);
    float4 w42 = *(const float4*)(w2+k);
    float4 w43 = *(const float4*)(w3+k);
    float hv0 = hk[(k+0)*B], hv1 = hk[(k+1)*B], hv2 = hk[(k+2)*B], hv3 = hk[(k+3)*B];
    a0 += w40.x*hv0 + w40.y*hv1;  p0 += w40.z*hv2 + w40.w*hv3;
    a1 += w41.x*hv0 + w41.y*hv1;  p1 += w41.z*hv2 + w41.w*hv3;
    a2 += w42.x*hv0 + w42.y*hv1;  p2 += w42.z*hv2 + w42.w*hv3;
    a3 += w43.x*hv0 + w43.y*hv1;  p3 += w43.z*hv2 + w43.w*hv3;
  }
  float g0=a0+p0, g1=a1+p1, g2=a2+p2, g3=a3+p3;
  g0 += __shfl_xor(g0, 32);
  g1 += __shfl_xor(g1, 32);
  g2 += __shfl_xor(g2, 32);
  g3 += __shfl_xor(g3, 32);
  g0 += xg_t[(0*H+h)*B + b];
  g1 += xg_t[(1*H+h)*B + b];
  g2 += xg_t[(2*H+h)*B + b];
  g3 += xg_t[(3*H+h)*B + b];
  float ig = sigm(g0), fg = sigm(g1), gg = tanhf(g2), og = sigm(g3);
  int sidx = h*B + b;
  float cn = fg*c[sidx] + ig*gg;
  float hn = og*tanhf(cn);
  if (kh==0){ c[sidx]=cn; h_out[sidx]=hn; }
}

__global__ __launch_bounds__(256) void k_cell1(const float* __restrict__ wih, const float* __restrict__ whh,
                       const float* __restrict__ bih, const float* __restrict__ bhh,
                       const float* __restrict__ h0n, const float* __restrict__ h_in,
                       float* __restrict__ h_out, float* __restrict__ c,
                       float* __restrict__ H1Tmk, int t){
  int h = (blockIdx.x*256 + threadIdx.x) >> 6;
  int lane = threadIdx.x & 63;
  int b = lane & 31, kh = lane >> 5;
  float a0=0,a1=0,a2=0,a3=0, p0=0,p1=0,p2=0,p3=0;
  {
    const float* w0 = wih + (0*H + h)*H + kh*512;
    const float* w1 = wih + (1*H + h)*H + kh*512;
    const float* w2 = wih + (2*H + h)*H + kh*512;
    const float* w3 = wih + (3*H + h)*H + kh*512;
    const float* hk = h0n + (kh*512)*B + b;
    #pragma unroll 4
    for (int k=0;k<512;k+=4){
      float4 w40 = *(const float4*)(w0+k);
      float4 w41 = *(const float4*)(w1+k);
      float4 w42 = *(const float4*)(w2+k);
      float4 w43 = *(const float4*)(w3+k);
      float hv0 = hk[(k+0)*B], hv1 = hk[(k+1)*B], hv2 = hk[(k+2)*B], hv3 = hk[(k+3)*B];
      a0 += w40.x*hv0 + w40.y*hv1;  p0 += w40.z*hv2 + w40.w*hv3;
      a1 += w41.x*hv0 + w41.y*hv1;  p1 += w41.z*hv2 + w41.w*hv3;
      a2 += w42.x*hv0 + w42.y*hv1;  p2 += w42.z*hv2 + w42.w*hv3;
      a3 += w43.x*hv0 + w43.y*hv1;  p3 += w43.z*hv2 + w43.w*hv3;
    }
  }
  {
    const float* w0 = whh + (0*H + h)*H + kh*512;
    const float* w1 = whh + (1*H + h)*H + kh*512;
    const float* w2 = whh + (2*H + h)*H + kh*512;
    const float* w3 = whh + (3*H + h)*H + kh*512;
    const float* hk = h_in + (kh*512)*B + b;
    #pragma unroll 4
    for (int k=0;k<512;k+=4){
      float4 w40 = *(const float4*)(w0+k);
      float4 w41 = *(const float4*)(w1+k);
      float4 w42 = *(const float4*)(w2+k);
      float4 w43 = *(const float4*)(w3+k);
      float hv0 = hk[(k+0)*B], hv1 = hk[(k+1)*B], hv2 = hk[(k+2)*B], hv3 = hk[(k+3)*B];
      a0 += w40.x*hv0 + w40.y*hv1;  p0 += w40.z*hv2 + w40.w*hv3;
      a1 += w41.x*hv0 + w41.y*hv1;  p1 += w41.z*hv2 + w41.w*hv3;
      a2 += w42.x*hv0 + w42.y*hv1;  p2 += w42.z*hv2 + w42.w*hv3;
      a3 += w43.x*hv0 + w43.y*hv1;  p3 += w43.z*hv2 + w43.w*hv3;
    }
  }
  float g0=a0+p0, g1=a1+p1, g2=a2+p2, g3=a3+p3;
  g0 += __shfl_xor(g0, 32);
  g1 += __shfl_xor(g1, 32);
  g2 += __shfl_xor(g2, 32);
  g3 += __shfl_xor(g3, 32);
  g0 += bih[0*H+h] + bhh[0*H+h];
  g1 += bih[1*H+h] + bhh[1*H+h];
  g2 += bih[2*H+h] + bhh[2*H+h];
  g3 += bih[3*H+h] + bhh[3*H+h];
  float ig = sigm(g0), fg = sigm(g1), gg = tanhf(g2), og = sigm(g3);
  int sidx = h*B + b;
  float cn = fg*c[sidx] + ig*gg;
  float hn = og*tanhf(cn);
  if (kh==0){ c[sidx]=cn; h_out[sidx]=hn; H1Tmk[((long)(b*T + t))*1024 + h] = hn; }
}

// ---------------- MFMA bf16 output GEMM (pre-swizzled operands) ----------------
__global__ __launch_bounds__(256, 2) void k_gemm_pre(const uint4* __restrict__ Abf4,
                      const uint4* __restrict__ Wsw4, const float* __restrict__ lb,
                      float* __restrict__ out){
  __shared__ uint4 As4[1024];
  __shared__ uint4 Ws4[1024];
  const int tid = threadIdx.x;
  int orig = blockIdx.x;
  int xcd = orig & 7, ii = orig >> 3;
  int wgid = (xcd < 2 ? xcd*407 : 814 + (xcd-2)*406) + ii;
  int bm = wgid % 13, bn = wgid / 13;
  int m0 = bm*128, n0 = bn*128;
  const int wv = tid >> 6, l = tid & 63;
  const int wm = (wv >> 1)*64, wn = (wv & 1)*64;
  const int lrow = l & 15, lk = l >> 4;

  floatx4 acc[4][4] = {};
  for (int k0c = 0; k0c < 16; k0c++){
    const uint4* sA = Abf4 + (long)(bm*16 + k0c)*1024;
    const uint4* sW = Wsw4 + (long)(bn*16 + k0c)*1024;
    #pragma unroll
    for (int it = 0; it < 4; it++){
      int slot = tid + it*256;
      As4[slot] = sA[slot];
      Ws4[slot] = sW[slot];
    }
    __syncthreads();
    #pragma unroll
    for (int ks = 0; ks < 2; ks++){
      short8 af[4], bf_[4];
      #pragma unroll
      for (int fi = 0; fi < 4; fi++){
        int row = wm + fi*16 + lrow;
        U16S8 u; u.u4 = As4[row*8 + ((ks*4 + lk) ^ (lrow & 7))];
        af[fi] = u.s8;
      }
      #pragma unroll
      for (int fj = 0; fj < 4; fj++){
        int row = wn + fj*16 + lrow;
        U16S8 u; u.u4 = Ws4[row*8 + ((ks*4 + lk) ^ (lrow & 7))];
        bf_[fj] = u.s8;
      }
      #pragma unroll
      for (int fi = 0; fi < 4; fi++)
        #pragma unroll
        for (int fj = 0; fj < 4; fj++)
          acc[fi][fj] = __builtin_amdgcn_mfma_f32_16x16x32_bf16(af[fi], bf_[fj], acc[fi][fj], 0, 0, 0);
    }
    __syncthreads();
  }
  #pragma unroll
  for (int fj = 0; fj < 4; fj++){
    int n = n0 + wn + fj*16 + lrow;
    float bias = lb[n];
    #pragma unroll
    for (int fi = 0; fi < 4; fi++){
      floatx4 av = acc[fi][fj];
      int mb = m0 + wm + fi*16 + lk*4;
      #pragma unroll
      for (int r = 0; r < 4; r++){
        int m = mb + r;
        if (m < B*T) out[(long)m*V + n] = av[r] + bias;
      }
    }
  }
}

// fallback GEMM: A pre-swizzled, W converted inline from f32
__global__ __launch_bounds__(256, 2) void k_gemm_inl(const uint4* __restrict__ Abf4,
                      const float* __restrict__ lw, const float* __restrict__ lb,
                      float* __restrict__ out){
  __shared__ uint4 As4[1024];
  __shared__ uint4 Ws4[1024];
  const int tid = threadIdx.x;
  int orig = blockIdx.x;
  int xcd = orig & 7, ii = orig >> 3;
  int wgid = (xcd < 2 ? xcd*407 : 814 + (xcd-2)*406) + ii;
  int bm = wgid % 13, bn = wgid / 13;
  int m0 = bm*128, n0 = bn*128;
  const int wv = tid >> 6, l = tid & 63;
  const int wm = (wv >> 1)*64, wn = (wv & 1)*64;
  const int lrow = l & 15, lk = l >> 4;

  floatx4 acc[4][4] = {};
  for (int k0c = 0; k0c < 16; k0c++){
    const uint4* sA = Abf4 + (long)(bm*16 + k0c)*1024;
    #pragma unroll
    for (int it = 0; it < 4; it++){
      int slot = tid + it*256;
      As4[slot] = sA[slot];
      int row = slot >> 3, seg = slot & 7;
      const float4* src = (const float4*)(lw + (long)(n0+row)*H + k0c*64 + seg*8);
      float4 v0 = src[0], v1 = src[1];
      uint4 pk;
      pk.x = pkbf(v0.x, v0.y); pk.y = pkbf(v0.z, v0.w);
      pk.z = pkbf(v1.x, v1.y); pk.w = pkbf(v1.z, v1.w);
      Ws4[row*8 + (seg ^ (row & 7))] = pk;
    }
    __syncthreads();
    #pragma unroll
    for (int ks = 0; ks < 2; ks++){
      short8 af[4], bf_[4];
      #pragma unroll
      for (int fi = 0; fi < 4; fi++){
        int row = wm + fi*16 + lrow;
        U16S8 u; u.u4 = As4[row*8 + ((ks*4 + lk) ^ (lrow & 7))];
        af[fi] = u.s8;
      }
      #pragma unroll
      for (int fj = 0; fj < 4; fj++){
        int row = wn + fj*16 + lrow;
        U16S8 u; u.u4 = Ws4[row*8 + ((ks*4 + lk) ^ (lrow & 7))];
        bf_[fj] = u.s8;
      }
      #pragma unroll
      for (int fi = 0; fi < 4; fi++)
        #pragma unroll
        for (int fj = 0; fj < 4; fj++)
          acc[fi][fj] = __builtin_amdgcn_mfma_f32_16x16x32_bf16(af[fi], bf_[fj], acc[fi][fj], 0, 0, 0);
    }
    __syncthreads();
  }
  #pragma unroll
  for (int fj = 0; fj < 4; fj++){
    int n = n0 + wn + fj*16 + lrow;
    float bias = lb[n];
    #pragma unroll
    for (int fi = 0; fi < 4; fi++){
      floatx4 av = acc[fi][fj];
      int mb = m0 + wm + fi*16 + lk*4;
      #pragma unroll
      for (int r = 0; r < 4; r++){
        int m = mb + r;
        if (m < B*T) out[(long)m*V + n] = av[r] + bias;
      }
    }
  }
}

// log-softmax with row cached in LDS (read out once, write once)
__global__ __launch_bounds__(1024) void k_lsm(float* __restrict__ out){
  __shared__ float4 rowbuf[V/4];          // 128 KB
  __shared__ float redm[1024], reds[1024];
  float4* row = (float4*)(out + (long)blockIdx.x * V);
  const int tid = threadIdx.x;
  float m = -INFINITY, s = 0.f;
  for (int n=tid;n<V/4;n+=1024){
    float4 v = row[n];
    rowbuf[n] = v;
    float cm = fmaxf(fmaxf(v.x,v.y), fmaxf(v.z,v.w));
    if (cm > m){ s *= __expf(m - cm); m = cm; }
    s += __expf(v.x-m)+__expf(v.y-m)+__expf(v.z-m)+__expf(v.w-m);
  }
  redm[tid]=m; reds[tid]=s; __syncthreads();
  for (int st=512;st>0;st>>=1){
    if (tid<st){
      float m1=redm[tid], s1=reds[tid];
      float m2=redm[tid+st], s2=reds[tid+st];
      float M=fmaxf(m1,m2);
      reds[tid]=s1*__expf(m1-M)+s2*__expf(m2-M);
      redm[tid]=M;
    }
    __syncthreads();
  }
  float lse = redm[0] + __logf(reds[0]);
  for (int n=tid;n<V/4;n+=1024){
    float4 v = rowbuf[n];
    v.x-=lse; v.y-=lse; v.z-=lse; v.w-=lse;
    row[n] = v;
  }
}

extern "C" void kernel_launch(void* const* d_in, const int* in_sizes, int n_in,
                              void* d_out, int out_size, void* d_ws, size_t ws_size,
                              hipStream_t stream){
  const float* enc    = (const float*)d_in[0];
  const float* target = (const float*)d_in[1];
  const float* pw     = (const float*)d_in[2];
  const float* pb     = (const float*)d_in[3];
  const float* wih0   = (const float*)d_in[4];
  const float* whh0   = (const float*)d_in[5];
  const float* bih0   = (const float*)d_in[6];
  const float* bhh0   = (const float*)d_in[7];
  const float* wih1   = (const float*)d_in[8];
  const float* whh1   = (const float*)d_in[9];
  const float* bih1   = (const float*)d_in[10];
  const float* bhh1   = (const float*)d_in[11];
  const float* lw     = (const float*)d_in[12];
  const float* lb     = (const float*)d_in[13];
  float* out = (float*)d_out;

  float* ws   = (float*)d_ws;
  float* xg0  = ws;                              // 6,553,600 f (fallback)
  float* P    = xg0 + (long)T*G4*B;              // 204,800 f (fallback)
  float* encp = P + T*E*B;                       // 4,096 f
  float* H1Tmk = encp + B*E;                     // 1,703,936 f (fallback)
  unsigned* Abf = (unsigned*)(H1Tmk + (long)MROWS*1024);  // 851,968 u32
  unsigned* h0A2 = Abf + 851968;                 // 16,384 each (64KB f16 state)
  unsigned* h0B2 = h0A2 + 16384;
  unsigned* h1A2 = h0B2 + 16384;
  unsigned* h1B2 = h1A2 + 16384;
  float* fh0a = (float*)(h1B2 + 16384);          // fallback f32 state
  float* fh0b = fh0a + H*B;
  float* fh1a = fh0b + H*B;
  float* fh1b = fh1a + H*B;
  float* fc0  = fh1b + H*B;
  float* fc1  = fc0 + H*B;
  unsigned* bar = (unsigned*)(fc1 + H*B);        // 1,024 u32
  __fp16* Pf16 = (__fp16*)(bar + 1024);          // 204,800 f16
  unsigned* lwsw = (unsigned*)(Pf16 + (long)T*B*E);  // 16,384,000 u32
  size_t need = (size_t)((char*)(lwsw + 16384000) - (char*)d_ws);
  bool pre = (ws_size >= need);

  k_encp<<<B, E, 0, stream>>>(enc, pw, pb, encp);
  k_proj<<<T*B, E, 0, stream>>>(target, pw, encp, P, Pf16);
  k_zero32<<<4, 256, 0, stream>>>(bar);

  uint4* lwsw4 = pre ? (uint4*)lwsw : (uint4*)0;
  void* cargs[] = {(void*)&whh0, (void*)&wih1, (void*)&whh1,
                   (void*)&wih0, (void*)&bih0, (void*)&bhh0,
                   (void*)&bih1, (void*)&bhh1,
                   (void*)&enc, (void*)&Pf16,
                   (void*)&lw, (void*)&lwsw4,
                   (void*)&h0A2, (void*)&h0B2, (void*)&h1A2, (void*)&h1B2,
                   (void*)&Abf, (void*)&bar};
  hipError_t cerr = hipLaunchCooperativeKernel((void*)k_cells, dim3(NB), dim3(1024),
                                               cargs, 0, stream);
  if (cerr != hipSuccess){
    if (pre) k_cvtw<<<16000, 256, 0, stream>>>(lw, (uint4*)lwsw);
    k_xg0<<<(T*G4*B)/256, 256, 0, stream>>>(wih0, bih0, bhh0, P, xg0);
    k_init<<<(H*B)/256, 256, 0, stream>>>(enc, fh0a, fc0, fh1a, fc1);
    float* h0in=fh0a; float* h0out=fh0b;
    float* h1in=fh1a; float* h1out=fh1b;
    for (int t=0;t<T;t++){
      k_cell0<<<256, 256, 0, stream>>>(whh0, xg0 + (long)t*G4*B, h0in, h0out, fc0);
      k_cell1<<<256, 256, 0, stream>>>(wih1, whh1, bih1, bhh1, h0out, h1in, h1out, fc1,
                                       H1Tmk, t);
      float* tmp;
      tmp=h0in; h0in=h0out; h0out=tmp;
      tmp=h1in; h1in=h1out; h1out=tmp;
    }
    k_pack<<<800, 256, 0, stream>>>(H1Tmk, (uint4*)Abf);
  }

  if (pre) k_gemm_pre<<<3250, 256, 0, stream>>>((const uint4*)Abf, (const uint4*)lwsw, lb, out);
  else     k_gemm_inl<<<3250, 256, 0, stream>>>((const uint4*)Abf, lw, lb, out);
  k_lsm<<<B*T, 1024, 0, stream>>>(out);
}

// Round 23
// 777.702 us; speedup vs baseline: 1.3745x; 1.0200x over previous
//
#include <hip/hip_runtime.h>
#include <hip/hip_bf16.h>
#include <math.h>

#define B 32
#define T 50
#define H 1024
#define E 128
#define V 32000
#define G4 4096   // 4*H
#define HE 1152   // H+E
#define MROWS 1664 // 13*128 padded M for GEMM
#define NB 256    // coop grid blocks

typedef __fp16 half2v __attribute__((ext_vector_type(2)));
typedef __fp16 half8 __attribute__((ext_vector_type(8)));
typedef unsigned long long ull;
union U32H2 { unsigned u; half2v h; };
union U4H8 { uint4 u4; half8 h8; };
typedef short short8 __attribute__((ext_vector_type(8)));
typedef float floatx4 __attribute__((ext_vector_type(4)));
union U16S8 { uint4 u4; short8 s8; };

// 16B LLC-coherent load (bypass L1+L2), issue-only; pair with one vmcnt wait.
#define LLC_LOAD(dst, ptr) \
  asm volatile("global_load_dwordx4 %0, %1, off sc0 sc1" : "=v"((dst).u4) : "v"(ptr))

__device__ __forceinline__ float sigm(float x){ return 1.0f/(1.0f+expf(-x)); }

__device__ __forceinline__ half2v pk2(float a, float b){
#if __has_builtin(__builtin_amdgcn_cvt_pkrtz)
  return __builtin_amdgcn_cvt_pkrtz(a, b);
#else
  half2v r; r.x = (__fp16)a; r.y = (__fp16)b; return r;
#endif
}

// pack two f32 -> one u32 of two bf16 (RNE)
__device__ __forceinline__ unsigned pkbf(float a, float b){
  unsigned ua = __float_as_uint(a), ub = __float_as_uint(b);
  unsigned ra = (ua + 0x7FFFu + ((ua>>16)&1u)) >> 16;
  unsigned rb = (ub + 0x7FFFu + ((ub>>16)&1u)) >> 16;
  return ra | (rb << 16);
}

// agent-scope store, 8B (bypasses caches, lands at LLC)
__device__ __forceinline__ void stA8(void* p, uint2 v){
  ull q = ((ull)v.y << 32) | (ull)v.x;
  __hip_atomic_store((ull*)p, q, __ATOMIC_RELAXED, __HIP_MEMORY_SCOPE_AGENT);
}

// ---- fence-free tree grid barrier (8 leaves x 32 + root) — r17 verified ----
__device__ __forceinline__ void gbar(unsigned* bar, unsigned ep){
  __syncthreads();
  if (threadIdx.x == 0){
    asm volatile("s_waitcnt vmcnt(0)" ::: "memory");
    unsigned g = blockIdx.x & 7u;
    unsigned old = __hip_atomic_fetch_add(&bar[64 + g*64], 1u,
                     __ATOMIC_RELAXED, __HIP_MEMORY_SCOPE_AGENT);
    if (old == ep*32u - 1u)
      __hip_atomic_fetch_add(&bar[0], 1u, __ATOMIC_RELAXED, __HIP_MEMORY_SCOPE_AGENT);
    while (__hip_atomic_load(&bar[0], __ATOMIC_RELAXED, __HIP_MEMORY_SCOPE_AGENT) < ep*8u)
      __builtin_amdgcn_s_sleep(1);
  }
  __syncthreads();
}

// encp[b][e] = proj_b[e] + sum_j enc[b][j] * proj_w[e][E+j]
__global__ void k_encp(const float* __restrict__ enc, const float* __restrict__ pw,
                       const float* __restrict__ pb, float* __restrict__ encp){
  int b = blockIdx.x, e = threadIdx.x;
  const float* er = enc + b*H;
  const float* wr = pw + e*HE + E;
  float acc = pb[e];
  for (int j=0;j<H;j+=4){
    float4 w4 = *(const float4*)(wr+j);
    float4 e4 = *(const float4*)(er+j);
    acc += w4.x*e4.x + w4.y*e4.y + w4.z*e4.z + w4.w*e4.w;
  }
  encp[b*E+e] = acc;
}

// P[t][e][b] f32 (fallback) + Pf16[t][b][e] (coop MFMA B-operand)
__global__ void k_proj(const float* __restrict__ target, const float* __restrict__ pw,
                       const float* __restrict__ encp, float* __restrict__ P,
                       __fp16* __restrict__ Pf16){
  int t = blockIdx.x / B, b = blockIdx.x % B, e = threadIdx.x;
  const float* xr = target + (b*T + t)*E;
  const float* wr = pw + e*HE;
  float acc = encp[b*E+e];
  for (int j=0;j<E;j+=4){
    float4 w4 = *(const float4*)(wr+j);
    float4 x4 = *(const float4*)(xr+j);
    acc += w4.x*x4.x + w4.y*x4.y + w4.z*x4.z + w4.w*x4.w;
  }
  P[(t*E + e)*B + b] = acc;
  Pf16[((long)t*B + b)*E + e] = (__fp16)acc;
}

// xg0[t][r][b] (fallback path only)
__global__ void k_xg0(const float* __restrict__ wih0, const float* __restrict__ bih0,
                      const float* __restrict__ bhh0, const float* __restrict__ P,
                      float* __restrict__ xg){
  int idx = blockIdx.x*256 + threadIdx.x;
  int b = idx & 31; int r = (idx >> 5) & 4095; int t = idx >> 17;
  const float* wr = wih0 + r*E;
  const float* pr = P + t*E*B + b;
  float acc = bih0[r] + bhh0[r];
  #pragma unroll 8
  for (int e=0;e<E;e+=4){
    float4 w4 = *(const float4*)(wr+e);
    acc += w4.x*pr[(e+0)*B] + w4.y*pr[(e+1)*B]
         + w4.z*pr[(e+2)*B] + w4.w*pr[(e+3)*B];
  }
  xg[idx] = acc;
}

__global__ void k_zero32(unsigned* __restrict__ p){
  p[blockIdx.x*256 + threadIdx.x] = 0u;
}

// convert lw f32 -> bf16 in the GEMM's swizzled tile layout (fallback path only)
__global__ void k_cvtw(const float* __restrict__ lw, uint4* __restrict__ wsw){
  int gid = blockIdx.x*256 + threadIdx.x;   // 4,096,000
  int n = gid >> 7, rem = gid & 127;
  int k0c = rem >> 3, seg = rem & 7;
  const float4* src = (const float4*)(lw + (long)n*H + k0c*64 + seg*8);
  float4 v0 = src[0], v1 = src[1];
  uint4 pk;
  pk.x = pkbf(v0.x, v0.y); pk.y = pkbf(v0.z, v0.w);
  pk.z = pkbf(v1.x, v1.y); pk.w = pkbf(v1.z, v1.w);
  int bn = n >> 7, row = n & 127;
  wsw[((long)(bn*16 + k0c)*128 + row)*8 + (seg ^ (row & 7))] = pk;
}

// pack H1Tmk f32 [m][k] -> Abf swizzled bf16 tiles (fallback path only)
__global__ void k_pack(const float* __restrict__ H1Tmk, uint4* __restrict__ Abf){
  int gid = blockIdx.x*256 + threadIdx.x;   // 204,800
  int m = gid >> 7, rem = gid & 127;
  int k0c = rem >> 3, seg = rem & 7;
  const float4* src = (const float4*)(H1Tmk + (long)m*1024 + k0c*64 + seg*8);
  float4 v0 = src[0], v1 = src[1];
  uint4 pk;
  pk.x = pkbf(v0.x, v0.y); pk.y = pkbf(v0.z, v0.w);
  pk.z = pkbf(v1.x, v1.y); pk.w = pkbf(v1.z, v1.w);
  int bm = m >> 7, row = m & 127;
  Abf[((long)(bm*16 + k0c)*128 + row)*8 + (seg ^ (row & 7))] = pk;
}

// ---------------- cooperative persistent cells (v16: pipelined cvtw) ----------------
__global__ __launch_bounds__(1024, 4) void k_cells(
    const float* __restrict__ whh0, const float* __restrict__ wih1, const float* __restrict__ whh1,
    const float* __restrict__ wih0, const float* __restrict__ bih0, const float* __restrict__ bhh0,
    const float* __restrict__ bih1, const float* __restrict__ bhh1,
    const float* __restrict__ enc, const __fp16* __restrict__ Pf16,
    const float* __restrict__ lw, uint4* __restrict__ lwsw,
    unsigned* __restrict__ h0A2, unsigned* __restrict__ h0B2,
    unsigned* __restrict__ h1A2, unsigned* __restrict__ h1B2,
    unsigned* __restrict__ Abf, unsigned* __restrict__ bar){
  const int gB = blockIdx.x;
  const int tid = threadIdx.x;
  const int w = tid >> 6;       // wave 0..15 = k-chunk owner
  const int l = tid & 63;
  const int lrow = l & 15;      // fragment row/col
  const int lk = l >> 4;        // k-segment 0..3

  __shared__ uint4 w0s4[16*128];        // layer0 whh0 rows, f16 swizzled (32 KB)
  __shared__ uint4 w1s4[32*128];        // wih1(0-15)+whh1(16-31) (64 KB)
  __shared__ uint4 w0x4[16*16];         // layer0 wih0 rows, f16 swizzled (4 KB)
  __shared__ float partial[16][16][34]; // [wave][row][b-col] pad 34
  __shared__ float gates[16][32];
  __shared__ float cst[2][4][32];
  __shared__ float bs1v[16];
  __shared__ float bs0v[16];
  __shared__ __fp16 h1loc[4][1600];     // [hl][b*T+t] (12.8 KB)

  // ---- stage weights f32 -> f16, XOR-swizzled segments ----
  for (int i = tid; i < 2048; i += 1024){
    int row = i >> 7, seg = i & 127;
    int q = row >> 2, hl = row & 3;
    const float* src = whh0 + ((long)q*H + 4*gB + hl)*H + seg*8;
    float4 v0 = *(const float4*)src, v1 = *(const float4*)(src+4);
    U32H2 z0,z1,z2,z3;
    z0.h = pk2(v0.x,v0.y); z1.h = pk2(v0.z,v0.w);
    z2.h = pk2(v1.x,v1.y); z3.h = pk2(v1.z,v1.w);
    uint4 pk; pk.x=z0.u; pk.y=z1.u; pk.z=z2.u; pk.w=z3.u;
    int phys = (seg & ~7) | ((seg & 7) ^ (row & 7));
    w0s4[row*128 + phys] = pk;
  }
  for (int i = tid; i < 4096; i += 1024){
    int row = i >> 7, seg = i & 127;
    int rr = row & 15;
    int q = rr >> 2, hl = rr & 3;
    const float* srcm = (row < 16) ? wih1 : whh1;
    const float* src = srcm + ((long)q*H + 4*gB + hl)*H + seg*8;
    float4 v0 = *(const float4*)src, v1 = *(const float4*)(src+4);
    U32H2 z0,z1,z2,z3;
    z0.h = pk2(v0.x,v0.y); z1.h = pk2(v0.z,v0.w);
    z2.h = pk2(v1.x,v1.y); z3.h = pk2(v1.z,v1.w);
    uint4 pk; pk.x=z0.u; pk.y=z1.u; pk.z=z2.u; pk.w=z3.u;
    int phys = (seg & ~7) | ((seg & 7) ^ (rr & 7));
    w1s4[row*128 + phys] = pk;
  }
  if (tid < 256){
    int row = tid >> 4, seg = tid & 15;
    int q = row >> 2, hl = row & 3;
    const float* src = wih0 + ((long)q*H + 4*gB + hl)*E + seg*8;
    float4 v0 = *(const float4*)src, v1 = *(const float4*)(src+4);
    U32H2 z0,z1,z2,z3;
    z0.h = pk2(v0.x,v0.y); z1.h = pk2(v0.z,v0.w);
    z2.h = pk2(v1.x,v1.y); z3.h = pk2(v1.z,v1.w);
    uint4 pk; pk.x=z0.u; pk.y=z1.u; pk.z=z2.u; pk.w=z3.u;
    int phys = (seg & ~7) | ((seg & 7) ^ (row & 7));
    w0x4[row*16 + phys] = pk;
  }
  if (tid < 16){
    int q = tid >> 2, hl = tid & 3;
    bs1v[tid] = bih1[q*H + 4*gB + hl] + bhh1[q*H + 4*gB + hl];
    bs0v[tid] = bih0[q*H + 4*gB + hl] + bhh0[q*H + 4*gB + hl];
  }
  if (tid < 128){
    int hl = tid >> 5, bb = tid & 31;
    float v = enc[bb*H + 4*gB + hl];
    cst[0][hl][bb] = v; cst[1][hl][bb] = v;
  }
  if (tid < 32){
    int bb = tid;
    U32H2 z0, z1;
    z0.h = pk2(enc[bb*H + 4*gB + 0], enc[bb*H + 4*gB + 1]);
    z1.h = pk2(enc[bb*H + 4*gB + 2], enc[bb*H + 4*gB + 3]);
    uint2 val; val.x = z0.u; val.y = z1.u;
    stA8((char*)h0A2 + (long)(bb*1024 + 4*gB)*2, val);
    stA8((char*)h1A2 + (long)(bb*1024 + 4*gB)*2, val);
  }
  unsigned ep = 1;
  gbar(bar, ep); ep++;

  const bool cvw = (lwsw != 0) && tid >= 128 && tid < 448;
  const int cvtid = tid - 128;
  float4 cva, cvb;   // pipelined lw values (loaded at p, stored at p+1)

  for (int p = 0; p <= T; p++){
    const unsigned* h0r = (p & 1) ? h0B2 : h0A2;
    unsigned*       h0w = (p & 1) ? h0A2 : h0B2;
    const unsigned* h1r = (p & 1) ? h1A2 : h1B2;
    unsigned*       h1w = (p & 1) ? h1B2 : h1A2;

    // ---- batched LLC state loads (issue all, wait once) ----
    int c = (w + gB + p) & 15;
    U4H8 b0a0, b0a1, b0b0, b0b1, b1a0, b1a1, b1b0, b1b1;
    {
      int kb = c*64;
      const __fp16* h0f = (const __fp16*)h0r;
      const __fp16* h1f = (const __fp16*)h1r;
      const __fp16* s0a = h0f + lrow*1024 + kb + lk*8;
      const __fp16* s0b = h0f + (16+lrow)*1024 + kb + lk*8;
      LLC_LOAD(b0a0, s0a);      LLC_LOAD(b0a1, s0a + 32);
      LLC_LOAD(b0b0, s0b);      LLC_LOAD(b0b1, s0b + 32);
      if (p >= 1){
        const __fp16* s1a = h1f + lrow*1024 + kb + lk*8;
        const __fp16* s1b = h1f + (16+lrow)*1024 + kb + lk*8;
        LLC_LOAD(b1a0, s1a);    LLC_LOAD(b1a1, s1a + 32);
        LLC_LOAD(b1b0, s1b);    LLC_LOAD(b1b1, s1b + 32);
      }
      asm volatile("s_waitcnt vmcnt(0)" ::: "memory");
      __builtin_amdgcn_sched_barrier(0);
    }

    // ---- MFMA matvec ----
    floatx4 acc10 = {0,0,0,0}, acc11 = {0,0,0,0};
    floatx4 acc00 = {0,0,0,0}, acc01 = {0,0,0,0};
    #pragma unroll
    for (int ks = 0; ks < 2; ks++){
      int phys = c*8 + (((ks<<2) + lk) ^ (lrow & 7));
      half8 B0a = ks ? b0a1.h8 : b0a0.h8;
      half8 B0b = ks ? b0b1.h8 : b0b0.h8;
      if (p < T){
        U4H8 a0v; a0v.u4 = w0s4[lrow*128 + phys];
        acc00 = __builtin_amdgcn_mfma_f32_16x16x32_f16(a0v.h8, B0a, acc00, 0, 0, 0);
        acc01 = __builtin_amdgcn_mfma_f32_16x16x32_f16(a0v.h8, B0b, acc01, 0, 0, 0);
      }
      if (p >= 1){
        U4H8 a1i; a1i.u4 = w1s4[lrow*128 + phys];
        U4H8 a1h; a1h.u4 = w1s4[(16+lrow)*128 + phys];
        half8 B1a = ks ? b1a1.h8 : b1a0.h8;
        half8 B1b = ks ? b1b1.h8 : b1b0.h8;
        acc10 = __builtin_amdgcn_mfma_f32_16x16x32_f16(a1i.h8, B0a, acc10, 0, 0, 0);
        acc10 = __builtin_amdgcn_mfma_f32_16x16x32_f16(a1h.h8, B1a, acc10, 0, 0, 0);
        acc11 = __builtin_amdgcn_mfma_f32_16x16x32_f16(a1i.h8, B0b, acc11, 0, 0, 0);
        acc11 = __builtin_amdgcn_mfma_f32_16x16x32_f16(a1h.h8, B1b, acc11, 0, 0, 0);
      }
    }
    // ---- fused xg contribution: waves with c<2 add wih0 . P_t ----
    if (p < T && c < 2){
      const __fp16* pbase = Pf16 + (long)p*B*E + c*64 + lk*8;
      U4H8 q0a, q1a, q0b, q1b;
      q0a.u4 = *(const uint4*)(pbase + lrow*E);
      q1a.u4 = *(const uint4*)(pbase + lrow*E + 32);
      q0b.u4 = *(const uint4*)(pbase + (16+lrow)*E);
      q1b.u4 = *(const uint4*)(pbase + (16+lrow)*E + 32);
      #pragma unroll
      for (int ks = 0; ks < 2; ks++){
        int phys = c*8 + (((ks<<2) + lk) ^ (lrow & 7));
        U4H8 aw; aw.u4 = w0x4[lrow*16 + phys];
        acc00 = __builtin_amdgcn_mfma_f32_16x16x32_f16(aw.h8, ks ? q1a.h8 : q0a.h8, acc00, 0, 0, 0);
        acc01 = __builtin_amdgcn_mfma_f32_16x16x32_f16(aw.h8, ks ? q1b.h8 : q0b.h8, acc01, 0, 0, 0);
      }
    }
    // ---- pipelined lw cvtw: store slot p-1 (regs ready), load slot p (no wait) ----
    if (cvw){
      if (p >= 1){
        int slot = (gB*T + (p-1))*320 + cvtid;
        int n = slot >> 7, rem = slot & 127;
        int k0c = rem >> 3, seg = rem & 7;
        uint4 pk;
        pk.x = pkbf(cva.x, cva.y); pk.y = pkbf(cva.z, cva.w);
        pk.z = pkbf(cvb.x, cvb.y); pk.w = pkbf(cvb.z, cvb.w);
        int bn = n >> 7, row = n & 127;
        lwsw[((long)(bn*16 + k0c)*128 + row)*8 + (seg ^ (row & 7))] = pk;
      }
      if (p < T){
        int slot = (gB*T + p)*320 + cvtid;
        int n = slot >> 7, rem = slot & 127;
        int k0c = rem >> 3, seg = rem & 7;
        const float4* src = (const float4*)(lw + (long)n*H + k0c*64 + seg*8);
        cva = src[0]; cvb = src[1];
      }
    }
    if (p >= 1){
      #pragma unroll
      for (int r = 0; r < 4; r++){
        partial[w][lk*4 + r][lrow]      = acc10[r];
        partial[w][lk*4 + r][16 + lrow] = acc11[r];
      }
    }
    __syncthreads();
    // ---- layer1(p-1) reduce + cell ----
    if (p >= 1 && tid < 512){
      int r = tid >> 5, bb = tid & 31;
      float s = 0.f;
      #pragma unroll
      for (int w2 = 0; w2 < 16; w2++) s += partial[w2][r][bb];
      float v = s + bs1v[r];
      gates[r][bb] = ((r >> 2) == 2) ? tanhf(v) : sigm(v);
    }
    __syncthreads();
    if (p >= 1 && tid < 32){
      int bb = tid, t1 = p - 1;
      float hn[4];
      #pragma unroll
      for (int hl = 0; hl < 4; hl++){
        float cn = gates[4+hl][bb]*cst[1][hl][bb] + gates[0+hl][bb]*gates[8+hl][bb];
        cst[1][hl][bb] = cn;
        hn[hl] = gates[12+hl][bb]*tanhf(cn);
        h1loc[hl][bb*T + t1] = (__fp16)hn[hl];
      }
      U32H2 z0, z1; z0.h = pk2(hn[0], hn[1]); z1.h = pk2(hn[2], hn[3]);
      uint2 val; val.x = z0.u; val.y = z1.u;
      stA8((char*)h1w + (long)(bb*1024 + 4*gB)*2, val);
    }
    // ---- layer0(p) partial stash ----
    if (p < T){
      #pragma unroll
      for (int r = 0; r < 4; r++){
        partial[w][lk*4 + r][lrow]      = acc00[r];
        partial[w][lk*4 + r][16 + lrow] = acc01[r];
      }
    }
    __syncthreads();
    if (p < T && tid < 512){
      int r = tid >> 5, bb = tid & 31;
      float s = 0.f;
      #pragma unroll
      for (int w2 = 0; w2 < 16; w2++) s += partial[w2][r][bb];
      float v = s + bs0v[r];
      gates[r][bb] = ((r >> 2) == 2) ? tanhf(v) : sigm(v);
    }
    __syncthreads();
    if (p < T && tid < 32){
      int bb = tid;
      float hn[4];
      #pragma unroll
      for (int hl = 0; hl < 4; hl++){
        float cn = gates[4+hl][bb]*cst[0][hl][bb] + gates[0+hl][bb]*gates[8+hl][bb];
        cst[0][hl][bb] = cn;
        hn[hl] = gates[12+hl][bb]*tanhf(cn);
      }
      U32H2 z0, z1; z0.h = pk2(hn[0], hn[1]); z1.h = pk2(hn[2], hn[3]);
      uint2 val; val.x = z0.u; val.y = z1.u;
      stA8((char*)h0w + (long)(bb*1024 + 4*gB)*2, val);
    }
    gbar(bar, ep); ep++;
  }

  // direct swizzled-Abf flush: block gB owns k = 4gB..4gB+3 (8B half-slot)
  {
    int k0c = gB >> 4;
    int seg = (gB & 15) >> 1;
    int posb = (gB & 1) * 8;
    for (int m = tid; m < B*T; m += 1024){
      float v0 = (float)h1loc[0][m], v1 = (float)h1loc[1][m];
      float v2 = (float)h1loc[2][m], v3 = (float)h1loc[3][m];
      int bm = m >> 7, row = m & 127;
      long slot = ((long)(bm*16 + k0c)*128 + row)*8 + (seg ^ (row & 7));
      uint2 val; val.x = pkbf(v0, v1); val.y = pkbf(v2, v3);
      *(uint2*)((char*)Abf + slot*16 + posb) = val;
    }
  }
}

// ---------------- fallback per-step cells ----------------
__global__ void k_init(const float* __restrict__ enc, float* __restrict__ h0, float* __restrict__ c0,
                       float* __restrict__ h1, float* __restrict__ c1){
  int idx = blockIdx.x*256 + threadIdx.x;
  int b = idx & 31, h = idx >> 5;
  float v = enc[b*H + h];
  h0[idx]=v; c0[idx]=v; h1[idx]=v; c1[idx]=v;
}

__global__ __launch_bounds__(256) void k_cell0(const float* __restrict__ whh, const float* __restrict__ xg_t,
                       const float* __restrict__ h_in, float* __restrict__ h_out,
                       float* __restrict__ c){
  int h = (blockIdx.x*256 + threadIdx.x) >> 6;
  int lane = threadIdx.x & 63;
  int b = lane & 31, kh = lane >> 5;
  const float* w0 = whh + (0*H + h)*H + kh*512;
  const float* w1 = whh + (1*H + h)*H + kh*512;
  const float* w2 = whh + (2*H + h)*H + kh*512;
  const float* w3 = whh + (3*H + h)*H + kh*512;
  const float* hk = h_in + (kh*512)*B + b;
  float a0=0,a1=0,a2=0,a3=0, p0=0,p1=0,p2=0,p3=0;
  #pragma unroll 4
  for (int k=0;k<512;k+=4){
    float4 w40 = *(const float4*)(w0+k);
    float4 w41 = *(const float4*)(w1+k);
    float4 w42 = *(const float4*)(w2+k);
    float4 w43 = *(const float4*)(w3+k);
    float hv0 = hk[(k+0)*B], hv1 = hk[(k+1)*B], hv2 = hk[(k+2)*B], hv3 = hk[(k+3)*B];
    a0 += w40.x*hv0 + w40.y*hv1;  p0 += w40.z*hv2 + w40.w*hv3;
    a1 += w41.x*hv0 + w41.y*hv1;  p1 += w41.z*hv2 + w41.w*hv3;
    a2 += w42.x*hv0 + w42.y*hv1;  p2 += w42.z*hv2 + w42.w*hv3;
    a3 += w43.x*hv0 + w43.y*hv1;  p3 += w43.z*hv2 + w43.w*hv3;
  }
  float g0=a0+p0, g1=a1+p1, g2=a2+p2, g3=a3+p3;
  g0 += __shfl_xor(g0, 32);
  g1 += __shfl_xor(g1, 32);
  g2 += __shfl_xor(g2, 32);
  g3 += __shfl_xor(g3, 32);
  g0 += xg_t[(0*H+h)*B + b];
  g1 += xg_t[(1*H+h)*B + b];
  g2 += xg_t[(2*H+h)*B + b];
  g3 += xg_t[(3*H+h)*B + b];
  float ig = sigm(g0), fg = sigm(g1), gg = tanhf(g2), og = sigm(g3);
  int sidx = h*B + b;
  float cn = fg*c[sidx] + ig*gg;
  float hn = og*tanhf(cn);
  if (kh==0){ c[sidx]=cn; h_out[sidx]=hn; }
}

__global__ __launch_bounds__(256) void k_cell1(const float* __restrict__ wih, const float* __restrict__ whh,
                       const float* __restrict__ bih, const float* __restrict__ bhh,
                       const float* __restrict__ h0n, const float* __restrict__ h_in,
                       float* __restrict__ h_out, float* __restrict__ c,
                       float* __restrict__ H1Tmk, int t){
  int h = (blockIdx.x*256 + threadIdx.x) >> 6;
  int lane = threadIdx.x & 63;
  int b = lane & 31, kh = lane >> 5;
  float a0=0,a1=0,a2=0,a3=0, p0=0,p1=0,p2=0,p3=0;
  {
    const float* w0 = wih + (0*H + h)*H + kh*512;
    const float* w1 = wih + (1*H + h)*H + kh*512;
    const float* w2 = wih + (2*H + h)*H + kh*512;
    const float* w3 = wih + (3*H + h)*H + kh*512;
    const float* hk = h0n + (kh*512)*B + b;
    #pragma unroll 4
    for (int k=0;k<512;k+=4){
      float4 w40 = *(const float4*)(w0+k);
      float4 w41 = *(const float4*)(w1+k);
      float4 w42 = *(const float4*)(w2+k);
      float4 w43 = *(const float4*)(w3+k);
      float hv0 = hk[(k+0)*B], hv1 = hk[(k+1)*B], hv2 = hk[(k+2)*B], hv3 = hk[(k+3)*B];
      a0 += w40.x*hv0 + w40.y*hv1;  p0 += w40.z*hv2 + w40.w*hv3;
      a1 += w41.x*hv0 + w41.y*hv1;  p1 += w41.z*hv2 + w41.w*hv3;
      a2 += w42.x*hv0 + w42.y*hv1;  p2 += w42.z*hv2 + w42.w*hv3;
      a3 += w43.x*hv0 + w43.y*hv1;  p3 += w43.z*hv2 + w43.w*hv3;
    }
  }
  {
    const float* w0 = whh + (0*H + h)*H + kh*512;
    const float* w1 = whh + (1*H + h)*H + kh*512;
    const float* w2 = whh + (2*H + h)*H + kh*512;
    const float* w3 = whh + (3*H + h)*H + kh*512;
    const float* hk = h_in + (kh*512)*B + b;
    #pragma unroll 4
    for (int k=0;k<512;k+=4){
      float4 w40 = *(const float4*)(w0+k);
      float4 w41 = *(const float4*)(w1+k);
      float4 w42 = *(const float4*)(w2+k);
      float4 w43 = *(const float4*)(w3+k);
      float hv0 = hk[(k+0)*B], hv1 = hk[(k+1)*B], hv2 = hk[(k+2)*B], hv3 = hk[(k+3)*B];
      a0 += w40.x*hv0 + w40.y*hv1;  p0 += w40.z*hv2 + w40.w*hv3;
      a1 += w41.x*hv0 + w41.y*hv1;  p1 += w41.z*hv2 + w41.w*hv3;
      a2 += w42.x*hv0 + w42.y*hv1;  p2 += w42.z*hv2 + w42.w*hv3;
      a3 += w43.x*hv0 + w43.y*hv1;  p3 += w43.z*hv2 + w43.w*hv3;
    }
  }
  float g0=a0+p0, g1=a1+p1, g2=a2+p2, g3=a3+p3;
  g0 += __shfl_xor(g0, 32);
  g1 += __shfl_xor(g1, 32);
  g2 += __shfl_xor(g2, 32);
  g3 += __shfl_xor(g3, 32);
  g0 += bih[0*H+h] + bhh[0*H+h];
  g1 += bih[1*H+h] + bhh[1*H+h];
  g2 += bih[2*H+h] + bhh[2*H+h];
  g3 += bih[3*H+h] + bhh[3*H+h];
  float ig = sigm(g0), fg = sigm(g1), gg = tanhf(g2), og = sigm(g3);
  int sidx = h*B + b;
  float cn = fg*c[sidx] + ig*gg;
  float hn = og*tanhf(cn);
  if (kh==0){ c[sidx]=cn; h_out[sidx]=hn; H1Tmk[((long)(b*T + t))*1024 + h] = hn; }
}

// ---------------- MFMA bf16 output GEMM (pre-swizzled operands) ----------------
__global__ __launch_bounds__(256, 2) void k_gemm_pre(const uint4* __restrict__ Abf4,
                      const uint4* __restrict__ Wsw4, const float* __restrict__ lb,
                      float* __restrict__ out){
  __shared__ uint4 As4[1024];
  __shared__ uint4 Ws4[1024];
  const int tid = threadIdx.x;
  int orig = blockIdx.x;
  int xcd = orig & 7, ii = orig >> 3;
  int wgid = (xcd < 2 ? xcd*407 : 814 + (xcd-2)*406) + ii;
  int bm = wgid % 13, bn = wgid / 13;
  int m0 = bm*128, n0 = bn*128;
  const int wv = tid >> 6, l = tid & 63;
  const int wm = (wv >> 1)*64, wn = (wv & 1)*64;
  const int lrow = l & 15, lk = l >> 4;

  floatx4 acc[4][4] = {};
  for (int k0c = 0; k0c < 16; k0c++){
    const uint4* sA = Abf4 + (long)(bm*16 + k0c)*1024;
    const uint4* sW = Wsw4 + (long)(bn*16 + k0c)*1024;
    #pragma unroll
    for (int it = 0; it < 4; it++){
      int slot = tid + it*256;
      As4[slot] = sA[slot];
      Ws4[slot] = sW[slot];
    }
    __syncthreads();
    #pragma unroll
    for (int ks = 0; ks < 2; ks++){
      short8 af[4], bf_[4];
      #pragma unroll
      for (int fi = 0; fi < 4; fi++){
        int row = wm + fi*16 + lrow;
        U16S8 u; u.u4 = As4[row*8 + ((ks*4 + lk) ^ (lrow & 7))];
        af[fi] = u.s8;
      }
      #pragma unroll
      for (int fj = 0; fj < 4; fj++){
        int row = wn + fj*16 + lrow;
        U16S8 u; u.u4 = Ws4[row*8 + ((ks*4 + lk) ^ (lrow & 7))];
        bf_[fj] = u.s8;
      }
      #pragma unroll
      for (int fi = 0; fi < 4; fi++)
        #pragma unroll
        for (int fj = 0; fj < 4; fj++)
          acc[fi][fj] = __builtin_amdgcn_mfma_f32_16x16x32_bf16(af[fi], bf_[fj], acc[fi][fj], 0, 0, 0);
    }
    __syncthreads();
  }
  #pragma unroll
  for (int fj = 0; fj < 4; fj++){
    int n = n0 + wn + fj*16 + lrow;
    float bias = lb[n];
    #pragma unroll
    for (int fi = 0; fi < 4; fi++){
      floatx4 av = acc[fi][fj];
      int mb = m0 + wm + fi*16 + lk*4;
      #pragma unroll
      for (int r = 0; r < 4; r++){
        int m = mb + r;
        if (m < B*T) out[(long)m*V + n] = av[r] + bias;
      }
    }
  }
}

// fallback GEMM: A pre-swizzled, W converted inline from f32
__global__ __launch_bounds__(256, 2) void k_gemm_inl(const uint4* __restrict__ Abf4,
                      const float* __restrict__ lw, const float* __restrict__ lb,
                      float* __restrict__ out){
  __shared__ uint4 As4[1024];
  __shared__ uint4 Ws4[1024];
  const int tid = threadIdx.x;
  int orig = blockIdx.x;
  int xcd = orig & 7, ii = orig >> 3;
  int wgid = (xcd < 2 ? xcd*407 : 814 + (xcd-2)*406) + ii;
  int bm = wgid % 13, bn = wgid / 13;
  int m0 = bm*128, n0 = bn*128;
  const int wv = tid >> 6, l = tid & 63;
  const int wm = (wv >> 1)*64, wn = (wv & 1)*64;
  const int lrow = l & 15, lk = l >> 4;

  floatx4 acc[4][4] = {};
  for (int k0c = 0; k0c < 16; k0c++){
    const uint4* sA = Abf4 + (long)(bm*16 + k0c)*1024;
    #pragma unroll
    for (int it = 0; it < 4; it++){
      int slot = tid + it*256;
      As4[slot] = sA[slot];
      int row = slot >> 3, seg = slot & 7;
      const float4* src = (const float4*)(lw + (long)(n0+row)*H + k0c*64 + seg*8);
      float4 v0 = src[0], v1 = src[1];
      uint4 pk;
      pk.x = pkbf(v0.x, v0.y); pk.y = pkbf(v0.z, v0.w);
      pk.z = pkbf(v1.x, v1.y); pk.w = pkbf(v1.z, v1.w);
      Ws4[row*8 + (seg ^ (row & 7))] = pk;
    }
    __syncthreads();
    #pragma unroll
    for (int ks = 0; ks < 2; ks++){
      short8 af[4], bf_[4];
      #pragma unroll
      for (int fi = 0; fi < 4; fi++){
        int row = wm + fi*16 + lrow;
        U16S8 u; u.u4 = As4[row*8 + ((ks*4 + lk) ^ (lrow & 7))];
        af[fi] = u.s8;
      }
      #pragma unroll
      for (int fj = 0; fj < 4; fj++){
        int row = wn + fj*16 + lrow;
        U16S8 u; u.u4 = Ws4[row*8 + ((ks*4 + lk) ^ (lrow & 7))];
        bf_[fj] = u.s8;
      }
      #pragma unroll
      for (int fi = 0; fi < 4; fi++)
        #pragma unroll
        for (int fj = 0; fj < 4; fj++)
          acc[fi][fj] = __builtin_amdgcn_mfma_f32_16x16x32_bf16(af[fi], bf_[fj], acc[fi][fj], 0, 0, 0);
    }
    __syncthreads();
  }
  #pragma unroll
  for (int fj = 0; fj < 4; fj++){
    int n = n0 + wn + fj*16 + lrow;
    float bias = lb[n];
    #pragma unroll
    for (int fi = 0; fi < 4; fi++){
      floatx4 av = acc[fi][fj];
      int mb = m0 + wm + fi*16 + lk*4;
      #pragma unroll
      for (int r = 0; r < 4; r++){
        int m = mb + r;
        if (m < B*T) out[(long)m*V + n] = av[r] + bias;
      }
    }
  }
}

// log-softmax with row cached in LDS (read out once, write once)
__global__ __launch_bounds__(1024) void k_lsm(float* __restrict__ out){
  __shared__ float4 rowbuf[V/4];          // 128 KB
  __shared__ float redm[1024], reds[1024];
  float4* row = (float4*)(out + (long)blockIdx.x * V);
  const int tid = threadIdx.x;
  float m = -INFINITY, s = 0.f;
  for (int n=tid;n<V/4;n+=1024){
    float4 v = row[n];
    rowbuf[n] = v;
    float cm = fmaxf(fmaxf(v.x,v.y), fmaxf(v.z,v.w));
    if (cm > m){ s *= __expf(m - cm); m = cm; }
    s += __expf(v.x-m)+__expf(v.y-m)+__expf(v.z-m)+__expf(v.w-m);
  }
  redm[tid]=m; reds[tid]=s; __syncthreads();
  for (int st=512;st>0;st>>=1){
    if (tid<st){
      float m1=redm[tid], s1=reds[tid];
      float m2=redm[tid+st], s2=reds[tid+st];
      float M=fmaxf(m1,m2);
      reds[tid]=s1*__expf(m1-M)+s2*__expf(m2-M);
      redm[tid]=M;
    }
    __syncthreads();
  }
  float lse = redm[0] + __logf(reds[0]);
  for (int n=tid;n<V/4;n+=1024){
    float4 v = rowbuf[n];
    v.x-=lse; v.y-=lse; v.z-=lse; v.w-=lse;
    row[n] = v;
  }
}

extern "C" void kernel_launch(void* const* d_in, const int* in_sizes, int n_in,
                              void* d_out, int out_size, void* d_ws, size_t ws_size,
                              hipStream_t stream){
  const float* enc    = (const float*)d_in[0];
  const float* target = (const float*)d_in[1];
  const float* pw     = (const float*)d_in[2];
  const float* pb     = (const float*)d_in[3];
  const float* wih0   = (const float*)d_in[4];
  const float* whh0   = (const float*)d_in[5];
  const float* bih0   = (const float*)d_in[6];
  const float* bhh0   = (const float*)d_in[7];
  const float* wih1   = (const float*)d_in[8];
  const float* whh1   = (const float*)d_in[9];
  const float* bih1   = (const float*)d_in[10];
  const float* bhh1   = (const float*)d_in[11];
  const float* lw     = (const float*)d_in[12];
  const float* lb     = (const float*)d_in[13];
  float* out = (float*)d_out;

  float* ws   = (float*)d_ws;
  float* xg0  = ws;                              // 6,553,600 f (fallback)
  float* P    = xg0 + (long)T*G4*B;              // 204,800 f (fallback)
  float* encp = P + T*E*B;                       // 4,096 f
  float* H1Tmk = encp + B*E;                     // 1,703,936 f (fallback)
  unsigned* Abf = (unsigned*)(H1Tmk + (long)MROWS*1024);  // 851,968 u32
  unsigned* h0A2 = Abf + 851968;                 // 16,384 each (64KB f16 state)
  unsigned* h0B2 = h0A2 + 16384;
  unsigned* h1A2 = h0B2 + 16384;
  unsigned* h1B2 = h1A2 + 16384;
  float* fh0a = (float*)(h1B2 + 16384);          // fallback f32 state
  float* fh0b = fh0a + H*B;
  float* fh1a = fh0b + H*B;
  float* fh1b = fh1a + H*B;
  float* fc0  = fh1b + H*B;
  float* fc1  = fc0 + H*B;
  unsigned* bar = (unsigned*)(fc1 + H*B);        // 1,024 u32
  __fp16* Pf16 = (__fp16*)(bar + 1024);          // 204,800 f16
  unsigned* lwsw = (unsigned*)(Pf16 + (long)T*B*E);  // 16,384,000 u32
  size_t need = (size_t)((char*)(lwsw + 16384000) - (char*)d_ws);
  bool pre = (ws_size >= need);

  k_encp<<<B, E, 0, stream>>>(enc, pw, pb, encp);
  k_proj<<<T*B, E, 0, stream>>>(target, pw, encp, P, Pf16);
  k_zero32<<<4, 256, 0, stream>>>(bar);

  uint4* lwsw4 = pre ? (uint4*)lwsw : (uint4*)0;
  void* cargs[] = {(void*)&whh0, (void*)&wih1, (void*)&whh1,
                   (void*)&wih0, (void*)&bih0, (void*)&bhh0,
                   (void*)&bih1, (void*)&bhh1,
                   (void*)&enc, (void*)&Pf16,
                   (void*)&lw, (void*)&lwsw4,
                   (void*)&h0A2, (void*)&h0B2, (void*)&h1A2, (void*)&h1B2,
                   (void*)&Abf, (void*)&bar};
  hipError_t cerr = hipLaunchCooperativeKernel((void*)k_cells, dim3(NB), dim3(1024),
                                               cargs, 0, stream);
  if (cerr != hipSuccess){
    if (pre) k_cvtw<<<16000, 256, 0, stream>>>(lw, (uint4*)lwsw);
    k_xg0<<<(T*G4*B)/256, 256, 0, stream>>>(wih0, bih0, bhh0, P, xg0);
    k_init<<<(H*B)/256, 256, 0, stream>>>(enc, fh0a, fc0, fh1a, fc1);
    float* h0in=fh0a; float* h0out=fh0b;
    float* h1in=fh1a; float* h1out=fh1b;
    for (int t=0;t<T;t++){
      k_cell0<<<256, 256, 0, stream>>>(whh0, xg0 + (long)t*G4*B, h0in, h0out, fc0);
      k_cell1<<<256, 256, 0, stream>>>(wih1, whh1, bih1, bhh1, h0out, h1in, h1out, fc1,
                                       H1Tmk, t);
      float* tmp;
      tmp=h0in; h0in=h0out; h0out=tmp;
      tmp=h1in; h1in=h1out; h1out=tmp;
    }
    k_pack<<<800, 256, 0, stream>>>(H1Tmk, (uint4*)Abf);
  }

  if (pre) k_gemm_pre<<<3250, 256, 0, stream>>>((const uint4*)Abf, (const uint4*)lwsw, lb, out);
  else     k_gemm_inl<<<3250, 256, 0, stream>>>((const uint4*)Abf, lw, lb, out);
  k_lsm<<<B*T, 1024, 0, stream>>>(out);
}

// Round 24
// 755.782 us; speedup vs baseline: 1.4144x; 1.0290x over previous
//
#include <hip/hip_runtime.h>
#include <hip/hip_bf16.h>
#include <math.h>

#define B 32
#define T 50
#define H 1024
#define E 128
#define V 32000
#define G4 4096   // 4*H
#define HE 1152   // H+E
#define MROWS 1664 // 13*128 padded M for GEMM
#define NB 256    // coop grid blocks

typedef __fp16 half2v __attribute__((ext_vector_type(2)));
typedef __fp16 half8 __attribute__((ext_vector_type(8)));
typedef unsigned long long ull;
union U32H2 { unsigned u; half2v h; };
union U4H8 { uint4 u4; half8 h8; };
typedef short short8 __attribute__((ext_vector_type(8)));
typedef float floatx4 __attribute__((ext_vector_type(4)));
union U16S8 { uint4 u4; short8 s8; };

// 16B LLC-coherent load (bypass L1+L2), issue-only; pair with one vmcnt wait.
#define LLC_LOAD(dst, ptr) \
  asm volatile("global_load_dwordx4 %0, %1, off sc0 sc1" : "=v"((dst).u4) : "v"(ptr))

__device__ __forceinline__ float sigm(float x){ return 1.0f/(1.0f+expf(-x)); }

__device__ __forceinline__ half2v pk2(float a, float b){
#if __has_builtin(__builtin_amdgcn_cvt_pkrtz)
  return __builtin_amdgcn_cvt_pkrtz(a, b);
#else
  half2v r; r.x = (__fp16)a; r.y = (__fp16)b; return r;
#endif
}

// pack two f32 -> one u32 of two bf16 (RNE)
__device__ __forceinline__ unsigned pkbf(float a, float b){
  unsigned ua = __float_as_uint(a), ub = __float_as_uint(b);
  unsigned ra = (ua + 0x7FFFu + ((ua>>16)&1u)) >> 16;
  unsigned rb = (ub + 0x7FFFu + ((ub>>16)&1u)) >> 16;
  return ra | (rb << 16);
}

// agent-scope store, 8B (bypasses caches, lands at LLC)
__device__ __forceinline__ void stA8(void* p, uint2 v){
  ull q = ((ull)v.y << 32) | (ull)v.x;
  __hip_atomic_store((ull*)p, q, __ATOMIC_RELAXED, __HIP_MEMORY_SCOPE_AGENT);
}

// ---- fence-free tree grid barrier (8 leaves x 32 + root) — r17 verified ----
__device__ __forceinline__ void gbar(unsigned* bar, unsigned ep){
  __syncthreads();
  if (threadIdx.x == 0){
    asm volatile("s_waitcnt vmcnt(0)" ::: "memory");
    unsigned g = blockIdx.x & 7u;
    unsigned old = __hip_atomic_fetch_add(&bar[64 + g*64], 1u,
                     __ATOMIC_RELAXED, __HIP_MEMORY_SCOPE_AGENT);
    if (old == ep*32u - 1u)
      __hip_atomic_fetch_add(&bar[0], 1u, __ATOMIC_RELAXED, __HIP_MEMORY_SCOPE_AGENT);
    while (__hip_atomic_load(&bar[0], __ATOMIC_RELAXED, __HIP_MEMORY_SCOPE_AGENT) < ep*8u)
      __builtin_amdgcn_s_sleep(1);
  }
  __syncthreads();
}

// encp[b][e] = proj_b[e] + sum_j enc[b][j] * proj_w[e][E+j]
__global__ void k_encp(const float* __restrict__ enc, const float* __restrict__ pw,
                       const float* __restrict__ pb, float* __restrict__ encp){
  int b = blockIdx.x, e = threadIdx.x;
  const float* er = enc + b*H;
  const float* wr = pw + e*HE + E;
  float acc = pb[e];
  for (int j=0;j<H;j+=4){
    float4 w4 = *(const float4*)(wr+j);
    float4 e4 = *(const float4*)(er+j);
    acc += w4.x*e4.x + w4.y*e4.y + w4.z*e4.z + w4.w*e4.w;
  }
  encp[b*E+e] = acc;
}

// P[t][e][b] f32 (fallback) + Pf16[t][b][e] (coop MFMA B-operand)
__global__ void k_proj(const float* __restrict__ target, const float* __restrict__ pw,
                       const float* __restrict__ encp, float* __restrict__ P,
                       __fp16* __restrict__ Pf16){
  int t = blockIdx.x / B, b = blockIdx.x % B, e = threadIdx.x;
  const float* xr = target + (b*T + t)*E;
  const float* wr = pw + e*HE;
  float acc = encp[b*E+e];
  for (int j=0;j<E;j+=4){
    float4 w4 = *(const float4*)(wr+j);
    float4 x4 = *(const float4*)(xr+j);
    acc += w4.x*x4.x + w4.y*x4.y + w4.z*x4.z + w4.w*x4.w;
  }
  P[(t*E + e)*B + b] = acc;
  Pf16[((long)t*B + b)*E + e] = (__fp16)acc;
}

// xg0[t][r][b] (fallback path only)
__global__ void k_xg0(const float* __restrict__ wih0, const float* __restrict__ bih0,
                      const float* __restrict__ bhh0, const float* __restrict__ P,
                      float* __restrict__ xg){
  int idx = blockIdx.x*256 + threadIdx.x;
  int b = idx & 31; int r = (idx >> 5) & 4095; int t = idx >> 17;
  const float* wr = wih0 + r*E;
  const float* pr = P + t*E*B + b;
  float acc = bih0[r] + bhh0[r];
  #pragma unroll 8
  for (int e=0;e<E;e+=4){
    float4 w4 = *(const float4*)(wr+e);
    acc += w4.x*pr[(e+0)*B] + w4.y*pr[(e+1)*B]
         + w4.z*pr[(e+2)*B] + w4.w*pr[(e+3)*B];
  }
  xg[idx] = acc;
}

__global__ void k_zero32(unsigned* __restrict__ p){
  p[blockIdx.x*256 + threadIdx.x] = 0u;
}

// convert lw f32 -> bf16 in the GEMM's swizzled tile layout (fallback path only)
__global__ void k_cvtw(const float* __restrict__ lw, uint4* __restrict__ wsw){
  int gid = blockIdx.x*256 + threadIdx.x;   // 4,096,000
  int n = gid >> 7, rem = gid & 127;
  int k0c = rem >> 3, seg = rem & 7;
  const float4* src = (const float4*)(lw + (long)n*H + k0c*64 + seg*8);
  float4 v0 = src[0], v1 = src[1];
  uint4 pk;
  pk.x = pkbf(v0.x, v0.y); pk.y = pkbf(v0.z, v0.w);
  pk.z = pkbf(v1.x, v1.y); pk.w = pkbf(v1.z, v1.w);
  int bn = n >> 7, row = n & 127;
  wsw[((long)(bn*16 + k0c)*128 + row)*8 + (seg ^ (row & 7))] = pk;
}

// pack H1Tmk f32 [m][k] -> Abf swizzled bf16 tiles (fallback path only)
__global__ void k_pack(const float* __restrict__ H1Tmk, uint4* __restrict__ Abf){
  int gid = blockIdx.x*256 + threadIdx.x;   // 204,800
  int m = gid >> 7, rem = gid & 127;
  int k0c = rem >> 3, seg = rem & 7;
  const float4* src = (const float4*)(H1Tmk + (long)m*1024 + k0c*64 + seg*8);
  float4 v0 = src[0], v1 = src[1];
  uint4 pk;
  pk.x = pkbf(v0.x, v0.y); pk.y = pkbf(v0.z, v0.w);
  pk.z = pkbf(v1.x, v1.y); pk.w = pkbf(v1.z, v1.w);
  int bm = m >> 7, row = m & 127;
  Abf[((long)(bm*16 + k0c)*128 + row)*8 + (seg ^ (row & 7))] = pk;
}

// ---------------- cooperative persistent cells (v17: parallel L0/L1 reduce) ----------------
__global__ __launch_bounds__(1024, 4) void k_cells(
    const float* __restrict__ whh0, const float* __restrict__ wih1, const float* __restrict__ whh1,
    const float* __restrict__ wih0, const float* __restrict__ bih0, const float* __restrict__ bhh0,
    const float* __restrict__ bih1, const float* __restrict__ bhh1,
    const float* __restrict__ enc, const __fp16* __restrict__ Pf16,
    const float* __restrict__ lw, uint4* __restrict__ lwsw,
    unsigned* __restrict__ h0A2, unsigned* __restrict__ h0B2,
    unsigned* __restrict__ h1A2, unsigned* __restrict__ h1B2,
    unsigned* __restrict__ Abf, unsigned* __restrict__ bar){
  const int gB = blockIdx.x;
  const int tid = threadIdx.x;
  const int w = tid >> 6;       // wave 0..15 = k-chunk owner
  const int l = tid & 63;
  const int lrow = l & 15;      // fragment row/col
  const int lk = l >> 4;        // k-segment 0..3

  __shared__ uint4 w0s4[16*128];        // layer0 whh0 rows, f16 swizzled (32 KB)
  __shared__ uint4 w1s4[32*128];        // wih1(0-15)+whh1(16-31) (64 KB)
  __shared__ uint4 w0x4[16*16];         // layer0 wih0 rows, f16 swizzled (4 KB)
  __shared__ __fp16 partA[16][16][34];  // layer1 partials (17.4 KB)
  __shared__ __fp16 partB[16][16][34];  // layer0 partials (17.4 KB)
  __shared__ float gates1[16][32];
  __shared__ float gates0[16][32];
  __shared__ float cst[2][4][32];
  __shared__ float bs1v[16];
  __shared__ float bs0v[16];
  __shared__ __fp16 h1loc[4][1600];     // [hl][b*T+t] (12.8 KB)

  // ---- stage weights f32 -> f16, XOR-swizzled segments ----
  for (int i = tid; i < 2048; i += 1024){
    int row = i >> 7, seg = i & 127;
    int q = row >> 2, hl = row & 3;
    const float* src = whh0 + ((long)q*H + 4*gB + hl)*H + seg*8;
    float4 v0 = *(const float4*)src, v1 = *(const float4*)(src+4);
    U32H2 z0,z1,z2,z3;
    z0.h = pk2(v0.x,v0.y); z1.h = pk2(v0.z,v0.w);
    z2.h = pk2(v1.x,v1.y); z3.h = pk2(v1.z,v1.w);
    uint4 pk; pk.x=z0.u; pk.y=z1.u; pk.z=z2.u; pk.w=z3.u;
    int phys = (seg & ~7) | ((seg & 7) ^ (row & 7));
    w0s4[row*128 + phys] = pk;
  }
  for (int i = tid; i < 4096; i += 1024){
    int row = i >> 7, seg = i & 127;
    int rr = row & 15;
    int q = rr >> 2, hl = rr & 3;
    const float* srcm = (row < 16) ? wih1 : whh1;
    const float* src = srcm + ((long)q*H + 4*gB + hl)*H + seg*8;
    float4 v0 = *(const float4*)src, v1 = *(const float4*)(src+4);
    U32H2 z0,z1,z2,z3;
    z0.h = pk2(v0.x,v0.y); z1.h = pk2(v0.z,v0.w);
    z2.h = pk2(v1.x,v1.y); z3.h = pk2(v1.z,v1.w);
    uint4 pk; pk.x=z0.u; pk.y=z1.u; pk.z=z2.u; pk.w=z3.u;
    int phys = (seg & ~7) | ((seg & 7) ^ (rr & 7));
    w1s4[row*128 + phys] = pk;
  }
  if (tid < 256){
    int row = tid >> 4, seg = tid & 15;
    int q = row >> 2, hl = row & 3;
    const float* src = wih0 + ((long)q*H + 4*gB + hl)*E + seg*8;
    float4 v0 = *(const float4*)src, v1 = *(const float4*)(src+4);
    U32H2 z0,z1,z2,z3;
    z0.h = pk2(v0.x,v0.y); z1.h = pk2(v0.z,v0.w);
    z2.h = pk2(v1.x,v1.y); z3.h = pk2(v1.z,v1.w);
    uint4 pk; pk.x=z0.u; pk.y=z1.u; pk.z=z2.u; pk.w=z3.u;
    int phys = (seg & ~7) | ((seg & 7) ^ (row & 7));
    w0x4[row*16 + phys] = pk;
  }
  if (tid < 16){
    int q = tid >> 2, hl = tid & 3;
    bs1v[tid] = bih1[q*H + 4*gB + hl] + bhh1[q*H + 4*gB + hl];
    bs0v[tid] = bih0[q*H + 4*gB + hl] + bhh0[q*H + 4*gB + hl];
  }
  if (tid < 128){
    int hl = tid >> 5, bb = tid & 31;
    float v = enc[bb*H + 4*gB + hl];
    cst[0][hl][bb] = v; cst[1][hl][bb] = v;
  }
  if (tid < 32){
    int bb = tid;
    U32H2 z0, z1;
    z0.h = pk2(enc[bb*H + 4*gB + 0], enc[bb*H + 4*gB + 1]);
    z1.h = pk2(enc[bb*H + 4*gB + 2], enc[bb*H + 4*gB + 3]);
    uint2 val; val.x = z0.u; val.y = z1.u;
    stA8((char*)h0A2 + (long)(bb*1024 + 4*gB)*2, val);
    stA8((char*)h1A2 + (long)(bb*1024 + 4*gB)*2, val);
  }
  unsigned ep = 1;
  gbar(bar, ep); ep++;

  const bool cvw = (lwsw != 0) && tid >= 128 && tid < 448;
  const int cvtid = tid - 128;
  float4 cva, cvb;   // pipelined lw values (loaded at p, stored at p+1)

  for (int p = 0; p <= T; p++){
    const unsigned* h0r = (p & 1) ? h0B2 : h0A2;
    unsigned*       h0w = (p & 1) ? h0A2 : h0B2;
    const unsigned* h1r = (p & 1) ? h1A2 : h1B2;
    unsigned*       h1w = (p & 1) ? h1B2 : h1A2;

    // ---- batched LLC state loads (issue all, wait once) ----
    int c = (w + gB + p) & 15;
    U4H8 b0a0, b0a1, b0b0, b0b1, b1a0, b1a1, b1b0, b1b1;
    {
      int kb = c*64;
      const __fp16* h0f = (const __fp16*)h0r;
      const __fp16* h1f = (const __fp16*)h1r;
      const __fp16* s0a = h0f + lrow*1024 + kb + lk*8;
      const __fp16* s0b = h0f + (16+lrow)*1024 + kb + lk*8;
      LLC_LOAD(b0a0, s0a);      LLC_LOAD(b0a1, s0a + 32);
      LLC_LOAD(b0b0, s0b);      LLC_LOAD(b0b1, s0b + 32);
      if (p >= 1){
        const __fp16* s1a = h1f + lrow*1024 + kb + lk*8;
        const __fp16* s1b = h1f + (16+lrow)*1024 + kb + lk*8;
        LLC_LOAD(b1a0, s1a);    LLC_LOAD(b1a1, s1a + 32);
        LLC_LOAD(b1b0, s1b);    LLC_LOAD(b1b1, s1b + 32);
      }
      asm volatile("s_waitcnt vmcnt(0)" ::: "memory");
      __builtin_amdgcn_sched_barrier(0);
    }

    // ---- MFMA matvec ----
    floatx4 acc10 = {0,0,0,0}, acc11 = {0,0,0,0};
    floatx4 acc00 = {0,0,0,0}, acc01 = {0,0,0,0};
    #pragma unroll
    for (int ks = 0; ks < 2; ks++){
      int phys = c*8 + (((ks<<2) + lk) ^ (lrow & 7));
      half8 B0a = ks ? b0a1.h8 : b0a0.h8;
      half8 B0b = ks ? b0b1.h8 : b0b0.h8;
      if (p < T){
        U4H8 a0v; a0v.u4 = w0s4[lrow*128 + phys];
        acc00 = __builtin_amdgcn_mfma_f32_16x16x32_f16(a0v.h8, B0a, acc00, 0, 0, 0);
        acc01 = __builtin_amdgcn_mfma_f32_16x16x32_f16(a0v.h8, B0b, acc01, 0, 0, 0);
      }
      if (p >= 1){
        U4H8 a1i; a1i.u4 = w1s4[lrow*128 + phys];
        U4H8 a1h; a1h.u4 = w1s4[(16+lrow)*128 + phys];
        half8 B1a = ks ? b1a1.h8 : b1a0.h8;
        half8 B1b = ks ? b1b1.h8 : b1b0.h8;
        acc10 = __builtin_amdgcn_mfma_f32_16x16x32_f16(a1i.h8, B0a, acc10, 0, 0, 0);
        acc10 = __builtin_amdgcn_mfma_f32_16x16x32_f16(a1h.h8, B1a, acc10, 0, 0, 0);
        acc11 = __builtin_amdgcn_mfma_f32_16x16x32_f16(a1i.h8, B0b, acc11, 0, 0, 0);
        acc11 = __builtin_amdgcn_mfma_f32_16x16x32_f16(a1h.h8, B1b, acc11, 0, 0, 0);
      }
    }
    // ---- fused xg contribution: waves with c<2 add wih0 . P_t ----
    if (p < T && c < 2){
      const __fp16* pbase = Pf16 + (long)p*B*E + c*64 + lk*8;
      U4H8 q0a, q1a, q0b, q1b;
      q0a.u4 = *(const uint4*)(pbase + lrow*E);
      q1a.u4 = *(const uint4*)(pbase + lrow*E + 32);
      q0b.u4 = *(const uint4*)(pbase + (16+lrow)*E);
      q1b.u4 = *(const uint4*)(pbase + (16+lrow)*E + 32);
      #pragma unroll
      for (int ks = 0; ks < 2; ks++){
        int phys = c*8 + (((ks<<2) + lk) ^ (lrow & 7));
        U4H8 aw; aw.u4 = w0x4[lrow*16 + phys];
        acc00 = __builtin_amdgcn_mfma_f32_16x16x32_f16(aw.h8, ks ? q1a.h8 : q0a.h8, acc00, 0, 0, 0);
        acc01 = __builtin_amdgcn_mfma_f32_16x16x32_f16(aw.h8, ks ? q1b.h8 : q0b.h8, acc01, 0, 0, 0);
      }
    }
    // ---- pipelined lw cvtw: store slot p-1 (regs ready), load slot p (no wait) ----
    if (cvw){
      if (p >= 1){
        int slot = (gB*T + (p-1))*320 + cvtid;
        int n = slot >> 7, rem = slot & 127;
        int k0c = rem >> 3, seg = rem & 7;
        uint4 pk;
        pk.x = pkbf(cva.x, cva.y); pk.y = pkbf(cva.z, cva.w);
        pk.z = pkbf(cvb.x, cvb.y); pk.w = pkbf(cvb.z, cvb.w);
        int bn = n >> 7, row = n & 127;
        lwsw[((long)(bn*16 + k0c)*128 + row)*8 + (seg ^ (row & 7))] = pk;
      }
      if (p < T){
        int slot = (gB*T + p)*320 + cvtid;
        int n = slot >> 7, rem = slot & 127;
        int k0c = rem >> 3, seg = rem & 7;
        const float4* src = (const float4*)(lw + (long)n*H + k0c*64 + seg*8);
        cva = src[0]; cvb = src[1];
      }
    }
    // ---- stash both layers' partials (f16), one sync ----
    if (p >= 1){
      #pragma unroll
      for (int r = 0; r < 4; r++){
        partA[w][lk*4 + r][lrow]      = (__fp16)acc10[r];
        partA[w][lk*4 + r][16 + lrow] = (__fp16)acc11[r];
      }
    }
    if (p < T){
      #pragma unroll
      for (int r = 0; r < 4; r++){
        partB[w][lk*4 + r][lrow]      = (__fp16)acc00[r];
        partB[w][lk*4 + r][16 + lrow] = (__fp16)acc01[r];
      }
    }
    __syncthreads();
    // ---- parallel reduce: tid<512 -> layer1, tid>=512 -> layer0 ----
    if (tid < 512){
      if (p >= 1){
        int r = tid >> 5, bb = tid & 31;
        float s = 0.f;
        #pragma unroll
        for (int w2 = 0; w2 < 16; w2++) s += (float)partA[w2][r][bb];
        float v = s + bs1v[r];
        gates1[r][bb] = ((r >> 2) == 2) ? tanhf(v) : sigm(v);
      }
    } else {
      if (p < T){
        int t2 = tid - 512;
        int r = t2 >> 5, bb = t2 & 31;
        float s = 0.f;
        #pragma unroll
        for (int w2 = 0; w2 < 16; w2++) s += (float)partB[w2][r][bb];
        float v = s + bs0v[r];
        gates0[r][bb] = ((r >> 2) == 2) ? tanhf(v) : sigm(v);
      }
    }
    __syncthreads();
    // ---- both cells on wave 0 (lanes 0-31: layer1, lanes 32-63: layer0) ----
    if (tid < 64){
      int bb = tid & 31;
      bool lay1 = (tid < 32);
      bool active = lay1 ? (p >= 1) : (p < T);
      if (active){
        float (*gs)[32] = lay1 ? gates1 : gates0;
        int ci = lay1 ? 1 : 0;
        float hn[4];
        #pragma unroll
        for (int hl = 0; hl < 4; hl++){
          float cn = gs[4+hl][bb]*cst[ci][hl][bb] + gs[0+hl][bb]*gs[8+hl][bb];
          cst[ci][hl][bb] = cn;
          hn[hl] = gs[12+hl][bb]*tanhf(cn);
        }
        if (lay1){
          int t1 = p - 1;
          #pragma unroll
          for (int hl = 0; hl < 4; hl++) h1loc[hl][bb*T + t1] = (__fp16)hn[hl];
        }
        U32H2 z0, z1; z0.h = pk2(hn[0], hn[1]); z1.h = pk2(hn[2], hn[3]);
        uint2 val; val.x = z0.u; val.y = z1.u;
        unsigned* dst = lay1 ? h1w : h0w;
        stA8((char*)dst + (long)(bb*1024 + 4*gB)*2, val);
      }
    }
    gbar(bar, ep); ep++;
  }

  // direct swizzled-Abf flush: block gB owns k = 4gB..4gB+3 (8B half-slot)
  {
    int k0c = gB >> 4;
    int seg = (gB & 15) >> 1;
    int posb = (gB & 1) * 8;
    for (int m = tid; m < B*T; m += 1024){
      float v0 = (float)h1loc[0][m], v1 = (float)h1loc[1][m];
      float v2 = (float)h1loc[2][m], v3 = (float)h1loc[3][m];
      int bm = m >> 7, row = m & 127;
      long slot = ((long)(bm*16 + k0c)*128 + row)*8 + (seg ^ (row & 7));
      uint2 val; val.x = pkbf(v0, v1); val.y = pkbf(v2, v3);
      *(uint2*)((char*)Abf + slot*16 + posb) = val;
    }
  }
}

// ---------------- fallback per-step cells ----------------
__global__ void k_init(const float* __restrict__ enc, float* __restrict__ h0, float* __restrict__ c0,
                       float* __restrict__ h1, float* __restrict__ c1){
  int idx = blockIdx.x*256 + threadIdx.x;
  int b = idx & 31, h = idx >> 5;
  float v = enc[b*H + h];
  h0[idx]=v; c0[idx]=v; h1[idx]=v; c1[idx]=v;
}

__global__ __launch_bounds__(256) void k_cell0(const float* __restrict__ whh, const float* __restrict__ xg_t,
                       const float* __restrict__ h_in, float* __restrict__ h_out,
                       float* __restrict__ c){
  int h = (blockIdx.x*256 + threadIdx.x) >> 6;
  int lane = threadIdx.x & 63;
  int b = lane & 31, kh = lane >> 5;
  const float* w0 = whh + (0*H + h)*H + kh*512;
  const float* w1 = whh + (1*H + h)*H + kh*512;
  const float* w2 = whh + (2*H + h)*H + kh*512;
  const float* w3 = whh + (3*H + h)*H + kh*512;
  const float* hk = h_in + (kh*512)*B + b;
  float a0=0,a1=0,a2=0,a3=0, p0=0,p1=0,p2=0,p3=0;
  #pragma unroll 4
  for (int k=0;k<512;k+=4){
    float4 w40 = *(const float4*)(w0+k);
    float4 w41 = *(const float4*)(w1+k);
    float4 w42 = *(const float4*)(w2+k);
    float4 w43 = *(const float4*)(w3+k);
    float hv0 = hk[(k+0)*B], hv1 = hk[(k+1)*B], hv2 = hk[(k+2)*B], hv3 = hk[(k+3)*B];
    a0 += w40.x*hv0 + w40.y*hv1;  p0 += w40.z*hv2 + w40.w*hv3;
    a1 += w41.x*hv0 + w41.y*hv1;  p1 += w41.z*hv2 + w41.w*hv3;
    a2 += w42.x*hv0 + w42.y*hv1;  p2 += w42.z*hv2 + w42.w*hv3;
    a3 += w43.x*hv0 + w43.y*hv1;  p3 += w43.z*hv2 + w43.w*hv3;
  }
  float g0=a0+p0, g1=a1+p1, g2=a2+p2, g3=a3+p3;
  g0 += __shfl_xor(g0, 32);
  g1 += __shfl_xor(g1, 32);
  g2 += __shfl_xor(g2, 32);
  g3 += __shfl_xor(g3, 32);
  g0 += xg_t[(0*H+h)*B + b];
  g1 += xg_t[(1*H+h)*B + b];
  g2 += xg_t[(2*H+h)*B + b];
  g3 += xg_t[(3*H+h)*B + b];
  float ig = sigm(g0), fg = sigm(g1), gg = tanhf(g2), og = sigm(g3);
  int sidx = h*B + b;
  float cn = fg*c[sidx] + ig*gg;
  float hn = og*tanhf(cn);
  if (kh==0){ c[sidx]=cn; h_out[sidx]=hn; }
}

__global__ __launch_bounds__(256) void k_cell1(const float* __restrict__ wih, const float* __restrict__ whh,
                       const float* __restrict__ bih, const float* __restrict__ bhh,
                       const float* __restrict__ h0n, const float* __restrict__ h_in,
                       float* __restrict__ h_out, float* __restrict__ c,
                       float* __restrict__ H1Tmk, int t){
  int h = (blockIdx.x*256 + threadIdx.x) >> 6;
  int lane = threadIdx.x & 63;
  int b = lane & 31, kh = lane >> 5;
  float a0=0,a1=0,a2=0,a3=0, p0=0,p1=0,p2=0,p3=0;
  {
    const float* w0 = wih + (0*H + h)*H + kh*512;
    const float* w1 = wih + (1*H + h)*H + kh*512;
    const float* w2 = wih + (2*H + h)*H + kh*512;
    const float* w3 = wih + (3*H + h)*H + kh*512;
    const float* hk = h0n + (kh*512)*B + b;
    #pragma unroll 4
    for (int k=0;k<512;k+=4){
      float4 w40 = *(const float4*)(w0+k);
      float4 w41 = *(const float4*)(w1+k);
      float4 w42 = *(const float4*)(w2+k);
      float4 w43 = *(const float4*)(w3+k);
      float hv0 = hk[(k+0)*B], hv1 = hk[(k+1)*B], hv2 = hk[(k+2)*B], hv3 = hk[(k+3)*B];
      a0 += w40.x*hv0 + w40.y*hv1;  p0 += w40.z*hv2 + w40.w*hv3;
      a1 += w41.x*hv0 + w41.y*hv1;  p1 += w41.z*hv2 + w41.w*hv3;
      a2 += w42.x*hv0 + w42.y*hv1;  p2 += w42.z*hv2 + w42.w*hv3;
      a3 += w43.x*hv0 + w43.y*hv1;  p3 += w43.z*hv2 + w43.w*hv3;
    }
  }
  {
    const float* w0 = whh + (0*H + h)*H + kh*512;
    const float* w1 = whh + (1*H + h)*H + kh*512;
    const float* w2 = whh + (2*H + h)*H + kh*512;
    const float* w3 = whh + (3*H + h)*H + kh*512;
    const float* hk = h_in + (kh*512)*B + b;
    #pragma unroll 4
    for (int k=0;k<512;k+=4){
      float4 w40 = *(const float4*)(w0+k);
      float4 w41 = *(const float4*)(w1+k);
      float4 w42 = *(const float4*)(w2+k);
      float4 w43 = *(const float4*)(w3+k);
      float hv0 = hk[(k+0)*B], hv1 = hk[(k+1)*B], hv2 = hk[(k+2)*B], hv3 = hk[(k+3)*B];
      a0 += w40.x*hv0 + w40.y*hv1;  p0 += w40.z*hv2 + w40.w*hv3;
      a1 += w41.x*hv0 + w41.y*hv1;  p1 += w41.z*hv2 + w41.w*hv3;
      a2 += w42.x*hv0 + w42.y*hv1;  p2 += w42.z*hv2 + w42.w*hv3;
      a3 += w43.x*hv0 + w43.y*hv1;  p3 += w43.z*hv2 + w43.w*hv3;
    }
  }
  float g0=a0+p0, g1=a1+p1, g2=a2+p2, g3=a3+p3;
  g0 += __shfl_xor(g0, 32);
  g1 += __shfl_xor(g1, 32);
  g2 += __shfl_xor(g2, 32);
  g3 += __shfl_xor(g3, 32);
  g0 += bih[0*H+h] + bhh[0*H+h];
  g1 += bih[1*H+h] + bhh[1*H+h];
  g2 += bih[2*H+h] + bhh[2*H+h];
  g3 += bih[3*H+h] + bhh[3*H+h];
  float ig = sigm(g0), fg = sigm(g1), gg = tanhf(g2), og = sigm(g3);
  int sidx = h*B + b;
  float cn = fg*c[sidx] + ig*gg;
  float hn = og*tanhf(cn);
  if (kh==0){ c[sidx]=cn; h_out[sidx]=hn; H1Tmk[((long)(b*T + t))*1024 + h] = hn; }
}

// ---------------- MFMA bf16 output GEMM (pre-swizzled operands) ----------------
__global__ __launch_bounds__(256, 2) void k_gemm_pre(const uint4* __restrict__ Abf4,
                      const uint4* __restrict__ Wsw4, const float* __restrict__ lb,
                      float* __restrict__ out){
  __shared__ uint4 As4[1024];
  __shared__ uint4 Ws4[1024];
  const int tid = threadIdx.x;
  int orig = blockIdx.x;
  int xcd = orig & 7, ii = orig >> 3;
  int wgid = (xcd < 2 ? xcd*407 : 814 + (xcd-2)*406) + ii;
  int bm = wgid % 13, bn = wgid / 13;
  int m0 = bm*128, n0 = bn*128;
  const int wv = tid >> 6, l = tid & 63;
  const int wm = (wv >> 1)*64, wn = (wv & 1)*64;
  const int lrow = l & 15, lk = l >> 4;

  floatx4 acc[4][4] = {};
  for (int k0c = 0; k0c < 16; k0c++){
    const uint4* sA = Abf4 + (long)(bm*16 + k0c)*1024;
    const uint4* sW = Wsw4 + (long)(bn*16 + k0c)*1024;
    #pragma unroll
    for (int it = 0; it < 4; it++){
      int slot = tid + it*256;
      As4[slot] = sA[slot];
      Ws4[slot] = sW[slot];
    }
    __syncthreads();
    #pragma unroll
    for (int ks = 0; ks < 2; ks++){
      short8 af[4], bf_[4];
      #pragma unroll
      for (int fi = 0; fi < 4; fi++){
        int row = wm + fi*16 + lrow;
        U16S8 u; u.u4 = As4[row*8 + ((ks*4 + lk) ^ (lrow & 7))];
        af[fi] = u.s8;
      }
      #pragma unroll
      for (int fj = 0; fj < 4; fj++){
        int row = wn + fj*16 + lrow;
        U16S8 u; u.u4 = Ws4[row*8 + ((ks*4 + lk) ^ (lrow & 7))];
        bf_[fj] = u.s8;
      }
      #pragma unroll
      for (int fi = 0; fi < 4; fi++)
        #pragma unroll
        for (int fj = 0; fj < 4; fj++)
          acc[fi][fj] = __builtin_amdgcn_mfma_f32_16x16x32_bf16(af[fi], bf_[fj], acc[fi][fj], 0, 0, 0);
    }
    __syncthreads();
  }
  #pragma unroll
  for (int fj = 0; fj < 4; fj++){
    int n = n0 + wn + fj*16 + lrow;
    float bias = lb[n];
    #pragma unroll
    for (int fi = 0; fi < 4; fi++){
      floatx4 av = acc[fi][fj];
      int mb = m0 + wm + fi*16 + lk*4;
      #pragma unroll
      for (int r = 0; r < 4; r++){
        int m = mb + r;
        if (m < B*T) out[(long)m*V + n] = av[r] + bias;
      }
    }
  }
}

// fallback GEMM: A pre-swizzled, W converted inline from f32
__global__ __launch_bounds__(256, 2) void k_gemm_inl(const uint4* __restrict__ Abf4,
                      const float* __restrict__ lw, const float* __restrict__ lb,
                      float* __restrict__ out){
  __shared__ uint4 As4[1024];
  __shared__ uint4 Ws4[1024];
  const int tid = threadIdx.x;
  int orig = blockIdx.x;
  int xcd = orig & 7, ii = orig >> 3;
  int wgid = (xcd < 2 ? xcd*407 : 814 + (xcd-2)*406) + ii;
  int bm = wgid % 13, bn = wgid / 13;
  int m0 = bm*128, n0 = bn*128;
  const int wv = tid >> 6, l = tid & 63;
  const int wm = (wv >> 1)*64, wn = (wv & 1)*64;
  const int lrow = l & 15, lk = l >> 4;

  floatx4 acc[4][4] = {};
  for (int k0c = 0; k0c < 16; k0c++){
    const uint4* sA = Abf4 + (long)(bm*16 + k0c)*1024;
    #pragma unroll
    for (int it = 0; it < 4; it++){
      int slot = tid + it*256;
      As4[slot] = sA[slot];
      int row = slot >> 3, seg = slot & 7;
      const float4* src = (const float4*)(lw + (long)(n0+row)*H + k0c*64 + seg*8);
      float4 v0 = src[0], v1 = src[1];
      uint4 pk;
      pk.x = pkbf(v0.x, v0.y); pk.y = pkbf(v0.z, v0.w);
      pk.z = pkbf(v1.x, v1.y); pk.w = pkbf(v1.z, v1.w);
      Ws4[row*8 + (seg ^ (row & 7))] = pk;
    }
    __syncthreads();
    #pragma unroll
    for (int ks = 0; ks < 2; ks++){
      short8 af[4], bf_[4];
      #pragma unroll
      for (int fi = 0; fi < 4; fi++){
        int row = wm + fi*16 + lrow;
        U16S8 u; u.u4 = As4[row*8 + ((ks*4 + lk) ^ (lrow & 7))];
        af[fi] = u.s8;
      }
      #pragma unroll
      for (int fj = 0; fj < 4; fj++){
        int row = wn + fj*16 + lrow;
        U16S8 u; u.u4 = Ws4[row*8 + ((ks*4 + lk) ^ (lrow & 7))];
        bf_[fj] = u.s8;
      }
      #pragma unroll
      for (int fi = 0; fi < 4; fi++)
        #pragma unroll
        for (int fj = 0; fj < 4; fj++)
          acc[fi][fj] = __builtin_amdgcn_mfma_f32_16x16x32_bf16(af[fi], bf_[fj], acc[fi][fj], 0, 0, 0);
    }
    __syncthreads();
  }
  #pragma unroll
  for (int fj = 0; fj < 4; fj++){
    int n = n0 + wn + fj*16 + lrow;
    float bias = lb[n];
    #pragma unroll
    for (int fi = 0; fi < 4; fi++){
      floatx4 av = acc[fi][fj];
      int mb = m0 + wm + fi*16 + lk*4;
      #pragma unroll
      for (int r = 0; r < 4; r++){
        int m = mb + r;
        if (m < B*T) out[(long)m*V + n] = av[r] + bias;
      }
    }
  }
}

// log-softmax with row cached in LDS (read out once, write once)
__global__ __launch_bounds__(1024) void k_lsm(float* __restrict__ out){
  __shared__ float4 rowbuf[V/4];          // 128 KB
  __shared__ float redm[1024], reds[1024];
  float4* row = (float4*)(out + (long)blockIdx.x * V);
  const int tid = threadIdx.x;
  float m = -INFINITY, s = 0.f;
  for (int n=tid;n<V/4;n+=1024){
    float4 v = row[n];
    rowbuf[n] = v;
    float cm = fmaxf(fmaxf(v.x,v.y), fmaxf(v.z,v.w));
    if (cm > m){ s *= __expf(m - cm); m = cm; }
    s += __expf(v.x-m)+__expf(v.y-m)+__expf(v.z-m)+__expf(v.w-m);
  }
  redm[tid]=m; reds[tid]=s; __syncthreads();
  for (int st=512;st>0;st>>=1){
    if (tid<st){
      float m1=redm[tid], s1=reds[tid];
      float m2=redm[tid+st], s2=reds[tid+st];
      float M=fmaxf(m1,m2);
      reds[tid]=s1*__expf(m1-M)+s2*__expf(m2-M);
      redm[tid]=M;
    }
    __syncthreads();
  }
  float lse = redm[0] + __logf(reds[0]);
  for (int n=tid;n<V/4;n+=1024){
    float4 v = rowbuf[n];
    v.x-=lse; v.y-=lse; v.z-=lse; v.w-=lse;
    row[n] = v;
  }
}

extern "C" void kernel_launch(void* const* d_in, const int* in_sizes, int n_in,
                              void* d_out, int out_size, void* d_ws, size_t ws_size,
                              hipStream_t stream){
  const float* enc    = (const float*)d_in[0];
  const float* target = (const float*)d_in[1];
  const float* pw     = (const float*)d_in[2];
  const float* pb     = (const float*)d_in[3];
  const float* wih0   = (const float*)d_in[4];
  const float* whh0   = (const float*)d_in[5];
  const float* bih0   = (const float*)d_in[6];
  const float* bhh0   = (const float*)d_in[7];
  const float* wih1   = (const float*)d_in[8];
  const float* whh1   = (const float*)d_in[9];
  const float* bih1   = (const float*)d_in[10];
  const float* bhh1   = (const float*)d_in[11];
  const float* lw     = (const float*)d_in[12];
  const float* lb     = (const float*)d_in[13];
  float* out = (float*)d_out;

  float* ws   = (float*)d_ws;
  float* xg0  = ws;                              // 6,553,600 f (fallback)
  float* P    = xg0 + (long)T*G4*B;              // 204,800 f (fallback)
  float* encp = P + T*E*B;                       // 4,096 f
  float* H1Tmk = encp + B*E;                     // 1,703,936 f (fallback)
  unsigned* Abf = (unsigned*)(H1Tmk + (long)MROWS*1024);  // 851,968 u32
  unsigned* h0A2 = Abf + 851968;                 // 16,384 each (64KB f16 state)
  unsigned* h0B2 = h0A2 + 16384;
  unsigned* h1A2 = h0B2 + 16384;
  unsigned* h1B2 = h1A2 + 16384;
  float* fh0a = (float*)(h1B2 + 16384);          // fallback f32 state
  float* fh0b = fh0a + H*B;
  float* fh1a = fh0b + H*B;
  float* fh1b = fh1a + H*B;
  float* fc0  = fh1b + H*B;
  float* fc1  = fc0 + H*B;
  unsigned* bar = (unsigned*)(fc1 + H*B);        // 1,024 u32
  __fp16* Pf16 = (__fp16*)(bar + 1024);          // 204,800 f16
  unsigned* lwsw = (unsigned*)(Pf16 + (long)T*B*E);  // 16,384,000 u32
  size_t need = (size_t)((char*)(lwsw + 16384000) - (char*)d_ws);
  bool pre = (ws_size >= need);

  k_encp<<<B, E, 0, stream>>>(enc, pw, pb, encp);
  k_proj<<<T*B, E, 0, stream>>>(target, pw, encp, P, Pf16);
  k_zero32<<<4, 256, 0, stream>>>(bar);

  uint4* lwsw4 = pre ? (uint4*)lwsw : (uint4*)0;
  void* cargs[] = {(void*)&whh0, (void*)&wih1, (void*)&whh1,
                   (void*)&wih0, (void*)&bih0, (void*)&bhh0,
                   (void*)&bih1, (void*)&bhh1,
                   (void*)&enc, (void*)&Pf16,
                   (void*)&lw, (void*)&lwsw4,
                   (void*)&h0A2, (void*)&h0B2, (void*)&h1A2, (void*)&h1B2,
                   (void*)&Abf, (void*)&bar};
  hipError_t cerr = hipLaunchCooperativeKernel((void*)k_cells, dim3(NB), dim3(1024),
                                               cargs, 0, stream);
  if (cerr != hipSuccess){
    if (pre) k_cvtw<<<16000, 256, 0, stream>>>(lw, (uint4*)lwsw);
    k_xg0<<<(T*G4*B)/256, 256, 0, stream>>>(wih0, bih0, bhh0, P, xg0);
    k_init<<<(H*B)/256, 256, 0, stream>>>(enc, fh0a, fc0, fh1a, fc1);
    float* h0in=fh0a; float* h0out=fh0b;
    float* h1in=fh1a; float* h1out=fh1b;
    for (int t=0;t<T;t++){
      k_cell0<<<256, 256, 0, stream>>>(whh0, xg0 + (long)t*G4*B, h0in, h0out, fc0);
      k_cell1<<<256, 256, 0, stream>>>(wih1, whh1, bih1, bhh1, h0out, h1in, h1out, fc1,
                                       H1Tmk, t);
      float* tmp;
      tmp=h0in; h0in=h0out; h0out=tmp;
      tmp=h1in; h1in=h1out; h1out=tmp;
    }
    k_pack<<<800, 256, 0, stream>>>(H1Tmk, (uint4*)Abf);
  }

  if (pre) k_gemm_pre<<<3250, 256, 0, stream>>>((const uint4*)Abf, (const uint4*)lwsw, lb, out);
  else     k_gemm_inl<<<3250, 256, 0, stream>>>((const uint4*)Abf, lw, lb, out);
  k_lsm<<<B*T, 1024, 0, stream>>>(out);
}